// Round 7
// baseline (21480.424 us; speedup 1.0000x reference)
//
#include <hip/hip_runtime.h>
#include <hip/hip_bf16.h>
#include <cstdint>

#define N_TOT 65536
#define NG 64
#define GS 1024
#define IN_DIM 34
#define WIDTH 126
#define EMB 128
#define PROP 32
#define SPACE 4
#define KNN 8
#define NCONV 5
#define FEAT (IN_DIM + NCONV*EMB)   /* 674 */
#define CATW (EMB + 2*PROP)         /* 192 */
#define AGGW (2*PROP)               /* 64 */
#define PRJW 36                     /* h(32) | s(4) */

// ---------------------------------------------------------------------------
// Register-tiled f32 GEMM, 256 threads, reg-prefetch + high occupancy.
// Split A operand [A1 | A2]. accum: 0 = C=act(A@W+bias)(+addx), 1 = C+=A@W,
// 2 = C=elu(C+A@W+bias). Optional second output (W2/C2) with its OWN Nn2/ldc2
// via extended grid.y (same A operand, e.g. h- and s-projections).
// ---------------------------------------------------------------------------
template<int BM, int BN, int BK, int TM, int TN>
__global__ __launch_bounds__(256, 4)
void gemm_tile_kernel(const float* __restrict__ A1, int lda1, int K1,
                      const float* __restrict__ A2, int lda2, int K2,
                      const float* __restrict__ W, const float* __restrict__ bias,
                      float* __restrict__ C, int ldc, int Nn,
                      int accum, int act,
                      const float* __restrict__ W2, const float* __restrict__ bias2,
                      float* __restrict__ C2, int ldc2, int Nn2,
                      const float* __restrict__ addx, int addx_ld, int addx_off)
{
  constexpr int LDA = BM + 4;
  constexpr int LDB = BN + 4;
  constexpr int APASS = (BM*BK)/1024;
  constexpr int BPASS = (BN*BK)/1024;
  constexpr int AROWS = 256/(BK/4);
  constexpr int BROWS = 256/(BN/4);
  __shared__ float As[BK*LDA];            // As[k][m]
  __shared__ float Bs[BK*LDB];            // Bs[k][n]
  const int K = K1 + K2;
  const int t = threadIdx.x;
  const int bm0 = blockIdx.x * BM;

  // select output (dual-output support with independent Nn/ldc)
  const int ny1 = (Nn + BN - 1)/BN;
  int by = blockIdx.y;
  const float* Wp = W; const float* bp = bias; float* Cp = C;
  int NN = Nn, LDC = ldc;
  if (W2 != nullptr && by >= ny1){
    Wp = W2; bp = bias2; Cp = C2; NN = Nn2; LDC = ldc2; by -= ny1;
  }
  const int bn0 = by * BN;

  const int tx = t % 16;
  const int ty = t / 16;

  const int a_r = t / (BK/4);
  const int a_k = 4 * (t % (BK/4));
  const int b_c = t % (BN/4);
  const int b_k = t / (BN/4);

  float ar[APASS][4], br[BPASS][4];

  auto load_tile = [&](int k0){
    #pragma unroll
    for (int p = 0; p < APASS; ++p){
      size_t rr = (size_t)(bm0 + a_r + p*AROWS);
      #pragma unroll
      for (int j = 0; j < 4; ++j){
        int ka = k0 + a_k + j;
        float v = 0.f;
        if (ka < K)
          v = (ka < K1) ? A1[rr*lda1 + ka] : A2[rr*lda2 + (ka - K1)];
        ar[p][j] = v;
      }
    }
    #pragma unroll
    for (int p = 0; p < BPASS; ++p){
      int kb = k0 + b_k + p*BROWS;
      #pragma unroll
      for (int j = 0; j < 4; ++j){
        int col = bn0 + 4*b_c + j;
        br[p][j] = (kb < K && col < NN) ? Wp[(size_t)kb*NN + col] : 0.f;
      }
    }
  };

  auto store_tile = [&](){
    #pragma unroll
    for (int p = 0; p < APASS; ++p)
      #pragma unroll
      for (int j = 0; j < 4; ++j)
        As[(a_k + j)*LDA + a_r + p*AROWS] = ar[p][j];
    #pragma unroll
    for (int p = 0; p < BPASS; ++p){
      float4 v = make_float4(br[p][0], br[p][1], br[p][2], br[p][3]);
      *(float4*)&Bs[(b_k + p*BROWS)*LDB + 4*b_c] = v;
    }
  };

  float acc[TM][TN];
  #pragma unroll
  for (int i = 0; i < TM; ++i)
    #pragma unroll
    for (int j = 0; j < TN; ++j) acc[i][j] = 0.f;

  auto compute_tile = [&](){
    #pragma unroll
    for (int kk = 0; kk < BK; ++kk){
      float a[TM], b[TN];
      #pragma unroll
      for (int iq = 0; iq < TM/4; ++iq){
        float4 v = *(const float4*)&As[kk*LDA + iq*(BM/2) + 4*ty];
        a[iq*4+0] = v.x; a[iq*4+1] = v.y; a[iq*4+2] = v.z; a[iq*4+3] = v.w;
      }
      #pragma unroll
      for (int jq = 0; jq < TN/4; ++jq){
        float4 v = *(const float4*)&Bs[kk*LDB + jq*(BN/2) + 4*tx];
        b[jq*4+0] = v.x; b[jq*4+1] = v.y; b[jq*4+2] = v.z; b[jq*4+3] = v.w;
      }
      #pragma unroll
      for (int i = 0; i < TM; ++i)
        #pragma unroll
        for (int j = 0; j < TN; ++j)
          acc[i][j] += a[i]*b[j];
    }
  };

  const int ntiles = (K + BK - 1)/BK;
  load_tile(0);
  store_tile();
  __syncthreads();
  for (int tt = 1; tt < ntiles; ++tt){
    load_tile(tt*BK);
    compute_tile();
    __syncthreads();
    store_tile();
    __syncthreads();
  }
  compute_tile();

  #pragma unroll
  for (int i = 0; i < TM; ++i){
    size_t row = (size_t)(bm0 + (i/4)*(BM/2) + 4*ty + (i%4));
    const int col0 = bn0 + 4*tx;
    float v[4];
    #pragma unroll
    for (int j = 0; j < 4; ++j) v[j] = acc[i][j];
    bool vec = ((LDC & 3) == 0) && (col0 + 3 < NN);
    if (accum == 1){
      if (vec){
        float4 c = *(const float4*)&Cp[row*LDC + col0];
        c.x += v[0]; c.y += v[1]; c.z += v[2]; c.w += v[3];
        *(float4*)&Cp[row*LDC + col0] = c;
      } else {
        #pragma unroll
        for (int j = 0; j < 4; ++j)
          if (col0 + j < NN) Cp[row*LDC + col0 + j] += v[j];
      }
    } else if (accum == 2){
      #pragma unroll
      for (int j = 0; j < 4; ++j){
        if (col0 + j < NN){
          float a2 = v[j] + Cp[row*LDC + col0 + j] + bp[col0 + j];
          Cp[row*LDC + col0 + j] = (a2 > 0.f) ? a2 : expm1f(a2);
        }
      }
    } else {
      #pragma unroll
      for (int j = 0; j < 4; ++j){
        int col = col0 + j;
        if (col < NN){
          if (bp) v[j] += bp[col];
          if (act == 1) v[j] = (v[j] > 0.f) ? v[j] : expm1f(v[j]);
          if (addx) v[j] += addx[row*addx_ld + addx_off + col];
        }
      }
      if (vec){
        *(float4*)&Cp[row*LDC + col0] = make_float4(v[0], v[1], v[2], v[3]);
      } else {
        #pragma unroll
        for (int j = 0; j < 4; ++j)
          if (col0 + j < NN) Cp[row*LDC + col0 + j] = v[j];
      }
    }
  }
}

// ---------------------------------------------------------------------------
// Per-graph kNN (K=8, incl. self) + weighted mean/max aggregation.
// proj: N x 36 rows = [h(32) | s(4)]. 16 blocks/graph x 64 threads.
// ---------------------------------------------------------------------------
#define KNN_THR 64
#define KNN_BPG 16

__global__ __launch_bounds__(KNN_THR)
void knn_agg_kernel(const float* __restrict__ proj, float* __restrict__ agg)
{
  __shared__ float4 ssv[GS];
  __shared__ float sn2[GS];
  int g     = blockIdx.x / KNN_BPG;
  int chunk = blockIdx.x % KNN_BPG;
  int t = threadIdx.x;

  const float* pg = proj + (size_t)g*GS*PRJW;
  for (int i = t; i < GS; i += KNN_THR){
    float4 v = *(const float4*)(pg + (size_t)i*PRJW + PROP);
    ssv[i] = v;
    sn2[i] = v.x*v.x + v.y*v.y + v.z*v.z + v.w*v.w;
  }
  __syncthreads();

  int i = chunk*KNN_THR + t;
  float4 sv = ssv[i];
  float myn2 = sn2[i];
  float si0 = sv.x, si1 = sv.y, si2 = sv.z, si3 = sv.w;

  float bd[KNN]; int bi[KNN];
  #pragma unroll
  for (int k = 0; k < KNN; ++k){ bd[k] = 1e30f; bi[k] = 0; }

  for (int j0 = 0; j0 < GS; j0 += 8){
    float dv[8];
    #pragma unroll
    for (int u = 0; u < 8; ++u){
      float4 sj = ssv[j0+u];
      float dot = si0*sj.x + si1*sj.y + si2*sj.z + si3*sj.w;
      dv[u] = myn2 + sn2[j0+u] - 2.f*dot;
    }
    float mn = fminf(fminf(fminf(dv[0],dv[1]), fminf(dv[2],dv[3])),
                     fminf(fminf(dv[4],dv[5]), fminf(dv[6],dv[7])));
    if (mn < bd[KNN-1]){
      #pragma unroll
      for (int u = 0; u < 8; ++u){
        float d2 = dv[u];
        if (d2 < bd[KNN-1]){
          int j = j0 + u;
          #pragma unroll
          for (int q = KNN-1; q >= 1; --q){
            bool cq = d2 < bd[q];
            bool cp = d2 < bd[q-1];
            float nv = cp ? bd[q-1] : d2;
            int   ni = cp ? bi[q-1] : j;
            if (cq){ bd[q] = nv; bi[q] = ni; }
          }
          if (d2 < bd[0]){ bd[0] = d2; bi[0] = j; }
        }
      }
    }
  }

  float w[KNN];
  #pragma unroll
  for (int k = 0; k < KNN; ++k){
    float4 sj = ssv[bi[k]];
    float d0 = si0 - sj.x, d1 = si1 - sj.y, d2_ = si2 - sj.z, d3 = si3 - sj.w;
    float dd = d0*d0 + d1*d1 + d2_*d2_ + d3*d3;
    w[k] = expf(-10.f*dd);
  }

  float msum[PROP], mmax[PROP];
  #pragma unroll
  for (int p = 0; p < PROP; ++p){ msum[p] = 0.f; mmax[p] = -1e30f; }
  #pragma unroll
  for (int k = 0; k < KNN; ++k){
    const float* hr = pg + (size_t)bi[k]*PRJW;
    float wk = w[k];
    #pragma unroll
    for (int p4 = 0; p4 < PROP/4; ++p4){
      float4 hv = *(const float4*)(hr + p4*4);
      float v0 = hv.x*wk, v1 = hv.y*wk, v2 = hv.z*wk, v3 = hv.w*wk;
      msum[p4*4+0] += v0; mmax[p4*4+0] = fmaxf(mmax[p4*4+0], v0);
      msum[p4*4+1] += v1; mmax[p4*4+1] = fmaxf(mmax[p4*4+1], v1);
      msum[p4*4+2] += v2; mmax[p4*4+2] = fmaxf(mmax[p4*4+2], v2);
      msum[p4*4+3] += v3; mmax[p4*4+3] = fmaxf(mmax[p4*4+3], v3);
    }
  }

  size_t row = (size_t)g*GS + i;
  float* arow = agg + row*AGGW;
  #pragma unroll
  for (int p = 0; p < PROP; ++p){
    arow[p]        = msum[p]*(1.f/KNN);
    arow[PROP + p] = mmax[p];
  }
}

// ---------------------------------------------------------------------------
extern "C" void kernel_launch(void* const* d_in, const int* in_sizes, int n_in,
                              void* d_out, int out_size, void* d_ws, size_t ws_size,
                              hipStream_t stream)
{
  const float* x     = (const float*)d_in[0];
  const float* n0W1  = (const float*)d_in[2];
  const float* n0b1  = (const float*)d_in[3];
  const float* n0W23 = (const float*)d_in[4];
  const float* n0b23 = (const float*)d_in[5];
  const float* n0W4  = (const float*)d_in[6];
  const float* n0b4  = (const float*)d_in[7];
  const float* cWh   = (const float*)d_in[8];
  const float* cbh   = (const float*)d_in[9];
  const float* cWs   = (const float*)d_in[10];
  const float* cbs   = (const float*)d_in[11];
  const float* cWo   = (const float*)d_in[12];
  const float* cbo   = (const float*)d_in[13];
  const float* HW1   = (const float*)d_in[14];
  const float* Hb1   = (const float*)d_in[15];
  const float* HW23  = (const float*)d_in[16];
  const float* Hb23  = (const float*)d_in[17];
  const float* Wid   = (const float*)d_in[18];
  const float* bid   = (const float*)d_in[19];
  const float* Wreg  = (const float*)d_in[20];
  const float* breg  = (const float*)d_in[21];
  const float* Wch   = (const float*)d_in[22];
  const float* bch   = (const float*)d_in[23];
  float* out = (float*)d_out;
  (void)in_sizes; (void)n_in; (void)out_size; (void)ws_size;

  // ---- workspace layout (159.4 MB, within proven budget) ----
  char* wsp = (char*)d_ws;
  float* P     = (float*)(wsp);                  // N x 128 (ld 128)
  float* Q     = (float*)(wsp + 33554432);       // N x 128 (ld 128)
  float* haccA = (float*)(wsp + 67108864);       // N x 126 (ld 126)
  float* haccB = (float*)(wsp + 100139008);      // N x 126 (ld 126)
  float* projb = (float*)(wsp + 133169152);      // N x 36
  float* aggb  = (float*)(wsp + 142606336);      // N x 64

  auto gemmL = [&](const float* A1, int lda1, int K1,
                   const float* A2, int lda2, int K2,
                   const float* W, const float* b,
                   float* C, int ldc, int Nn, int accum, int act,
                   const float* W2, const float* b2, float* C2, int ldc2, int Nn2,
                   const float* addx, int addx_ld, int addx_off){
    int ny = (Nn + 63)/64 + (W2 ? (Nn2 + 63)/64 : 0);
    dim3 grid(N_TOT/128, ny);
    hipLaunchKernelGGL((gemm_tile_kernel<128,64,32,8,4>), grid, dim3(256), 0, stream,
        A1, lda1, K1, A2, lda2, K2, W, b, C, ldc, Nn, accum, act,
        W2, b2, C2, ldc2, Nn2, addx, addx_ld, addx_off);
  };
  auto gemmS = [&](const float* A1, int lda1, int K1,
                   const float* W, const float* b,
                   float* C, int ldc, int Nn, int accum, int act,
                   const float* W2, const float* b2, float* C2, int ldc2, int Nn2,
                   const float* addx, int addx_ld, int addx_off){
    int ny = (Nn + 63)/64 + (W2 ? (Nn2 + 63)/64 : 0);
    dim3 grid(N_TOT/64, ny);
    hipLaunchKernelGGL((gemm_tile_kernel<64,64,32,4,4>), grid, dim3(256), 0, stream,
        A1, lda1, K1, (const float*)nullptr, 0, 0, W, b, C, ldc, Nn, accum, act,
        W2, b2, C2, ldc2, Nn2, addx, addx_ld, addx_off);
  };

  for (int s = 0; s < 2; ++s){
    // ---- embedding MLP -> P (scratch: Q, haccA) ----
    gemmL(x, IN_DIM, IN_DIM, nullptr,0,0, n0W1, n0b1,
          Q, EMB, WIDTH, 0, 1, nullptr,nullptr,nullptr,0,0, nullptr,0,0);
    gemmL(Q, EMB, WIDTH, nullptr,0,0, n0W23, n0b23,
          haccA, WIDTH, WIDTH, 0, 1, nullptr,nullptr,nullptr,0,0, nullptr,0,0);
    gemmL(haccA, WIDTH, WIDTH, nullptr,0,0, n0W23 + WIDTH*WIDTH, n0b23 + WIDTH,
          Q, EMB, WIDTH, 0, 1, nullptr,nullptr,nullptr,0,0, nullptr,0,0);
    gemmL(Q, EMB, WIDTH, nullptr,0,0, n0W4, n0b4,
          P, EMB, EMB, 0, 0, nullptr,nullptr,nullptr,0,0, nullptr,0,0);

    // ---- head layer-1 init: hacc = x @ W1[rows 0..33] ----
    int h0 = (s == 0) ? 0 : 1;
    gemmL(x, IN_DIM, IN_DIM, nullptr,0,0,
          HW1 + (size_t)h0*FEAT*WIDTH, nullptr,
          haccA, WIDTH, WIDTH, 0, 0,
          (s==1) ? HW1 + (size_t)2*FEAT*WIDTH : nullptr, nullptr,
          (s==1) ? haccB : nullptr, WIDTH, WIDTH,
          nullptr,0,0);

    float* cur = P; float* nxt = Q;
    for (int cv = 0; cv < NCONV; ++cv){
      int pidx = s*NCONV + cv;
      // h|s projections (dual output into projb cols 0..31 / 32..35)
      gemmS(cur, EMB, EMB,
            cWh + (size_t)pidx*EMB*PROP, cbh + pidx*PROP,
            projb, PRJW, PROP, 0, 0,
            cWs + (size_t)pidx*EMB*SPACE, cbs + pidx*SPACE,
            projb + PROP, PRJW, SPACE,
            nullptr,0,0);
      // kNN + aggregate -> aggb
      hipLaunchKernelGGL(knn_agg_kernel, dim3(NG*KNN_BPG), dim3(KNN_THR), 0, stream,
                         projb, aggb);
      // o_cv = [cur | agg] @ Wo + bo -> nxt
      gemmL(cur, EMB, EMB, aggb, AGGW, AGGW,
            cWo + (size_t)pidx*CATW*EMB, cbo + pidx*EMB,
            nxt, EMB, EMB, 0, 0, nullptr,nullptr,nullptr,0,0, nullptr,0,0);
      // hacc += o_cv @ W1[rows 34+cv*128 ..]; last conv fuses bias+ELU
      int acc_mode = (cv == NCONV-1) ? 2 : 1;
      gemmL(nxt, EMB, EMB, nullptr,0,0,
            HW1 + (size_t)h0*FEAT*WIDTH + (size_t)(IN_DIM + cv*EMB)*WIDTH,
            (acc_mode==2) ? Hb1 + h0*WIDTH : nullptr,
            haccA, WIDTH, WIDTH, acc_mode, 0,
            (s==1) ? HW1 + (size_t)2*FEAT*WIDTH + (size_t)(IN_DIM + cv*EMB)*WIDTH : nullptr,
            (s==1 && acc_mode==2) ? Hb1 + 2*WIDTH : nullptr,
            (s==1) ? haccB : nullptr, WIDTH, WIDTH,
            nullptr,0,0);
      float* tmp = cur; cur = nxt; nxt = tmp;
    }

    // ---- head finish (scratch: P, free after conv loop) ----
    auto finish_head = [&](int hidx, float* hacc, float* dst, int dst_ld, int out_dim,
                           const float* Wl, const float* bl,
                           const float* addx, int addx_ld, int addx_off){
      gemmL(hacc, WIDTH, WIDTH, nullptr,0,0,
            HW23 + (size_t)(hidx*2+0)*WIDTH*WIDTH, Hb23 + (hidx*2+0)*WIDTH,
            P, EMB, WIDTH, 0, 1, nullptr,nullptr,nullptr,0,0, nullptr,0,0);
      gemmL(P, EMB, WIDTH, nullptr,0,0,
            HW23 + (size_t)(hidx*2+1)*WIDTH*WIDTH, Hb23 + (hidx*2+1)*WIDTH,
            hacc, WIDTH, WIDTH, 0, 1, nullptr,nullptr,nullptr,0,0, nullptr,0,0);
      gemmS(hacc, WIDTH, WIDTH, Wl, bl,
            dst, dst_ld, out_dim, 0, 0, nullptr,nullptr,nullptr,0,0,
            addx, addx_ld, addx_off);
    };

    if (s == 0){
      finish_head(0, haccA, out, 8, 8, Wid, bid, nullptr, 0, 0);
    } else {
      finish_head(1, haccA, out + (size_t)N_TOT*8, 4, 4, Wreg, breg, x, IN_DIM, 1);
      finish_head(2, haccB, out + (size_t)N_TOT*12, 1, 1, Wch, bch, nullptr, 0, 0);
    }
  }
}

// Round 8
// 4151.336 us; speedup vs baseline: 5.1743x; 5.1743x over previous
//
#include <hip/hip_runtime.h>
#include <hip/hip_bf16.h>
#include <cstdint>

#define N_TOT 65536
#define NG 64
#define GS 1024
#define IN_DIM 34
#define WIDTH 126
#define EMB 128
#define PROP 32
#define SPACE 4
#define KNN 8
#define NCONV 5
#define FEAT (IN_DIM + NCONV*EMB)   /* 674 */
#define CATW (EMB + 2*PROP)         /* 192 */
#define AGGW (2*PROP)               /* 64 */
#define PRJW 36                     /* h(32) | s(4) */

typedef __attribute__((ext_vector_type(8))) short short8v;
typedef __attribute__((ext_vector_type(4))) float f32x4;

__device__ __forceinline__ unsigned short f2bf(float f){
  unsigned int u = __float_as_uint(f);
  unsigned int r = (u + 0x7FFFu + ((u >> 16) & 1u)) >> 16;
  return (unsigned short)r;
}
__device__ __forceinline__ float bf2f(unsigned short b){
  return __uint_as_float(((unsigned int)b) << 16);
}

// ---------------------------------------------------------------------------
// MFMA bf16 GEMM with LIMBS-limb f32 emulation (LIMBS=1: plain bf16;
// LIMBS=3: products i+j<=2, ~2^-22 relative error ~ f32-grade).
// C[M x Nn] (f32) = op(A @ W + ...). A split [A1|A2] f32; W f32 [K][Nn].
// mode: 0 = C = act(A@W + bias), 1 = C += A@W, 2 = C = elu(C + A@W + bias).
// Block: 256 thr = 4 waves (2x2), tile 128x128, BK=32, mfma 16x16x32.
// ---------------------------------------------------------------------------
template<int LIMBS>
__global__ __launch_bounds__(256)
void mfma_gemm(const float* __restrict__ A1, int lda1, int K1,
               const float* __restrict__ A2, int lda2, int K2,
               const float* __restrict__ W, const float* __restrict__ bias,
               float* __restrict__ C, int ldc, int Nn,
               int mode, int act)
{
  constexpr int ASTR = LIMBS*32 + 8;          // ushort stride; *2B is 16B-mult
  __shared__ __align__(16) unsigned short Alds[128*ASTR];
  __shared__ __align__(16) unsigned short Blds[128*ASTR];

  const int K = K1 + K2;
  const int t = threadIdx.x;
  const int bm0 = blockIdx.x * 128;
  const int lane = t & 63;
  const int wid  = t >> 6;
  const int wr = (wid >> 1) * 64;             // wave row offset
  const int wc = (wid & 1) * 64;              // wave col offset
  const int frow = lane & 15;
  const int fk   = (lane >> 4) * 8;

  // staging maps
  const int a_row = t >> 1;                   // 0..127
  const int a_kh  = (t & 1) * 16;             // 0|16
  const int b_col = t & 127;
  const int b_kh  = (t >> 7) * 16;

  f32x4 acc[4][4];
  #pragma unroll
  for (int i = 0; i < 4; ++i)
    #pragma unroll
    for (int j = 0; j < 4; ++j)
      acc[i][j] = (f32x4){0.f, 0.f, 0.f, 0.f};

  const int ntiles = (K + 31) / 32;
  for (int kt = 0; kt < ntiles; ++kt){
    const int k0 = kt * 32;
    __syncthreads();
    // ---- stage A (128 x 32 f32 -> LIMBS bf16 limbs) ----
    {
      float v[16];
      const size_t rr = (size_t)(bm0 + a_row);
      #pragma unroll
      for (int j = 0; j < 16; ++j){
        int ka = k0 + a_kh + j;
        float x = 0.f;
        if (ka < K)
          x = (ka < K1) ? A1[rr*lda1 + ka] : A2[rr*lda2 + (ka - K1)];
        v[j] = x;
      }
      #pragma unroll
      for (int l = 0; l < LIMBS; ++l){
        short8v p0, p1;
        #pragma unroll
        for (int j = 0; j < 8; ++j){
          unsigned short b = f2bf(v[j]); v[j] -= bf2f(b); p0[j] = (short)b;
        }
        #pragma unroll
        for (int j = 0; j < 8; ++j){
          unsigned short b = f2bf(v[8+j]); v[8+j] -= bf2f(b); p1[j] = (short)b;
        }
        *(short8v*)&Alds[a_row*ASTR + l*32 + a_kh]     = p0;
        *(short8v*)&Alds[a_row*ASTR + l*32 + a_kh + 8] = p1;
      }
    }
    // ---- stage B transposed: Blds[col][k] ----
    {
      float v[16];
      #pragma unroll
      for (int j = 0; j < 16; ++j){
        int kb = k0 + b_kh + j;
        v[j] = (kb < K && b_col < Nn) ? W[(size_t)kb*Nn + b_col] : 0.f;
      }
      #pragma unroll
      for (int l = 0; l < LIMBS; ++l){
        short8v p0, p1;
        #pragma unroll
        for (int j = 0; j < 8; ++j){
          unsigned short b = f2bf(v[j]); v[j] -= bf2f(b); p0[j] = (short)b;
        }
        #pragma unroll
        for (int j = 0; j < 8; ++j){
          unsigned short b = f2bf(v[8+j]); v[8+j] -= bf2f(b); p1[j] = (short)b;
        }
        *(short8v*)&Blds[b_col*ASTR + l*32 + b_kh]     = p0;
        *(short8v*)&Blds[b_col*ASTR + l*32 + b_kh + 8] = p1;
      }
    }
    __syncthreads();
    // ---- compute: limb passes (i+j < LIMBS ... i+j<=LIMBS-1? see below) ----
    // kept pairs: lA + lB <= LIMBS-1 ... for LIMBS=3 we keep i+j<=2 (6 passes)
    #pragma unroll
    for (int lA = 0; lA < LIMBS; ++lA){
      short8v af[4];
      #pragma unroll
      for (int rb = 0; rb < 4; ++rb)
        af[rb] = *(const short8v*)&Alds[(wr + rb*16 + frow)*ASTR + lA*32 + fk];
      #pragma unroll
      for (int lB = 0; lB < LIMBS - lA; ++lB){
        short8v bfr[4];
        #pragma unroll
        for (int cb = 0; cb < 4; ++cb)
          bfr[cb] = *(const short8v*)&Blds[(wc + cb*16 + frow)*ASTR + lB*32 + fk];
        #pragma unroll
        for (int rb = 0; rb < 4; ++rb)
          #pragma unroll
          for (int cb = 0; cb < 4; ++cb)
            acc[rb][cb] = __builtin_amdgcn_mfma_f32_16x16x32_bf16(
                af[rb], bfr[cb], acc[rb][cb], 0, 0, 0);
      }
    }
  }

  // ---- epilogue ----
  const int lr4 = (lane >> 4) * 4;
  #pragma unroll
  for (int rb = 0; rb < 4; ++rb){
    #pragma unroll
    for (int cb = 0; cb < 4; ++cb){
      const int col = wc + cb*16 + frow;
      if (col < Nn){
        #pragma unroll
        for (int ri = 0; ri < 4; ++ri){
          const size_t row = (size_t)(bm0 + wr + rb*16 + lr4 + ri);
          float v = acc[rb][cb][ri];
          if (mode == 1){
            C[row*ldc + col] += v;
          } else if (mode == 2){
            float a2 = v + C[row*ldc + col] + bias[col];
            C[row*ldc + col] = (a2 > 0.f) ? a2 : expm1f(a2);
          } else {
            if (bias) v += bias[col];
            if (act == 1) v = (v > 0.f) ? v : expm1f(v);
            C[row*ldc + col] = v;
          }
        }
      }
    }
  }
}

// ---------------------------------------------------------------------------
// f32 register-tiled GEMM (round-6 proven engine) — used only for the tiny
// final head projections (N=8/4/1) incl. the mom +x[:,1:5] residual.
// ---------------------------------------------------------------------------
template<int BM, int BN, int BK, int TM, int TN>
__global__ __launch_bounds__(256)
void gemm_tile_kernel(const float* __restrict__ A1, int lda1, int K1,
                      const float* __restrict__ W, const float* __restrict__ bias,
                      float* __restrict__ C, int ldc, int Nn, int act,
                      const float* __restrict__ addx, int addx_ld, int addx_off)
{
  constexpr int LDA = BM + 4;
  constexpr int LDB = BN + 4;
  constexpr int APASS = (BM*BK)/1024;
  constexpr int BPASS = (BN*BK)/1024;
  constexpr int AROWS = 256/(BK/4);
  constexpr int BROWS = 256/(BN/4);
  __shared__ float As[BK*LDA];
  __shared__ float Bs[BK*LDB];
  const int K = K1;
  const int t = threadIdx.x;
  const int bm0 = blockIdx.x * BM;
  const int bn0 = blockIdx.y * BN;
  const int tx = t % 16;
  const int ty = t / 16;
  const int a_r = t / (BK/4);
  const int a_k = 4 * (t % (BK/4));
  const int b_c = t % (BN/4);
  const int b_k = t / (BN/4);

  float ar[APASS][4], br[BPASS][4];
  auto load_tile = [&](int k0){
    #pragma unroll
    for (int p = 0; p < APASS; ++p){
      size_t rr = (size_t)(bm0 + a_r + p*AROWS);
      #pragma unroll
      for (int j = 0; j < 4; ++j){
        int ka = k0 + a_k + j;
        ar[p][j] = (ka < K) ? A1[rr*lda1 + ka] : 0.f;
      }
    }
    #pragma unroll
    for (int p = 0; p < BPASS; ++p){
      int kb = k0 + b_k + p*BROWS;
      #pragma unroll
      for (int j = 0; j < 4; ++j){
        int col = bn0 + 4*b_c + j;
        br[p][j] = (kb < K && col < Nn) ? W[(size_t)kb*Nn + col] : 0.f;
      }
    }
  };
  auto store_tile = [&](){
    #pragma unroll
    for (int p = 0; p < APASS; ++p)
      #pragma unroll
      for (int j = 0; j < 4; ++j)
        As[(a_k + j)*LDA + a_r + p*AROWS] = ar[p][j];
    #pragma unroll
    for (int p = 0; p < BPASS; ++p)
      *(float4*)&Bs[(b_k + p*BROWS)*LDB + 4*b_c] =
          make_float4(br[p][0], br[p][1], br[p][2], br[p][3]);
  };

  float acc[TM][TN];
  #pragma unroll
  for (int i = 0; i < TM; ++i)
    #pragma unroll
    for (int j = 0; j < TN; ++j) acc[i][j] = 0.f;

  auto compute_tile = [&](){
    #pragma unroll
    for (int kk = 0; kk < BK; ++kk){
      float a[TM], b[TN];
      #pragma unroll
      for (int iq = 0; iq < TM/4; ++iq){
        float4 v = *(const float4*)&As[kk*LDA + iq*(BM/2) + 4*ty];
        a[iq*4+0] = v.x; a[iq*4+1] = v.y; a[iq*4+2] = v.z; a[iq*4+3] = v.w;
      }
      #pragma unroll
      for (int jq = 0; jq < TN/4; ++jq){
        float4 v = *(const float4*)&Bs[kk*LDB + jq*(BN/2) + 4*tx];
        b[jq*4+0] = v.x; b[jq*4+1] = v.y; b[jq*4+2] = v.z; b[jq*4+3] = v.w;
      }
      #pragma unroll
      for (int i = 0; i < TM; ++i)
        #pragma unroll
        for (int j = 0; j < TN; ++j)
          acc[i][j] += a[i]*b[j];
    }
  };

  const int ntiles = (K + BK - 1)/BK;
  load_tile(0); store_tile(); __syncthreads();
  for (int tt = 1; tt < ntiles; ++tt){
    load_tile(tt*BK);
    compute_tile();
    __syncthreads();
    store_tile();
    __syncthreads();
  }
  compute_tile();

  #pragma unroll
  for (int i = 0; i < TM; ++i){
    size_t row = (size_t)(bm0 + (i/4)*(BM/2) + 4*ty + (i%4));
    #pragma unroll
    for (int j = 0; j < TN; ++j){
      int col = bn0 + (j/4)*(BN/2) + 4*tx + (j%4);
      if (col < Nn){
        float v = acc[i][j];
        if (bias) v += bias[col];
        if (act == 1) v = (v > 0.f) ? v : expm1f(v);
        if (addx) v += addx[row*addx_ld + addx_off + col];
        C[row*ldc + col] = v;
      }
    }
  }
}

// ---------------------------------------------------------------------------
// Per-graph kNN (K=8, incl. self) + weighted mean/max aggregation (unchanged).
// ---------------------------------------------------------------------------
#define KNN_THR 64
#define KNN_BPG 16

__global__ __launch_bounds__(KNN_THR)
void knn_agg_kernel(const float* __restrict__ proj, float* __restrict__ agg)
{
  __shared__ float4 ssv[GS];
  __shared__ float sn2[GS];
  int g     = blockIdx.x / KNN_BPG;
  int chunk = blockIdx.x % KNN_BPG;
  int t = threadIdx.x;

  const float* pg = proj + (size_t)g*GS*PRJW;
  for (int i = t; i < GS; i += KNN_THR){
    float4 v = *(const float4*)(pg + (size_t)i*PRJW + PROP);
    ssv[i] = v;
    sn2[i] = v.x*v.x + v.y*v.y + v.z*v.z + v.w*v.w;
  }
  __syncthreads();

  int i = chunk*KNN_THR + t;
  float4 sv = ssv[i];
  float myn2 = sn2[i];
  float si0 = sv.x, si1 = sv.y, si2 = sv.z, si3 = sv.w;

  float bd[KNN]; int bi[KNN];
  #pragma unroll
  for (int k = 0; k < KNN; ++k){ bd[k] = 1e30f; bi[k] = 0; }

  for (int j0 = 0; j0 < GS; j0 += 8){
    float dv[8];
    #pragma unroll
    for (int u = 0; u < 8; ++u){
      float4 sj = ssv[j0+u];
      float dot = si0*sj.x + si1*sj.y + si2*sj.z + si3*sj.w;
      dv[u] = myn2 + sn2[j0+u] - 2.f*dot;
    }
    float mn = fminf(fminf(fminf(dv[0],dv[1]), fminf(dv[2],dv[3])),
                     fminf(fminf(dv[4],dv[5]), fminf(dv[6],dv[7])));
    if (mn < bd[KNN-1]){
      #pragma unroll
      for (int u = 0; u < 8; ++u){
        float d2 = dv[u];
        if (d2 < bd[KNN-1]){
          int j = j0 + u;
          #pragma unroll
          for (int q = KNN-1; q >= 1; --q){
            bool cq = d2 < bd[q];
            bool cp = d2 < bd[q-1];
            float nv = cp ? bd[q-1] : d2;
            int   ni = cp ? bi[q-1] : j;
            if (cq){ bd[q] = nv; bi[q] = ni; }
          }
          if (d2 < bd[0]){ bd[0] = d2; bi[0] = j; }
        }
      }
    }
  }

  float w[KNN];
  #pragma unroll
  for (int k = 0; k < KNN; ++k){
    float4 sj = ssv[bi[k]];
    float d0 = si0 - sj.x, d1 = si1 - sj.y, d2_ = si2 - sj.z, d3 = si3 - sj.w;
    float dd = d0*d0 + d1*d1 + d2_*d2_ + d3*d3;
    w[k] = expf(-10.f*dd);
  }

  float msum[PROP], mmax[PROP];
  #pragma unroll
  for (int p = 0; p < PROP; ++p){ msum[p] = 0.f; mmax[p] = -1e30f; }
  #pragma unroll
  for (int k = 0; k < KNN; ++k){
    const float* hr = pg + (size_t)bi[k]*PRJW;
    float wk = w[k];
    #pragma unroll
    for (int p4 = 0; p4 < PROP/4; ++p4){
      float4 hv = *(const float4*)(hr + p4*4);
      float v0 = hv.x*wk, v1 = hv.y*wk, v2 = hv.z*wk, v3 = hv.w*wk;
      msum[p4*4+0] += v0; mmax[p4*4+0] = fmaxf(mmax[p4*4+0], v0);
      msum[p4*4+1] += v1; mmax[p4*4+1] = fmaxf(mmax[p4*4+1], v1);
      msum[p4*4+2] += v2; mmax[p4*4+2] = fmaxf(mmax[p4*4+2], v2);
      msum[p4*4+3] += v3; mmax[p4*4+3] = fmaxf(mmax[p4*4+3], v3);
    }
  }

  size_t row = (size_t)g*GS + i;
  float* arow = agg + row*AGGW;
  #pragma unroll
  for (int p = 0; p < PROP; ++p){
    arow[p]        = msum[p]*(1.f/KNN);
    arow[PROP + p] = mmax[p];
  }
}

// ---------------------------------------------------------------------------
extern "C" void kernel_launch(void* const* d_in, const int* in_sizes, int n_in,
                              void* d_out, int out_size, void* d_ws, size_t ws_size,
                              hipStream_t stream)
{
  const float* x     = (const float*)d_in[0];
  const float* n0W1  = (const float*)d_in[2];
  const float* n0b1  = (const float*)d_in[3];
  const float* n0W23 = (const float*)d_in[4];
  const float* n0b23 = (const float*)d_in[5];
  const float* n0W4  = (const float*)d_in[6];
  const float* n0b4  = (const float*)d_in[7];
  const float* cWh   = (const float*)d_in[8];
  const float* cbh   = (const float*)d_in[9];
  const float* cWs   = (const float*)d_in[10];
  const float* cbs   = (const float*)d_in[11];
  const float* cWo   = (const float*)d_in[12];
  const float* cbo   = (const float*)d_in[13];
  const float* HW1   = (const float*)d_in[14];
  const float* Hb1   = (const float*)d_in[15];
  const float* HW23  = (const float*)d_in[16];
  const float* Hb23  = (const float*)d_in[17];
  const float* Wid   = (const float*)d_in[18];
  const float* bid   = (const float*)d_in[19];
  const float* Wreg  = (const float*)d_in[20];
  const float* breg  = (const float*)d_in[21];
  const float* Wch   = (const float*)d_in[22];
  const float* bch   = (const float*)d_in[23];
  float* out = (float*)d_out;
  (void)in_sizes; (void)n_in; (void)out_size; (void)ws_size;

  char* wsp = (char*)d_ws;
  float* P     = (float*)(wsp);                  // N x 128 (ld 128)
  float* Q     = (float*)(wsp + 33554432);       // N x 128 (ld 128)
  float* haccA = (float*)(wsp + 67108864);       // N x 126 (ld 126)
  float* haccB = (float*)(wsp + 100139008);      // N x 126 (ld 126)
  float* projb = (float*)(wsp + 133169152);      // N x 36
  float* aggb  = (float*)(wsp + 142606336);      // N x 64

  // 3-limb (f32-grade) MFMA GEMM — selection-critical conv chain
  auto gemm3 = [&](const float* A1, int lda1, int K1,
                   const float* A2, int lda2, int K2,
                   const float* W, const float* b,
                   float* C, int ldc, int Nn, int mode, int act){
    hipLaunchKernelGGL((mfma_gemm<3>), dim3(N_TOT/128), dim3(256), 0, stream,
        A1, lda1, K1, A2, lda2, K2, W, b, C, ldc, Nn, mode, act);
  };
  // 1-limb (bf16) MFMA GEMM — head-side smooth path
  auto gemm1 = [&](const float* A1, int lda1, int K1,
                   const float* W, const float* b,
                   float* C, int ldc, int Nn, int mode, int act){
    hipLaunchKernelGGL((mfma_gemm<1>), dim3(N_TOT/128), dim3(256), 0, stream,
        A1, lda1, K1, (const float*)nullptr, 0, 0, W, b, C, ldc, Nn, mode, act);
  };
  // small f32 GEMM for final head outputs
  auto gemmS = [&](const float* A1, int lda1, int K1,
                   const float* W, const float* b,
                   float* C, int ldc, int Nn, int act,
                   const float* addx, int addx_ld, int addx_off){
    dim3 grid(N_TOT/64, (Nn+63)/64);
    hipLaunchKernelGGL((gemm_tile_kernel<64,64,32,4,4>), grid, dim3(256), 0, stream,
        A1, lda1, K1, W, b, C, ldc, Nn, act, addx, addx_ld, addx_off);
  };

  for (int s = 0; s < 2; ++s){
    // ---- embedding MLP: x ->126(ELU)->126(ELU)->126(ELU)->128 -> P ----
    gemm3(x, IN_DIM, IN_DIM, nullptr,0,0, n0W1, n0b1, Q, EMB, WIDTH, 0, 1);
    gemm3(Q, EMB, WIDTH, nullptr,0,0, n0W23, n0b23, P, EMB, WIDTH, 0, 1);
    gemm3(P, EMB, WIDTH, nullptr,0,0, n0W23 + WIDTH*WIDTH, n0b23 + WIDTH,
          Q, EMB, WIDTH, 0, 1);
    gemm3(Q, EMB, WIDTH, nullptr,0,0, n0W4, n0b4, P, EMB, EMB, 0, 0);

    // ---- head layer-1 init: hacc = x @ W1[rows 0..33] (no bias yet) ----
    int h0 = (s == 0) ? 0 : 1;
    gemm1(x, IN_DIM, IN_DIM, HW1 + (size_t)h0*FEAT*WIDTH, nullptr,
          haccA, WIDTH, WIDTH, 0, 0);
    if (s == 1)
      gemm1(x, IN_DIM, IN_DIM, HW1 + (size_t)2*FEAT*WIDTH, nullptr,
            haccB, WIDTH, WIDTH, 0, 0);

    float* cur = P; float* nxt = Q;
    for (int cv = 0; cv < NCONV; ++cv){
      int pidx = s*NCONV + cv;
      // h-projection -> projb cols 0..31 ; s-projection -> cols 32..35
      gemm3(cur, EMB, EMB, nullptr,0,0,
            cWh + (size_t)pidx*EMB*PROP, cbh + pidx*PROP,
            projb, PRJW, PROP, 0, 0);
      gemm3(cur, EMB, EMB, nullptr,0,0,
            cWs + (size_t)pidx*EMB*SPACE, cbs + pidx*SPACE,
            projb + PROP, PRJW, SPACE, 0, 0);
      // kNN + aggregate -> aggb
      hipLaunchKernelGGL(knn_agg_kernel, dim3(NG*KNN_BPG), dim3(KNN_THR), 0, stream,
                         projb, aggb);
      // o_cv = [cur | agg] @ Wo + bo -> nxt
      gemm3(cur, EMB, EMB, aggb, AGGW, AGGW,
            cWo + (size_t)pidx*CATW*EMB, cbo + pidx*EMB,
            nxt, EMB, EMB, 0, 0);
      // hacc += o_cv @ W1[rows 34+cv*128 ..]; last conv fuses bias+ELU
      int mode = (cv == NCONV-1) ? 2 : 1;
      gemm1(nxt, EMB, EMB,
            HW1 + (size_t)h0*FEAT*WIDTH + (size_t)(IN_DIM + cv*EMB)*WIDTH,
            (mode==2) ? Hb1 + h0*WIDTH : nullptr,
            haccA, WIDTH, WIDTH, mode, 0);
      if (s == 1)
        gemm1(nxt, EMB, EMB,
              HW1 + (size_t)2*FEAT*WIDTH + (size_t)(IN_DIM + cv*EMB)*WIDTH,
              (mode==2) ? Hb1 + 2*WIDTH : nullptr,
              haccB, WIDTH, WIDTH, mode, 0);
      float* tmp = cur; cur = nxt; nxt = tmp;
    }

    // ---- head finish (P is free scratch after conv loop) ----
    auto finish_head = [&](int hidx, float* hacc, float* dst, int dst_ld, int out_dim,
                           const float* Wl, const float* bl,
                           const float* addx, int addx_ld, int addx_off){
      gemm1(hacc, WIDTH, WIDTH,
            HW23 + (size_t)(hidx*2+0)*WIDTH*WIDTH, Hb23 + (hidx*2+0)*WIDTH,
            P, EMB, WIDTH, 0, 1);
      gemm1(P, EMB, WIDTH,
            HW23 + (size_t)(hidx*2+1)*WIDTH*WIDTH, Hb23 + (hidx*2+1)*WIDTH,
            hacc, WIDTH, WIDTH, 0, 1);
      gemmS(hacc, WIDTH, WIDTH, Wl, bl,
            dst, dst_ld, out_dim, 0, addx, addx_ld, addx_off);
    };

    if (s == 0){
      finish_head(0, haccA, out, 8, 8, Wid, bid, nullptr, 0, 0);
    } else {
      finish_head(1, haccA, out + (size_t)N_TOT*8, 4, 4, Wreg, breg, x, IN_DIM, 1);
      finish_head(2, haccB, out + (size_t)N_TOT*12, 1, 1, Wch, bch, nullptr, 0, 0);
    }
  }
}

// Round 9
// 3167.299 us; speedup vs baseline: 6.7819x; 1.3107x over previous
//
#include <hip/hip_runtime.h>
#include <hip/hip_bf16.h>
#include <cstdint>

#define N_TOT 65536
#define NG 64
#define GS 1024
#define IN_DIM 34
#define WIDTH 126
#define EMB 128
#define PROP 32
#define SPACE 4
#define KNN 8
#define NCONV 5
#define FEAT (IN_DIM + NCONV*EMB)   /* 674 */
#define CATW (EMB + 2*PROP)         /* 192 */
#define AGGW (2*PROP)               /* 64 */
#define PRJW 36                     /* h(32) | s(4) */

typedef __attribute__((ext_vector_type(8))) short short8v;
typedef __attribute__((ext_vector_type(4))) float f32x4;

__device__ __forceinline__ unsigned short f2bf(float f){
  unsigned int u = __float_as_uint(f);
  unsigned int r = (u + 0x7FFFu + ((u >> 16) & 1u)) >> 16;
  return (unsigned short)r;
}
__device__ __forceinline__ float bf2f(unsigned short b){
  return __uint_as_float(((unsigned int)b) << 16);
}

// ---------------------------------------------------------------------------
// Weight pre-conversion: f32 matrix (optionally two col-concatenated sources)
// -> bf16 limb pool, layout [limb][ktile][col(<ncolpad)][k32], zero-padded.
// ---------------------------------------------------------------------------
struct WDesc {
  const float* s1; const float* s2;
  int ld1, ld2, nc1, K, Nn, limbs;
  long long dstoff;
};
#define NMAT 42
struct WDescs { WDesc d[NMAT]; };

__global__ __launch_bounds__(256)
void conv_weights_kernel(WDescs DS, unsigned short* __restrict__ pool)
{
  int m = blockIdx.y;
  WDesc d = DS.d[m];
  int ntiles = (d.K + 31) >> 5;
  int ncp = (d.Nn + 127) & ~127;
  int nchunk = ncp >> 5;
  int kt = blockIdx.x / nchunk;
  int cc = blockIdx.x % nchunk;
  if (kt >= ntiles) return;
  int t = threadIdx.x;
  int kk = t & 31;
  int k = kt*32 + kk;
  for (int c = (t >> 5); c < 32; c += 8){
    int col = cc*32 + c;
    float v = 0.f;
    if (k < d.K && col < d.Nn)
      v = (col < d.nc1) ? d.s1[(size_t)k*d.ld1 + col]
                        : d.s2[(size_t)k*d.ld2 + (col - d.nc1)];
    #pragma unroll 3
    for (int l = 0; l < d.limbs; ++l){
      unsigned short b = f2bf(v); v -= bf2f(b);
      pool[d.dstoff + ((long long)(l*ntiles + kt)*ncp + col)*32 + kk] = b;
    }
  }
}

// ---------------------------------------------------------------------------
// MFMA bf16 GEMM, LIMBS-limb f32 emulation. A staged+converted in LDS;
// B fragments read DIRECTLY from the pre-converted limb pool (coalesced,
// L2-resident). mode: 0 C=act(A@W+bias), 1 C+=A@W, 2 C=elu(C+A@W+bias).
// bias[col] = col<bsplit ? bias1[col] : bias2[col-bsplit].
// Block 256 thr = 4 waves (2x2), tile 128x128/k32, mfma 16x16x32.
// ---------------------------------------------------------------------------
template<int LIMBS>
__global__ __launch_bounds__(256)
void mfma_gemm(const float* __restrict__ A1, int lda1, int K1,
               const float* __restrict__ A2, int lda2, int K2,
               const unsigned short* __restrict__ BL, int ncp,
               const float* __restrict__ bias1, const float* __restrict__ bias2,
               int bsplit,
               float* __restrict__ C, int ldc, int Nn, int mode, int act)
{
  constexpr int ASTR = LIMBS*32 + 8;
  __shared__ __align__(16) unsigned short Alds[128*ASTR];

  const int K = K1 + K2;
  const int ntiles = (K + 31) >> 5;
  const int t = threadIdx.x;
  const int bm0 = blockIdx.x * 128;
  const int col0 = blockIdx.y * 128;
  const int lane = t & 63;
  const int wid  = t >> 6;
  const int wr = (wid >> 1) * 64;
  const int wc = (wid & 1) * 64;
  const int frow = lane & 15;
  const int fk   = (lane >> 4) * 8;

  const int a_row = t >> 1;
  const int a_kh  = (t & 1) * 16;

  f32x4 acc[4][4];
  #pragma unroll
  for (int i = 0; i < 4; ++i)
    #pragma unroll
    for (int j = 0; j < 4; ++j)
      acc[i][j] = (f32x4){0.f, 0.f, 0.f, 0.f};

  for (int kt = 0; kt < ntiles; ++kt){
    const int k0 = kt * 32;
    __syncthreads();
    // ---- stage A: 128 x 32 f32 -> LIMBS bf16 limbs in LDS ----
    {
      float v[16];
      const size_t rr = (size_t)(bm0 + a_row);
      #pragma unroll
      for (int j = 0; j < 16; ++j){
        int ka = k0 + a_kh + j;
        float x = 0.f;
        if (ka < K)
          x = (ka < K1) ? A1[rr*lda1 + ka] : A2[rr*lda2 + (ka - K1)];
        v[j] = x;
      }
      #pragma unroll
      for (int l = 0; l < LIMBS; ++l){
        short8v p0, p1;
        #pragma unroll
        for (int j = 0; j < 8; ++j){
          unsigned short b = f2bf(v[j]); v[j] -= bf2f(b); p0[j] = (short)b;
        }
        #pragma unroll
        for (int j = 0; j < 8; ++j){
          unsigned short b = f2bf(v[8+j]); v[8+j] -= bf2f(b); p1[j] = (short)b;
        }
        *(short8v*)&Alds[a_row*ASTR + l*32 + a_kh]     = p0;
        *(short8v*)&Alds[a_row*ASTR + l*32 + a_kh + 8] = p1;
      }
    }
    __syncthreads();
    // ---- compute: limb pairs lA+lB <= LIMBS-1 ----
    #pragma unroll
    for (int lA = 0; lA < LIMBS; ++lA){
      short8v af[4];
      #pragma unroll
      for (int rb = 0; rb < 4; ++rb)
        af[rb] = *(const short8v*)&Alds[(wr + rb*16 + frow)*ASTR + lA*32 + fk];
      #pragma unroll
      for (int lB = 0; lB < LIMBS - lA; ++lB){
        const unsigned short* bbase =
            BL + ((long long)(lB*ntiles + kt)*ncp)*32;
        short8v bfr[4];
        #pragma unroll
        for (int cb = 0; cb < 4; ++cb){
          int col = col0 + wc + cb*16 + frow;
          bfr[cb] = *(const short8v*)&bbase[(long long)col*32 + fk];
        }
        #pragma unroll
        for (int rb = 0; rb < 4; ++rb)
          #pragma unroll
          for (int cb = 0; cb < 4; ++cb)
            acc[rb][cb] = __builtin_amdgcn_mfma_f32_16x16x32_bf16(
                af[rb], bfr[cb], acc[rb][cb], 0, 0, 0);
      }
    }
  }

  // ---- epilogue ----
  const int lr4 = (lane >> 4) * 4;
  #pragma unroll
  for (int rb = 0; rb < 4; ++rb){
    #pragma unroll
    for (int cb = 0; cb < 4; ++cb){
      const int col = col0 + wc + cb*16 + frow;
      if (col < Nn){
        float bv = 0.f;
        if (bias1) bv = (col < bsplit) ? bias1[col] : bias2[col - bsplit];
        #pragma unroll
        for (int ri = 0; ri < 4; ++ri){
          const size_t row = (size_t)(bm0 + wr + rb*16 + lr4 + ri);
          float v = acc[rb][cb][ri];
          if (mode == 1){
            C[row*ldc + col] += v;
          } else if (mode == 2){
            float a2 = v + C[row*ldc + col] + bv;
            C[row*ldc + col] = (a2 > 0.f) ? a2 : expm1f(a2);
          } else {
            if (bias1) v += bv;
            if (act == 1) v = (v > 0.f) ? v : expm1f(v);
            C[row*ldc + col] = v;
          }
        }
      }
    }
  }
}

// ---------------------------------------------------------------------------
// f32 register-tiled GEMM — only for the tiny final head projections.
// ---------------------------------------------------------------------------
template<int BM, int BN, int BK, int TM, int TN>
__global__ __launch_bounds__(256)
void gemm_tile_kernel(const float* __restrict__ A1, int lda1, int K1,
                      const float* __restrict__ W, const float* __restrict__ bias,
                      float* __restrict__ C, int ldc, int Nn, int act,
                      const float* __restrict__ addx, int addx_ld, int addx_off)
{
  constexpr int LDA = BM + 4;
  constexpr int LDB = BN + 4;
  constexpr int APASS = (BM*BK)/1024;
  constexpr int BPASS = (BN*BK)/1024;
  constexpr int AROWS = 256/(BK/4);
  constexpr int BROWS = 256/(BN/4);
  __shared__ float As[BK*LDA];
  __shared__ float Bs[BK*LDB];
  const int K = K1;
  const int t = threadIdx.x;
  const int bm0 = blockIdx.x * BM;
  const int bn0 = blockIdx.y * BN;
  const int tx = t % 16;
  const int ty = t / 16;
  const int a_r = t / (BK/4);
  const int a_k = 4 * (t % (BK/4));
  const int b_c = t % (BN/4);
  const int b_k = t / (BN/4);

  float ar[APASS][4], br[BPASS][4];
  auto load_tile = [&](int k0){
    #pragma unroll
    for (int p = 0; p < APASS; ++p){
      size_t rr = (size_t)(bm0 + a_r + p*AROWS);
      #pragma unroll
      for (int j = 0; j < 4; ++j){
        int ka = k0 + a_k + j;
        ar[p][j] = (ka < K) ? A1[rr*lda1 + ka] : 0.f;
      }
    }
    #pragma unroll
    for (int p = 0; p < BPASS; ++p){
      int kb = k0 + b_k + p*BROWS;
      #pragma unroll
      for (int j = 0; j < 4; ++j){
        int col = bn0 + 4*b_c + j;
        br[p][j] = (kb < K && col < Nn) ? W[(size_t)kb*Nn + col] : 0.f;
      }
    }
  };
  auto store_tile = [&](){
    #pragma unroll
    for (int p = 0; p < APASS; ++p)
      #pragma unroll
      for (int j = 0; j < 4; ++j)
        As[(a_k + j)*LDA + a_r + p*AROWS] = ar[p][j];
    #pragma unroll
    for (int p = 0; p < BPASS; ++p)
      *(float4*)&Bs[(b_k + p*BROWS)*LDB + 4*b_c] =
          make_float4(br[p][0], br[p][1], br[p][2], br[p][3]);
  };

  float acc[TM][TN];
  #pragma unroll
  for (int i = 0; i < TM; ++i)
    #pragma unroll
    for (int j = 0; j < TN; ++j) acc[i][j] = 0.f;

  auto compute_tile = [&](){
    #pragma unroll
    for (int kk = 0; kk < BK; ++kk){
      float a[TM], b[TN];
      #pragma unroll
      for (int iq = 0; iq < TM/4; ++iq){
        float4 v = *(const float4*)&As[kk*LDA + iq*(BM/2) + 4*ty];
        a[iq*4+0] = v.x; a[iq*4+1] = v.y; a[iq*4+2] = v.z; a[iq*4+3] = v.w;
      }
      #pragma unroll
      for (int jq = 0; jq < TN/4; ++jq){
        float4 v = *(const float4*)&Bs[kk*LDB + jq*(BN/2) + 4*tx];
        b[jq*4+0] = v.x; b[jq*4+1] = v.y; b[jq*4+2] = v.z; b[jq*4+3] = v.w;
      }
      #pragma unroll
      for (int i = 0; i < TM; ++i)
        #pragma unroll
        for (int j = 0; j < TN; ++j)
          acc[i][j] += a[i]*b[j];
    }
  };

  const int ntiles = (K + BK - 1)/BK;
  load_tile(0); store_tile(); __syncthreads();
  for (int tt = 1; tt < ntiles; ++tt){
    load_tile(tt*BK);
    compute_tile();
    __syncthreads();
    store_tile();
    __syncthreads();
  }
  compute_tile();

  #pragma unroll
  for (int i = 0; i < TM; ++i){
    size_t row = (size_t)(bm0 + (i/4)*(BM/2) + 4*ty + (i%4));
    #pragma unroll
    for (int j = 0; j < TN; ++j){
      int col = bn0 + (j/4)*(BN/2) + 4*tx + (j%4);
      if (col < Nn){
        float v = acc[i][j];
        if (bias) v += bias[col];
        if (act == 1) v = (v > 0.f) ? v : expm1f(v);
        if (addx) v += addx[row*addx_ld + addx_off + col];
        C[row*ldc + col] = v;
      }
    }
  }
}

// ---------------------------------------------------------------------------
// kNN + aggregation, 4-wave split-scan. Block = 256 thr handles 64 rows of one
// graph; wave w scans neighbor chunk [256w,256w+256); chunk top-8s merged in
// chunk order (selection bitwise-identical to full sequential scan); weights +
// mean/max aggregation distributed across all 256 threads.
// ---------------------------------------------------------------------------
__global__ __launch_bounds__(256)
void knn_agg_kernel(const float* __restrict__ proj, float* __restrict__ agg)
{
  __shared__ float4 ssv[GS];            // 16 KB
  __shared__ float  sn2[GS];            // 4 KB
  __shared__ float  cd[4][64][KNN];     // 8 KB chunk top-8 dists
  __shared__ int    ci[4][64][KNN];     // 8 KB chunk top-8 idx
  __shared__ float  wl[64][KNN];        // 2 KB weights

  const int g   = blockIdx.x >> 4;
  const int seg = blockIdx.x & 15;
  const int t = threadIdx.x;
  const int wave = t >> 6;
  const int lane = t & 63;

  const float* pg = proj + (size_t)g*GS*PRJW;
  for (int i = t; i < GS; i += 256){
    float4 v = *(const float4*)(pg + (size_t)i*PRJW + PROP);
    ssv[i] = v;
    sn2[i] = v.x*v.x + v.y*v.y + v.z*v.z + v.w*v.w;
  }
  __syncthreads();

  const int i = seg*64 + lane;          // my row within graph
  float4 sv = ssv[i];
  float myn2 = sn2[i];
  float si0 = sv.x, si1 = sv.y, si2 = sv.z, si3 = sv.w;

  float bd[KNN]; int bi[KNN];
  #pragma unroll
  for (int k = 0; k < KNN; ++k){ bd[k] = 1e30f; bi[k] = 0; }

  // scan my wave's chunk
  const int jbeg = wave * 256;
  for (int j0 = jbeg; j0 < jbeg + 256; j0 += 8){
    float dv[8];
    #pragma unroll
    for (int u = 0; u < 8; ++u){
      float4 sj = ssv[j0+u];
      float dot = si0*sj.x + si1*sj.y + si2*sj.z + si3*sj.w;
      dv[u] = myn2 + sn2[j0+u] - 2.f*dot;
    }
    float mn = fminf(fminf(fminf(dv[0],dv[1]), fminf(dv[2],dv[3])),
                     fminf(fminf(dv[4],dv[5]), fminf(dv[6],dv[7])));
    if (mn < bd[KNN-1]){
      #pragma unroll
      for (int u = 0; u < 8; ++u){
        float d2 = dv[u];
        if (d2 < bd[KNN-1]){
          int j = j0 + u;
          #pragma unroll
          for (int q = KNN-1; q >= 1; --q){
            bool cq = d2 < bd[q];
            bool cp = d2 < bd[q-1];
            float nv = cp ? bd[q-1] : d2;
            int   ni = cp ? bi[q-1] : j;
            if (cq){ bd[q] = nv; bi[q] = ni; }
          }
          if (d2 < bd[0]){ bd[0] = d2; bi[0] = j; }
        }
      }
    }
  }
  #pragma unroll
  for (int k = 0; k < KNN; ++k){ cd[wave][lane][k] = bd[k]; ci[wave][lane][k] = bi[k]; }
  __syncthreads();

  // wave 0 merges chunks 1..3 (in order -> identical tie-break semantics)
  if (wave == 0){
    #pragma unroll
    for (int c = 1; c < 4; ++c){
      #pragma unroll
      for (int k = 0; k < KNN; ++k){
        float d2 = cd[c][lane][k];
        if (d2 < bd[KNN-1]){
          int j = ci[c][lane][k];
          #pragma unroll
          for (int q = KNN-1; q >= 1; --q){
            bool cq = d2 < bd[q];
            bool cp = d2 < bd[q-1];
            float nv = cp ? bd[q-1] : d2;
            int   ni = cp ? bi[q-1] : j;
            if (cq){ bd[q] = nv; bi[q] = ni; }
          }
          if (d2 < bd[0]){ bd[0] = d2; bi[0] = j; }
        }
      }
    }
    #pragma unroll
    for (int k = 0; k < KNN; ++k){ cd[0][lane][k] = bd[k]; ci[0][lane][k] = bi[k]; }
  }
  __syncthreads();

  // weights: thread handles (row r = t&63, k = t>>6 and k+4)
  {
    const int r = t & 63;
    float4 si_ = ssv[seg*64 + r];
    #pragma unroll
    for (int kx = (t >> 6); kx < KNN; kx += 4){
      int j = ci[0][r][kx];
      float4 sj = ssv[j];
      float d0 = si_.x - sj.x, d1 = si_.y - sj.y;
      float d2_ = si_.z - sj.z, d3 = si_.w - sj.w;
      float dd = d0*d0 + d1*d1 + d2_*d2_ + d3*d3;
      wl[r][kx] = expf(-10.f*dd);
    }
  }
  __syncthreads();

  // aggregation: thread = (row r, prop-octet q); bitwise-same k-ascending order
  {
    const int r = t & 63;
    const int q = t >> 6;
    float msum[8], mmax[8];
    #pragma unroll
    for (int u = 0; u < 8; ++u){ msum[u] = 0.f; mmax[u] = -1e30f; }
    #pragma unroll
    for (int k = 0; k < KNN; ++k){
      int j = ci[0][r][k];
      float wk = wl[r][k];
      const float* hr = pg + (size_t)j*PRJW + q*8;
      float4 h0 = *(const float4*)(hr);
      float4 h1 = *(const float4*)(hr + 4);
      float v0 = h0.x*wk, v1 = h0.y*wk, v2 = h0.z*wk, v3 = h0.w*wk;
      float v4 = h1.x*wk, v5 = h1.y*wk, v6 = h1.z*wk, v7 = h1.w*wk;
      msum[0]+=v0; mmax[0]=fmaxf(mmax[0],v0);
      msum[1]+=v1; mmax[1]=fmaxf(mmax[1],v1);
      msum[2]+=v2; mmax[2]=fmaxf(mmax[2],v2);
      msum[3]+=v3; mmax[3]=fmaxf(mmax[3],v3);
      msum[4]+=v4; mmax[4]=fmaxf(mmax[4],v4);
      msum[5]+=v5; mmax[5]=fmaxf(mmax[5],v5);
      msum[6]+=v6; mmax[6]=fmaxf(mmax[6],v6);
      msum[7]+=v7; mmax[7]=fmaxf(mmax[7],v7);
    }
    float* arow = agg + ((size_t)g*GS + seg*64 + r)*AGGW;
    #pragma unroll
    for (int u = 0; u < 8; ++u){
      arow[q*8 + u]        = msum[u]*(1.f/KNN);
      arow[PROP + q*8 + u] = mmax[u];
    }
  }
}

// ---------------------------------------------------------------------------
extern "C" void kernel_launch(void* const* d_in, const int* in_sizes, int n_in,
                              void* d_out, int out_size, void* d_ws, size_t ws_size,
                              hipStream_t stream)
{
  const float* x     = (const float*)d_in[0];
  const float* n0W1  = (const float*)d_in[2];
  const float* n0b1  = (const float*)d_in[3];
  const float* n0W23 = (const float*)d_in[4];
  const float* n0b23 = (const float*)d_in[5];
  const float* n0W4  = (const float*)d_in[6];
  const float* n0b4  = (const float*)d_in[7];
  const float* cWh   = (const float*)d_in[8];
  const float* cbh   = (const float*)d_in[9];
  const float* cWs   = (const float*)d_in[10];
  const float* cbs   = (const float*)d_in[11];
  const float* cWo   = (const float*)d_in[12];
  const float* cbo   = (const float*)d_in[13];
  const float* HW1   = (const float*)d_in[14];
  const float* Hb1   = (const float*)d_in[15];
  const float* HW23  = (const float*)d_in[16];
  const float* Hb23  = (const float*)d_in[17];
  const float* Wid   = (const float*)d_in[18];
  const float* bid   = (const float*)d_in[19];
  const float* Wreg  = (const float*)d_in[20];
  const float* breg  = (const float*)d_in[21];
  const float* Wch   = (const float*)d_in[22];
  const float* bch   = (const float*)d_in[23];
  float* out = (float*)d_out;
  (void)in_sizes; (void)n_in; (void)out_size; (void)ws_size;

  // ---- workspace layout (~163 MB; ws >= 188 MB proven in round 1) ----
  char* wsp = (char*)d_ws;
  float* P     = (float*)(wsp);                  // N x 128
  float* Q     = (float*)(wsp + 33554432);       // N x 128
  float* hacc  = (float*)(wsp + 67108864);       // N x 252 (s0 uses cols 0..125)
  float* projb = (float*)(wsp + 133169152);      // N x 36
  float* aggb  = (float*)(wsp + 142606336);      // N x 64
  unsigned short* pool = (unsigned short*)(wsp + 159383552);  // limb pool

  // ---- build weight descriptors ----
  WDescs DS{};
  long long woff = 0; int nd = 0;
  auto addm = [&](const float* s1, const float* s2, int ld1, int ld2,
                  int nc1, int K, int Nn, int limbs)->long long {
    int ntiles = (K + 31) >> 5;
    int ncp = (Nn + 127) & ~127;
    long long o = woff;
    DS.d[nd].s1 = s1; DS.d[nd].s2 = s2; DS.d[nd].ld1 = ld1; DS.d[nd].ld2 = ld2;
    DS.d[nd].nc1 = nc1; DS.d[nd].K = K; DS.d[nd].Nn = Nn; DS.d[nd].limbs = limbs;
    DS.d[nd].dstoff = o; nd++;
    woff += (long long)limbs * ntiles * ncp * 32;
    return o;
  };
  // embedding (3-limb)
  long long o_e1 = addm(n0W1, nullptr, WIDTH, 0, WIDTH, IN_DIM, WIDTH, 3);
  long long o_e2 = addm(n0W23, nullptr, WIDTH, 0, WIDTH, WIDTH, WIDTH, 3);
  long long o_e3 = addm(n0W23 + WIDTH*WIDTH, nullptr, WIDTH, 0, WIDTH, WIDTH, WIDTH, 3);
  long long o_e4 = addm(n0W4, nullptr, EMB, 0, EMB, WIDTH, EMB, 3);
  // conv projections merged h|s and Wo (3-limb), pidx 0..9
  long long o_pj[10], o_wo[10];
  for (int p = 0; p < 10; ++p){
    o_pj[p] = addm(cWh + (size_t)p*EMB*PROP, cWs + (size_t)p*EMB*SPACE,
                   PROP, SPACE, PROP, EMB, PRJW, 3);
    o_wo[p] = addm(cWo + (size_t)p*CATW*EMB, nullptr, EMB, 0, EMB, CATW, EMB, 3);
  }
  // head layer-1 slices (1-limb): s0 head0; s1 heads1+2 merged (Nn=252)
  long long o_h0[6], o_h12[6];
  for (int cv = -1; cv < NCONV; ++cv){
    int r0 = (cv < 0) ? 0 : IN_DIM + cv*EMB;
    int Ks = (cv < 0) ? IN_DIM : EMB;
    o_h0[cv+1] = addm(HW1 + (size_t)r0*WIDTH, nullptr, WIDTH, 0, WIDTH, Ks, WIDTH, 1);
    o_h12[cv+1] = addm(HW1 + (size_t)1*FEAT*WIDTH + (size_t)r0*WIDTH,
                       HW1 + (size_t)2*FEAT*WIDTH + (size_t)r0*WIDTH,
                       WIDTH, WIDTH, WIDTH, Ks, 2*WIDTH, 1);
  }
  // head hidden layers (1-limb)
  long long o_hh[6];
  for (int q = 0; q < 6; ++q)
    o_hh[q] = addm(HW23 + (size_t)q*WIDTH*WIDTH, nullptr, WIDTH, 0, WIDTH, WIDTH, WIDTH, 1);

  hipLaunchKernelGGL(conv_weights_kernel, dim3(48, NMAT), dim3(256), 0, stream, DS, pool);

  auto gemmM = [&](int limbs, const float* A1, int lda1, int K1,
                   const float* A2, int lda2, int K2,
                   long long boff, const float* b1, const float* b2, int bsplit,
                   float* C, int ldc, int Nn, int mode, int act){
    int ncp = (Nn + 127) & ~127;
    dim3 grid(N_TOT/128, ncp/128);
    if (limbs == 3)
      hipLaunchKernelGGL((mfma_gemm<3>), grid, dim3(256), 0, stream,
          A1, lda1, K1, A2, lda2, K2, pool + boff, ncp, b1, b2, bsplit,
          C, ldc, Nn, mode, act);
    else
      hipLaunchKernelGGL((mfma_gemm<1>), grid, dim3(256), 0, stream,
          A1, lda1, K1, A2, lda2, K2, pool + boff, ncp, b1, b2, bsplit,
          C, ldc, Nn, mode, act);
  };
  auto gemmS = [&](const float* A1, int lda1, int K1,
                   const float* W, const float* b,
                   float* C, int ldc, int Nn, int act,
                   const float* addx, int addx_ld, int addx_off){
    dim3 grid(N_TOT/64, (Nn+63)/64);
    hipLaunchKernelGGL((gemm_tile_kernel<64,64,32,4,4>), grid, dim3(256), 0, stream,
        A1, lda1, K1, W, b, C, ldc, Nn, act, addx, addx_ld, addx_off);
  };
  const int BIG = 1 << 30;

  for (int s = 0; s < 2; ++s){
    // ---- embedding MLP -> P ----
    gemmM(3, x, IN_DIM, IN_DIM, nullptr,0,0, o_e1, n0b1, nullptr, BIG, Q, EMB, WIDTH, 0, 1);
    gemmM(3, Q, EMB, WIDTH, nullptr,0,0, o_e2, n0b23, nullptr, BIG, P, EMB, WIDTH, 0, 1);
    gemmM(3, P, EMB, WIDTH, nullptr,0,0, o_e3, n0b23 + WIDTH, nullptr, BIG, Q, EMB, WIDTH, 0, 1);
    gemmM(3, Q, EMB, WIDTH, nullptr,0,0, o_e4, n0b4, nullptr, BIG, P, EMB, EMB, 0, 0);

    // ---- head layer-1 init ----
    if (s == 0)
      gemmM(1, x, IN_DIM, IN_DIM, nullptr,0,0, o_h0[0], nullptr, nullptr, BIG,
            hacc, 252, WIDTH, 0, 0);
    else
      gemmM(1, x, IN_DIM, IN_DIM, nullptr,0,0, o_h12[0], nullptr, nullptr, BIG,
            hacc, 252, 2*WIDTH, 0, 0);

    float* cur = P; float* nxt = Q;
    for (int cv = 0; cv < NCONV; ++cv){
      int pidx = s*NCONV + cv;
      // h|s projections -> projb (split bias)
      gemmM(3, cur, EMB, EMB, nullptr,0,0, o_pj[pidx],
            cbh + pidx*PROP, cbs + pidx*SPACE, PROP,
            projb, PRJW, PRJW, 0, 0);
      // kNN + aggregate -> aggb
      hipLaunchKernelGGL(knn_agg_kernel, dim3(NG*16), dim3(256), 0, stream,
                         projb, aggb);
      // o_cv = [cur | agg] @ Wo + bo -> nxt
      gemmM(3, cur, EMB, EMB, aggb, AGGW, AGGW, o_wo[pidx],
            cbo + pidx*EMB, nullptr, BIG, nxt, EMB, EMB, 0, 0);
      // hacc += o_cv @ W1 slice; last conv fuses bias+ELU
      int mode = (cv == NCONV-1) ? 2 : 1;
      if (s == 0)
        gemmM(1, nxt, EMB, EMB, nullptr,0,0, o_h0[cv+1],
              (mode==2) ? Hb1 : nullptr, nullptr, BIG,
              hacc, 252, WIDTH, mode, 0);
      else
        gemmM(1, nxt, EMB, EMB, nullptr,0,0, o_h12[cv+1],
              (mode==2) ? Hb1 + WIDTH : nullptr, nullptr, BIG,
              hacc, 252, 2*WIDTH, mode, 0);
      float* tmp = cur; cur = nxt; nxt = tmp;
    }

    // ---- head finish (P free as scratch) ----
    auto finish_head = [&](int hidx, float* ha, float* dst, int dst_ld, int out_dim,
                           const float* Wl, const float* bl,
                           const float* addx, int addx_ld, int addx_off){
      gemmM(1, ha, 252, WIDTH, nullptr,0,0, o_hh[hidx*2+0],
            Hb23 + (hidx*2+0)*WIDTH, nullptr, BIG, P, EMB, WIDTH, 0, 1);
      gemmM(1, P, EMB, WIDTH, nullptr,0,0, o_hh[hidx*2+1],
            Hb23 + (hidx*2+1)*WIDTH, nullptr, BIG, ha, 252, WIDTH, 0, 1);
      gemmS(ha, 252, WIDTH, Wl, bl, dst, dst_ld, out_dim, 0,
            addx, addx_ld, addx_off);
    };

    if (s == 0){
      finish_head(0, hacc, out, 8, 8, Wid, bid, nullptr, 0, 0);
    } else {
      finish_head(1, hacc, out + (size_t)N_TOT*8, 4, 4, Wreg, breg, x, IN_DIM, 1);
      finish_head(2, hacc + WIDTH, out + (size_t)N_TOT*12, 1, 1, Wch, bch, nullptr, 0, 0);
    }
  }
}

// Round 10
// 2549.853 us; speedup vs baseline: 8.4242x; 1.2421x over previous
//
#include <hip/hip_runtime.h>
#include <hip/hip_bf16.h>
#include <cstdint>

#define N_TOT 65536
#define NG 64
#define GS 1024
#define IN_DIM 34
#define WIDTH 126
#define EMB 128
#define PROP 32
#define SPACE 4
#define KNN 8
#define NCONV 5
#define FEAT (IN_DIM + NCONV*EMB)   /* 674 */
#define FLDB 680                    /* featb bf16 leading dim (16B-aligned rows) */
#define CATW (EMB + 2*PROP)         /* 192 */
#define AGGW (2*PROP)               /* 64 */
#define PRJW 36                     /* h(32) | s(4) */

typedef __attribute__((ext_vector_type(8))) short short8v;
typedef __attribute__((ext_vector_type(4))) float f32x4;

__device__ __forceinline__ unsigned short f2bf(float f){
  unsigned int u = __float_as_uint(f);
  unsigned int r = (u + 0x7FFFu + ((u >> 16) & 1u)) >> 16;
  return (unsigned short)r;
}
__device__ __forceinline__ float bf2f(unsigned short b){
  return __uint_as_float(((unsigned int)b) << 16);
}

// ---------------------------------------------------------------------------
// Weight pre-conversion: f32 matrix (optionally two col-concatenated sources)
// -> bf16 limb pool, layout [limb][ktile][col(<ncolpad)][k32], zero-padded.
// ---------------------------------------------------------------------------
struct WDesc {
  const float* s1; const float* s2;
  int ld1, ld2, nc1, K, Nn, limbs;
  long long dstoff;
};
#define NMAT 32
struct WDescs { WDesc d[NMAT]; };

__global__ __launch_bounds__(256)
void conv_weights_kernel(WDescs DS, unsigned short* __restrict__ pool)
{
  int m = blockIdx.y;
  WDesc d = DS.d[m];
  if (d.K == 0) return;
  int ntiles = (d.K + 31) >> 5;
  int ncp = (d.Nn + 127) & ~127;
  int nchunk = ncp >> 5;
  int kt = blockIdx.x / nchunk;
  int cc = blockIdx.x % nchunk;
  if (kt >= ntiles) return;
  int t = threadIdx.x;
  int kk = t & 31;
  int k = kt*32 + kk;
  for (int c = (t >> 5); c < 32; c += 8){
    int col = cc*32 + c;
    float v = 0.f;
    if (k < d.K && col < d.Nn)
      v = (col < d.nc1) ? d.s1[(size_t)k*d.ld1 + col]
                        : d.s2[(size_t)k*d.ld2 + (col - d.nc1)];
    for (int l = 0; l < d.limbs; ++l){
      unsigned short b = f2bf(v); v -= bf2f(b);
      pool[d.dstoff + ((long long)(l*ntiles + kt)*ncp + col)*32 + kk] = b;
    }
  }
}

// ---------------------------------------------------------------------------
// x (f32 N x 34) -> featb bf16 cols 0..33
// ---------------------------------------------------------------------------
__global__ __launch_bounds__(256)
void xconv_kernel(const float* __restrict__ x, unsigned short* __restrict__ featb)
{
  int idx = blockIdx.x*256 + threadIdx.x;
  if (idx < N_TOT*IN_DIM){
    int r = idx / IN_DIM, c = idx - r*IN_DIM;
    featb[(size_t)r*FLDB + c] = f2bf(x[idx]);
  }
}

// ---------------------------------------------------------------------------
// MFMA bf16 GEMM, LIMBS-limb f32 emulation. ABF=1: A is already bf16 (ushort,
// LIMBS must be 1) — staged without conversion. B fragments read directly from
// the pre-converted limb pool. mode: 0 C=act(A@W+bias), 1 C+=A@W,
// 2 C=elu(C+A@W+bias). bias split at bsplit. Optional bf16 secondary output Cb
// (mode 0 only). Block 256 thr = 4 waves (2x2), tile 128x128/k32.
// ---------------------------------------------------------------------------
template<int LIMBS, int ABF>
__global__ __launch_bounds__(256)
void mfma_gemm(const void* __restrict__ A1v, int lda1, int K1,
               const float* __restrict__ A2, int lda2, int K2,
               const unsigned short* __restrict__ BL, int ncp,
               const float* __restrict__ bias1, const float* __restrict__ bias2,
               int bsplit,
               float* __restrict__ C, int ldc, int Nn, int mode, int act,
               unsigned short* __restrict__ Cb, int ldcb)
{
  constexpr int ASTR = LIMBS*32 + 8;
  __shared__ __align__(16) unsigned short Alds[128*ASTR];
  const float* A1 = (const float*)A1v;
  const unsigned short* Ab = (const unsigned short*)A1v;

  const int K = K1 + K2;
  const int ntiles = (K + 31) >> 5;
  const int t = threadIdx.x;
  const int bm0 = blockIdx.x * 128;
  const int col0 = blockIdx.y * 128;
  const int lane = t & 63;
  const int wid  = t >> 6;
  const int wr = (wid >> 1) * 64;
  const int wc = (wid & 1) * 64;
  const int frow = lane & 15;
  const int fk   = (lane >> 4) * 8;

  const int a_row = t >> 1;
  const int a_kh  = (t & 1) * 16;

  f32x4 acc[4][4];
  #pragma unroll
  for (int i = 0; i < 4; ++i)
    #pragma unroll
    for (int j = 0; j < 4; ++j)
      acc[i][j] = (f32x4){0.f, 0.f, 0.f, 0.f};

  for (int kt = 0; kt < ntiles; ++kt){
    const int k0 = kt * 32;
    __syncthreads();
    if (ABF){
      // ---- stage A: already bf16, no conversion ----
      const size_t rr = (size_t)(bm0 + a_row);
      short8v p0, p1;
      if (k0 + 31 < K){
        p0 = *(const short8v*)&Ab[rr*lda1 + k0 + a_kh];
        p1 = *(const short8v*)&Ab[rr*lda1 + k0 + a_kh + 8];
      } else {
        #pragma unroll
        for (int j = 0; j < 8; ++j){
          int ka = k0 + a_kh + j;
          p0[j] = (ka < K) ? (short)Ab[rr*lda1 + ka] : (short)0;
        }
        #pragma unroll
        for (int j = 0; j < 8; ++j){
          int ka = k0 + a_kh + 8 + j;
          p1[j] = (ka < K) ? (short)Ab[rr*lda1 + ka] : (short)0;
        }
      }
      *(short8v*)&Alds[a_row*ASTR + a_kh]     = p0;
      *(short8v*)&Alds[a_row*ASTR + a_kh + 8] = p1;
    } else {
      // ---- stage A: f32 -> LIMBS bf16 limbs ----
      float v[16];
      const size_t rr = (size_t)(bm0 + a_row);
      #pragma unroll
      for (int j = 0; j < 16; ++j){
        int ka = k0 + a_kh + j;
        float xv = 0.f;
        if (ka < K)
          xv = (ka < K1) ? A1[rr*lda1 + ka] : A2[rr*lda2 + (ka - K1)];
        v[j] = xv;
      }
      #pragma unroll
      for (int l = 0; l < LIMBS; ++l){
        short8v p0, p1;
        #pragma unroll
        for (int j = 0; j < 8; ++j){
          unsigned short b = f2bf(v[j]); v[j] -= bf2f(b); p0[j] = (short)b;
        }
        #pragma unroll
        for (int j = 0; j < 8; ++j){
          unsigned short b = f2bf(v[8+j]); v[8+j] -= bf2f(b); p1[j] = (short)b;
        }
        *(short8v*)&Alds[a_row*ASTR + l*32 + a_kh]     = p0;
        *(short8v*)&Alds[a_row*ASTR + l*32 + a_kh + 8] = p1;
      }
    }
    __syncthreads();
    // ---- compute: limb pairs lA+lB <= LIMBS-1 ----
    #pragma unroll
    for (int lA = 0; lA < LIMBS; ++lA){
      short8v af[4];
      #pragma unroll
      for (int rb = 0; rb < 4; ++rb)
        af[rb] = *(const short8v*)&Alds[(wr + rb*16 + frow)*ASTR + lA*32 + fk];
      #pragma unroll
      for (int lB = 0; lB < LIMBS - lA; ++lB){
        const unsigned short* bbase =
            BL + ((long long)(lB*ntiles + kt)*ncp)*32;
        short8v bfr[4];
        #pragma unroll
        for (int cb = 0; cb < 4; ++cb){
          int col = col0 + wc + cb*16 + frow;
          bfr[cb] = *(const short8v*)&bbase[(long long)col*32 + fk];
        }
        #pragma unroll
        for (int rb = 0; rb < 4; ++rb)
          #pragma unroll
          for (int cb = 0; cb < 4; ++cb)
            acc[rb][cb] = __builtin_amdgcn_mfma_f32_16x16x32_bf16(
                af[rb], bfr[cb], acc[rb][cb], 0, 0, 0);
      }
    }
  }

  // ---- epilogue ----
  const int lr4 = (lane >> 4) * 4;
  #pragma unroll
  for (int rb = 0; rb < 4; ++rb){
    #pragma unroll
    for (int cb = 0; cb < 4; ++cb){
      const int col = col0 + wc + cb*16 + frow;
      if (col < Nn){
        float bv = 0.f;
        if (bias1) bv = (col < bsplit) ? bias1[col] : bias2[col - bsplit];
        #pragma unroll
        for (int ri = 0; ri < 4; ++ri){
          const size_t row = (size_t)(bm0 + wr + rb*16 + lr4 + ri);
          float v = acc[rb][cb][ri];
          if (mode == 1){
            C[row*ldc + col] += v;
          } else if (mode == 2){
            float a2 = v + C[row*ldc + col] + bv;
            C[row*ldc + col] = (a2 > 0.f) ? a2 : expm1f(a2);
          } else {
            if (bias1) v += bv;
            if (act == 1) v = (v > 0.f) ? v : expm1f(v);
            C[row*ldc + col] = v;
            if (Cb) Cb[row*(size_t)ldcb + col] = f2bf(v);
          }
        }
      }
    }
  }
}

// ---------------------------------------------------------------------------
// f32 register-tiled GEMM — only for the tiny final head projections.
// ---------------------------------------------------------------------------
template<int BM, int BN, int BK, int TM, int TN>
__global__ __launch_bounds__(256)
void gemm_tile_kernel(const float* __restrict__ A1, int lda1, int K1,
                      const float* __restrict__ W, const float* __restrict__ bias,
                      float* __restrict__ C, int ldc, int Nn, int act,
                      const float* __restrict__ addx, int addx_ld, int addx_off)
{
  constexpr int LDA = BM + 4;
  constexpr int LDB = BN + 4;
  constexpr int APASS = (BM*BK)/1024;
  constexpr int BPASS = (BN*BK)/1024;
  constexpr int AROWS = 256/(BK/4);
  constexpr int BROWS = 256/(BN/4);
  __shared__ float As[BK*LDA];
  __shared__ float Bs[BK*LDB];
  const int K = K1;
  const int t = threadIdx.x;
  const int bm0 = blockIdx.x * BM;
  const int bn0 = blockIdx.y * BN;
  const int tx = t % 16;
  const int ty = t / 16;
  const int a_r = t / (BK/4);
  const int a_k = 4 * (t % (BK/4));
  const int b_c = t % (BN/4);
  const int b_k = t / (BN/4);

  float ar[APASS][4], br[BPASS][4];
  auto load_tile = [&](int k0){
    #pragma unroll
    for (int p = 0; p < APASS; ++p){
      size_t rr = (size_t)(bm0 + a_r + p*AROWS);
      #pragma unroll
      for (int j = 0; j < 4; ++j){
        int ka = k0 + a_k + j;
        ar[p][j] = (ka < K) ? A1[rr*lda1 + ka] : 0.f;
      }
    }
    #pragma unroll
    for (int p = 0; p < BPASS; ++p){
      int kb = k0 + b_k + p*BROWS;
      #pragma unroll
      for (int j = 0; j < 4; ++j){
        int col = bn0 + 4*b_c + j;
        br[p][j] = (kb < K && col < Nn) ? W[(size_t)kb*Nn + col] : 0.f;
      }
    }
  };
  auto store_tile = [&](){
    #pragma unroll
    for (int p = 0; p < APASS; ++p)
      #pragma unroll
      for (int j = 0; j < 4; ++j)
        As[(a_k + j)*LDA + a_r + p*AROWS] = ar[p][j];
    #pragma unroll
    for (int p = 0; p < BPASS; ++p)
      *(float4*)&Bs[(b_k + p*BROWS)*LDB + 4*b_c] =
          make_float4(br[p][0], br[p][1], br[p][2], br[p][3]);
  };

  float acc[TM][TN];
  #pragma unroll
  for (int i = 0; i < TM; ++i)
    #pragma unroll
    for (int j = 0; j < TN; ++j) acc[i][j] = 0.f;

  auto compute_tile = [&](){
    #pragma unroll
    for (int kk = 0; kk < BK; ++kk){
      float a[TM], b[TN];
      #pragma unroll
      for (int iq = 0; iq < TM/4; ++iq){
        float4 v = *(const float4*)&As[kk*LDA + iq*(BM/2) + 4*ty];
        a[iq*4+0] = v.x; a[iq*4+1] = v.y; a[iq*4+2] = v.z; a[iq*4+3] = v.w;
      }
      #pragma unroll
      for (int jq = 0; jq < TN/4; ++jq){
        float4 v = *(const float4*)&Bs[kk*LDB + jq*(BN/2) + 4*tx];
        b[jq*4+0] = v.x; b[jq*4+1] = v.y; b[jq*4+2] = v.z; b[jq*4+3] = v.w;
      }
      #pragma unroll
      for (int i = 0; i < TM; ++i)
        #pragma unroll
        for (int j = 0; j < TN; ++j)
          acc[i][j] += a[i]*b[j];
    }
  };

  const int ntiles = (K + BK - 1)/BK;
  load_tile(0); store_tile(); __syncthreads();
  for (int tt = 1; tt < ntiles; ++tt){
    load_tile(tt*BK);
    compute_tile();
    __syncthreads();
    store_tile();
    __syncthreads();
  }
  compute_tile();

  #pragma unroll
  for (int i = 0; i < TM; ++i){
    size_t row = (size_t)(bm0 + (i/4)*(BM/2) + 4*ty + (i%4));
    #pragma unroll
    for (int j = 0; j < TN; ++j){
      int col = bn0 + (j/4)*(BN/2) + 4*tx + (j%4);
      if (col < Nn){
        float v = acc[i][j];
        if (bias) v += bias[col];
        if (act == 1) v = (v > 0.f) ? v : expm1f(v);
        if (addx) v += addx[row*addx_ld + addx_off + col];
        C[row*ldc + col] = v;
      }
    }
  }
}

// ---------------------------------------------------------------------------
// kNN + aggregation, 4-wave split-scan (unchanged from round 9).
// ---------------------------------------------------------------------------
__global__ __launch_bounds__(256)
void knn_agg_kernel(const float* __restrict__ proj, float* __restrict__ agg)
{
  __shared__ float4 ssv[GS];
  __shared__ float  sn2[GS];
  __shared__ float  cd[4][64][KNN];
  __shared__ int    ci[4][64][KNN];
  __shared__ float  wl[64][KNN];

  const int g   = blockIdx.x >> 4;
  const int seg = blockIdx.x & 15;
  const int t = threadIdx.x;
  const int wave = t >> 6;
  const int lane = t & 63;

  const float* pg = proj + (size_t)g*GS*PRJW;
  for (int i = t; i < GS; i += 256){
    float4 v = *(const float4*)(pg + (size_t)i*PRJW + PROP);
    ssv[i] = v;
    sn2[i] = v.x*v.x + v.y*v.y + v.z*v.z + v.w*v.w;
  }
  __syncthreads();

  const int i = seg*64 + lane;
  float4 sv = ssv[i];
  float myn2 = sn2[i];
  float si0 = sv.x, si1 = sv.y, si2 = sv.z, si3 = sv.w;

  float bd[KNN]; int bi[KNN];
  #pragma unroll
  for (int k = 0; k < KNN; ++k){ bd[k] = 1e30f; bi[k] = 0; }

  const int jbeg = wave * 256;
  for (int j0 = jbeg; j0 < jbeg + 256; j0 += 8){
    float dv[8];
    #pragma unroll
    for (int u = 0; u < 8; ++u){
      float4 sj = ssv[j0+u];
      float dot = si0*sj.x + si1*sj.y + si2*sj.z + si3*sj.w;
      dv[u] = myn2 + sn2[j0+u] - 2.f*dot;
    }
    float mn = fminf(fminf(fminf(dv[0],dv[1]), fminf(dv[2],dv[3])),
                     fminf(fminf(dv[4],dv[5]), fminf(dv[6],dv[7])));
    if (mn < bd[KNN-1]){
      #pragma unroll
      for (int u = 0; u < 8; ++u){
        float d2 = dv[u];
        if (d2 < bd[KNN-1]){
          int j = j0 + u;
          #pragma unroll
          for (int q = KNN-1; q >= 1; --q){
            bool cq = d2 < bd[q];
            bool cp = d2 < bd[q-1];
            float nv = cp ? bd[q-1] : d2;
            int   ni = cp ? bi[q-1] : j;
            if (cq){ bd[q] = nv; bi[q] = ni; }
          }
          if (d2 < bd[0]){ bd[0] = d2; bi[0] = j; }
        }
      }
    }
  }
  #pragma unroll
  for (int k = 0; k < KNN; ++k){ cd[wave][lane][k] = bd[k]; ci[wave][lane][k] = bi[k]; }
  __syncthreads();

  if (wave == 0){
    #pragma unroll
    for (int c = 1; c < 4; ++c){
      #pragma unroll
      for (int k = 0; k < KNN; ++k){
        float d2 = cd[c][lane][k];
        if (d2 < bd[KNN-1]){
          int j = ci[c][lane][k];
          #pragma unroll
          for (int q = KNN-1; q >= 1; --q){
            bool cq = d2 < bd[q];
            bool cp = d2 < bd[q-1];
            float nv = cp ? bd[q-1] : d2;
            int   ni = cp ? bi[q-1] : j;
            if (cq){ bd[q] = nv; bi[q] = ni; }
          }
          if (d2 < bd[0]){ bd[0] = d2; bi[0] = j; }
        }
      }
    }
    #pragma unroll
    for (int k = 0; k < KNN; ++k){ cd[0][lane][k] = bd[k]; ci[0][lane][k] = bi[k]; }
  }
  __syncthreads();

  {
    const int r = t & 63;
    float4 si_ = ssv[seg*64 + r];
    #pragma unroll
    for (int kx = (t >> 6); kx < KNN; kx += 4){
      int j = ci[0][r][kx];
      float4 sj = ssv[j];
      float d0 = si_.x - sj.x, d1 = si_.y - sj.y;
      float d2_ = si_.z - sj.z, d3 = si_.w - sj.w;
      float dd = d0*d0 + d1*d1 + d2_*d2_ + d3*d3;
      wl[r][kx] = expf(-10.f*dd);
    }
  }
  __syncthreads();

  {
    const int r = t & 63;
    const int q = t >> 6;
    float msum[8], mmax[8];
    #pragma unroll
    for (int u = 0; u < 8; ++u){ msum[u] = 0.f; mmax[u] = -1e30f; }
    #pragma unroll
    for (int k = 0; k < KNN; ++k){
      int j = ci[0][r][k];
      float wk = wl[r][k];
      const float* hr = pg + (size_t)j*PRJW + q*8;
      float4 h0 = *(const float4*)(hr);
      float4 h1 = *(const float4*)(hr + 4);
      float v0 = h0.x*wk, v1 = h0.y*wk, v2 = h0.z*wk, v3 = h0.w*wk;
      float v4 = h1.x*wk, v5 = h1.y*wk, v6 = h1.z*wk, v7 = h1.w*wk;
      msum[0]+=v0; mmax[0]=fmaxf(mmax[0],v0);
      msum[1]+=v1; mmax[1]=fmaxf(mmax[1],v1);
      msum[2]+=v2; mmax[2]=fmaxf(mmax[2],v2);
      msum[3]+=v3; mmax[3]=fmaxf(mmax[3],v3);
      msum[4]+=v4; mmax[4]=fmaxf(mmax[4],v4);
      msum[5]+=v5; mmax[5]=fmaxf(mmax[5],v5);
      msum[6]+=v6; mmax[6]=fmaxf(mmax[6],v6);
      msum[7]+=v7; mmax[7]=fmaxf(mmax[7],v7);
    }
    float* arow = agg + ((size_t)g*GS + seg*64 + r)*AGGW;
    #pragma unroll
    for (int u = 0; u < 8; ++u){
      arow[q*8 + u]        = msum[u]*(1.f/KNN);
      arow[PROP + q*8 + u] = mmax[u];
    }
  }
}

// ---------------------------------------------------------------------------
extern "C" void kernel_launch(void* const* d_in, const int* in_sizes, int n_in,
                              void* d_out, int out_size, void* d_ws, size_t ws_size,
                              hipStream_t stream)
{
  const float* x     = (const float*)d_in[0];
  const float* n0W1  = (const float*)d_in[2];
  const float* n0b1  = (const float*)d_in[3];
  const float* n0W23 = (const float*)d_in[4];
  const float* n0b23 = (const float*)d_in[5];
  const float* n0W4  = (const float*)d_in[6];
  const float* n0b4  = (const float*)d_in[7];
  const float* cWh   = (const float*)d_in[8];
  const float* cbh   = (const float*)d_in[9];
  const float* cWs   = (const float*)d_in[10];
  const float* cbs   = (const float*)d_in[11];
  const float* cWo   = (const float*)d_in[12];
  const float* cbo   = (const float*)d_in[13];
  const float* HW1   = (const float*)d_in[14];
  const float* Hb1   = (const float*)d_in[15];
  const float* HW23  = (const float*)d_in[16];
  const float* Hb23  = (const float*)d_in[17];
  const float* Wid   = (const float*)d_in[18];
  const float* bid   = (const float*)d_in[19];
  const float* Wreg  = (const float*)d_in[20];
  const float* breg  = (const float*)d_in[21];
  const float* Wch   = (const float*)d_in[22];
  const float* bch   = (const float*)d_in[23];
  float* out = (float*)d_out;
  (void)in_sizes; (void)n_in; (void)out_size; (void)ws_size;

  // ---- workspace layout (~186 MB; < 188.5 MB proven in round 1) ----
  char* wsp = (char*)d_ws;
  unsigned short* featb = (unsigned short*)(wsp);        // N x 680 bf16 (89.1 MB)
  float* P     = (float*)(wsp + 89128960);               // N x 128
  float* Q     = (float*)(wsp + 122683392);              // N x 128
  float* projb = (float*)(wsp + 156237824);              // N x 36
  float* aggb  = (float*)(wsp + 165675008);              // N x 64
  unsigned short* pool = (unsigned short*)(wsp + 182452224);
  float* hacc  = P;                                      // head phase: N x 126/252 (P∪Q)
  float* t1    = (float*)wsp;                            // head phase: N x 126 f32 (featb region)

  // ---- build weight descriptors ----
  WDescs DS{};
  long long woff = 0; int nd = 0;
  auto addm = [&](const float* s1, const float* s2, int ld1, int ld2,
                  int nc1, int K, int Nn, int limbs)->long long {
    int ntiles = (K + 31) >> 5;
    int ncp = (Nn + 127) & ~127;
    long long o = woff;
    DS.d[nd].s1 = s1; DS.d[nd].s2 = s2; DS.d[nd].ld1 = ld1; DS.d[nd].ld2 = ld2;
    DS.d[nd].nc1 = nc1; DS.d[nd].K = K; DS.d[nd].Nn = Nn; DS.d[nd].limbs = limbs;
    DS.d[nd].dstoff = o; nd++;
    woff += (long long)limbs * ntiles * ncp * 32;
    return o;
  };
  // embedding (3-limb)
  long long o_e1 = addm(n0W1, nullptr, WIDTH, 0, WIDTH, IN_DIM, WIDTH, 3);
  long long o_e2 = addm(n0W23, nullptr, WIDTH, 0, WIDTH, WIDTH, WIDTH, 3);
  long long o_e3 = addm(n0W23 + WIDTH*WIDTH, nullptr, WIDTH, 0, WIDTH, WIDTH, WIDTH, 3);
  long long o_e4 = addm(n0W4, nullptr, EMB, 0, EMB, WIDTH, EMB, 3);
  // conv projections merged h|s and Wo (3-limb), pidx 0..9
  long long o_pj[10], o_wo[10];
  for (int p = 0; p < 10; ++p){
    o_pj[p] = addm(cWh + (size_t)p*EMB*PROP, cWs + (size_t)p*EMB*SPACE,
                   PROP, SPACE, PROP, EMB, PRJW, 3);
    o_wo[p] = addm(cWo + (size_t)p*CATW*EMB, nullptr, EMB, 0, EMB, CATW, EMB, 3);
  }
  // head layer-1, FULL K=674 (1-limb): s0 head0 (Nn=126); s1 heads1+2 (Nn=252)
  long long o_L1s0  = addm(HW1, nullptr, WIDTH, 0, WIDTH, FEAT, WIDTH, 1);
  long long o_L1s12 = addm(HW1 + (size_t)1*FEAT*WIDTH, HW1 + (size_t)2*FEAT*WIDTH,
                           WIDTH, WIDTH, WIDTH, FEAT, 2*WIDTH, 1);
  // head hidden layers (1-limb)
  long long o_hh[6];
  for (int q = 0; q < 6; ++q)
    o_hh[q] = addm(HW23 + (size_t)q*WIDTH*WIDTH, nullptr, WIDTH, 0, WIDTH, WIDTH, WIDTH, 1);

  hipLaunchKernelGGL(conv_weights_kernel, dim3(176, NMAT), dim3(256), 0, stream, DS, pool);

  auto gemmM = [&](int limbs, int abf, const void* A1, int lda1, int K1,
                   const float* A2, int lda2, int K2,
                   long long boff, const float* b1, const float* b2, int bsplit,
                   float* C, int ldc, int Nn, int mode, int act,
                   unsigned short* Cb, int ldcb){
    int ncp = (Nn + 127) & ~127;
    dim3 grid(N_TOT/128, ncp/128);
    if (limbs == 3)
      hipLaunchKernelGGL((mfma_gemm<3,0>), grid, dim3(256), 0, stream,
          A1, lda1, K1, A2, lda2, K2, pool + boff, ncp, b1, b2, bsplit,
          C, ldc, Nn, mode, act, Cb, ldcb);
    else if (abf)
      hipLaunchKernelGGL((mfma_gemm<1,1>), grid, dim3(256), 0, stream,
          A1, lda1, K1, A2, lda2, K2, pool + boff, ncp, b1, b2, bsplit,
          C, ldc, Nn, mode, act, Cb, ldcb);
    else
      hipLaunchKernelGGL((mfma_gemm<1,0>), grid, dim3(256), 0, stream,
          A1, lda1, K1, A2, lda2, K2, pool + boff, ncp, b1, b2, bsplit,
          C, ldc, Nn, mode, act, Cb, ldcb);
  };
  auto gemmS = [&](const float* A1, int lda1, int K1,
                   const float* W, const float* b,
                   float* C, int ldc, int Nn, int act,
                   const float* addx, int addx_ld, int addx_off){
    dim3 grid(N_TOT/64, (Nn+63)/64);
    hipLaunchKernelGGL((gemm_tile_kernel<64,64,32,4,4>), grid, dim3(256), 0, stream,
        A1, lda1, K1, W, b, C, ldc, Nn, act, addx, addx_ld, addx_off);
  };
  const int BIG = 1 << 30;

  for (int s = 0; s < 2; ++s){
    // ---- x -> featb bf16 cols 0..33 (featb region was scratch last stack) ----
    hipLaunchKernelGGL(xconv_kernel, dim3((N_TOT*IN_DIM + 255)/256), dim3(256),
                       0, stream, x, featb);

    // ---- embedding MLP -> P ----
    gemmM(3,0, x, IN_DIM, IN_DIM, nullptr,0,0, o_e1, n0b1, nullptr, BIG,
          Q, EMB, WIDTH, 0, 1, nullptr, 0);
    gemmM(3,0, Q, EMB, WIDTH, nullptr,0,0, o_e2, n0b23, nullptr, BIG,
          P, EMB, WIDTH, 0, 1, nullptr, 0);
    gemmM(3,0, P, EMB, WIDTH, nullptr,0,0, o_e3, n0b23 + WIDTH, nullptr, BIG,
          Q, EMB, WIDTH, 0, 1, nullptr, 0);
    gemmM(3,0, Q, EMB, WIDTH, nullptr,0,0, o_e4, n0b4, nullptr, BIG,
          P, EMB, EMB, 0, 0, nullptr, 0);

    float* cur = P; float* nxt = Q;
    for (int cv = 0; cv < NCONV; ++cv){
      int pidx = s*NCONV + cv;
      // h|s projections -> projb (split bias)
      gemmM(3,0, cur, EMB, EMB, nullptr,0,0, o_pj[pidx],
            cbh + pidx*PROP, cbs + pidx*SPACE, PROP,
            projb, PRJW, PRJW, 0, 0, nullptr, 0);
      // kNN + aggregate -> aggb
      hipLaunchKernelGGL(knn_agg_kernel, dim3(NG*16), dim3(256), 0, stream,
                         projb, aggb);
      // o_cv = [cur | agg] @ Wo + bo -> nxt (f32) AND featb slot (bf16)
      gemmM(3,0, cur, EMB, EMB, aggb, AGGW, AGGW, o_wo[pidx],
            cbo + pidx*EMB, nullptr, BIG, nxt, EMB, EMB, 0, 0,
            featb + IN_DIM + cv*EMB, FLDB);
      float* tmp = cur; cur = nxt; nxt = tmp;
    }

    // ---- head layer-1: ONE K=674 GEMM from featb (bf16 A), bias+ELU fused ----
    // (overwrites P/Q region; conv buffers dead now)
    if (s == 0){
      gemmM(1,1, featb, FLDB, FEAT, nullptr,0,0, o_L1s0,
            Hb1, nullptr, BIG, hacc, WIDTH, WIDTH, 0, 1, nullptr, 0);
    } else {
      gemmM(1,1, featb, FLDB, FEAT, nullptr,0,0, o_L1s12,
            Hb1 + WIDTH, Hb1 + 2*WIDTH, WIDTH,
            hacc, 2*WIDTH, 2*WIDTH, 0, 1, nullptr, 0);
    }

    // ---- head finish; t1 scratch overlays featb region (rebuilt next stack) ----
    auto finish_head = [&](int hidx, float* ha, int lda_ha,
                           float* dst, int dst_ld, int out_dim,
                           const float* Wl, const float* bl,
                           const float* addx, int addx_ld, int addx_off){
      gemmM(1,0, ha, lda_ha, WIDTH, nullptr,0,0, o_hh[hidx*2+0],
            Hb23 + (hidx*2+0)*WIDTH, nullptr, BIG,
            t1, WIDTH, WIDTH, 0, 1, nullptr, 0);
      gemmM(1,0, t1, WIDTH, WIDTH, nullptr,0,0, o_hh[hidx*2+1],
            Hb23 + (hidx*2+1)*WIDTH, nullptr, BIG,
            ha, lda_ha, WIDTH, 0, 1, nullptr, 0);
      gemmS(ha, lda_ha, WIDTH, Wl, bl, dst, dst_ld, out_dim, 0,
            addx, addx_ld, addx_off);
    };

    if (s == 0){
      finish_head(0, hacc, WIDTH, out, 8, 8, Wid, bid, nullptr, 0, 0);
    } else {
      finish_head(1, hacc, 2*WIDTH, out + (size_t)N_TOT*8, 4, 4,
                  Wreg, breg, x, IN_DIM, 1);
      finish_head(2, hacc + WIDTH, 2*WIDTH, out + (size_t)N_TOT*12, 1, 1,
                  Wch, bch, nullptr, 0, 0);
    }
  }
}

// Round 11
// 2354.697 us; speedup vs baseline: 9.1224x; 1.0829x over previous
//
#include <hip/hip_runtime.h>
#include <hip/hip_bf16.h>
#include <cstdint>

#define N_TOT 65536
#define NG 64
#define GS 1024
#define IN_DIM 34
#define WIDTH 126
#define EMB 128
#define PROP 32
#define SPACE 4
#define KNN 8
#define NCONV 5
#define FEAT (IN_DIM + NCONV*EMB)   /* 674 */
#define FLDB 680                    /* featb bf16 leading dim */
#define CATW (EMB + 2*PROP)         /* 192 */
#define AGGW (2*PROP)               /* 64 */
#define PRJW 36                     /* h(32) | s(4) */

typedef __attribute__((ext_vector_type(8))) short short8v;
typedef __attribute__((ext_vector_type(4))) float f32x4;

__device__ __forceinline__ unsigned short f2bf(float f){
  unsigned int u = __float_as_uint(f);
  unsigned int r = (u + 0x7FFFu + ((u >> 16) & 1u)) >> 16;
  return (unsigned short)r;
}
__device__ __forceinline__ float bf2f(unsigned short b){
  return __uint_as_float(((unsigned int)b) << 16);
}

// ---------------------------------------------------------------------------
// Weight pre-conversion -> bf16 limb pool [limb][ktile][col(<ncp)][k32].
// ---------------------------------------------------------------------------
struct WDesc {
  const float* s1; const float* s2;
  int ld1, ld2, nc1, K, Nn, limbs, ncp;
  long long dstoff;
};
#define NMAT 32
struct WDescs { WDesc d[NMAT]; };

__global__ __launch_bounds__(256)
void conv_weights_kernel(WDescs DS, unsigned short* __restrict__ pool)
{
  int m = blockIdx.y;
  WDesc d = DS.d[m];
  if (d.K == 0) return;
  int ntiles = (d.K + 31) >> 5;
  int ncp = d.ncp;
  int nchunk = ncp >> 5;
  int kt = blockIdx.x / nchunk;
  int cc = blockIdx.x % nchunk;
  if (kt >= ntiles) return;
  int t = threadIdx.x;
  int kk = t & 31;
  int k = kt*32 + kk;
  for (int c = (t >> 5); c < 32; c += 8){
    int col = cc*32 + c;
    float v = 0.f;
    if (k < d.K && col < d.Nn)
      v = (col < d.nc1) ? d.s1[(size_t)k*d.ld1 + col]
                        : d.s2[(size_t)k*d.ld2 + (col - d.nc1)];
    for (int l = 0; l < d.limbs; ++l){
      unsigned short b = f2bf(v); v -= bf2f(b);
      pool[d.dstoff + ((long long)(l*ntiles + kt)*ncp + col)*32 + kk] = b;
    }
  }
}

// ---------------------------------------------------------------------------
// x (f32 N x 34) -> featb bf16 cols 0..33
// ---------------------------------------------------------------------------
__global__ __launch_bounds__(256)
void xconv_kernel(const float* __restrict__ x, unsigned short* __restrict__ featb)
{
  int idx = blockIdx.x*256 + threadIdx.x;
  if (idx < N_TOT*IN_DIM){
    int r = idx / IN_DIM, c = idx - r*IN_DIM;
    featb[(size_t)r*FLDB + c] = f2bf(x[idx]);
  }
}

// ---------------------------------------------------------------------------
// MFMA bf16 GEMM, LIMBS-limb f32 emulation, A-register-prefetch pipelined.
// ABF=1: A already bf16 (LIMBS=1). NT: output col-tile (128: 2x2 waves of
// 64x64; 64: 4 waves of 32 rows x 64 cols). B fragments from limb pool.
// mode: 0 C=act(A@W+bias)(+Cb bf16 copy), 1 C+=A@W, 2 C=elu(C+A@W+bias).
// ---------------------------------------------------------------------------
template<int LIMBS, int ABF, int NT>
__global__ __launch_bounds__(256)
void mfma_gemm(const void* __restrict__ A1v, int lda1, int K1,
               const float* __restrict__ A2, int lda2, int K2,
               const unsigned short* __restrict__ BL, int ncp,
               const float* __restrict__ bias1, const float* __restrict__ bias2,
               int bsplit,
               float* __restrict__ C, int ldc, int Nn, int mode, int act,
               unsigned short* __restrict__ Cb, int ldcb)
{
  constexpr int ASTR = LIMBS*32 + 8;
  constexpr int RB = (NT == 128) ? 4 : 2;
  __shared__ __align__(16) unsigned short Alds[128*ASTR];
  const float* A1 = (const float*)A1v;
  const unsigned short* Ab = (const unsigned short*)A1v;

  const int K = K1 + K2;
  const int ntiles = (K + 31) >> 5;
  const int t = threadIdx.x;
  const int bm0 = blockIdx.x * 128;
  const int col0 = blockIdx.y * NT;
  const int lane = t & 63;
  const int wid  = t >> 6;
  const int wr = (NT == 128) ? (wid >> 1) * 64 : wid * 32;
  const int wc = (NT == 128) ? (wid & 1) * 64 : 0;
  const int frow = lane & 15;
  const int fk   = (lane >> 4) * 8;
  const int a_row = t >> 1;
  const int a_kh  = (t & 1) * 16;
  const size_t rr = (size_t)(bm0 + a_row);

  float v[16];
  short8v pb0, pb1;

  auto loadreg = [&](int kt){
    const int k0 = kt * 32;
    if (ABF){
      if (k0 + 31 < K){
        pb0 = *(const short8v*)&Ab[rr*lda1 + k0 + a_kh];
        pb1 = *(const short8v*)&Ab[rr*lda1 + k0 + a_kh + 8];
      } else {
        #pragma unroll
        for (int j = 0; j < 8; ++j){
          int ka = k0 + a_kh + j;
          pb0[j] = (ka < K) ? (short)Ab[rr*lda1 + ka] : (short)0;
        }
        #pragma unroll
        for (int j = 0; j < 8; ++j){
          int ka = k0 + a_kh + 8 + j;
          pb1[j] = (ka < K) ? (short)Ab[rr*lda1 + ka] : (short)0;
        }
      }
    } else {
      #pragma unroll
      for (int j = 0; j < 16; ++j){
        int ka = k0 + a_kh + j;
        float xv = 0.f;
        if (ka < K)
          xv = (ka < K1) ? A1[rr*lda1 + ka] : A2[rr*lda2 + (ka - K1)];
        v[j] = xv;
      }
    }
  };

  auto storelds = [&](){
    if (ABF){
      *(short8v*)&Alds[a_row*ASTR + a_kh]     = pb0;
      *(short8v*)&Alds[a_row*ASTR + a_kh + 8] = pb1;
    } else {
      #pragma unroll
      for (int l = 0; l < LIMBS; ++l){
        short8v q0, q1;
        #pragma unroll
        for (int j = 0; j < 8; ++j){
          unsigned short b = f2bf(v[j]); v[j] -= bf2f(b); q0[j] = (short)b;
        }
        #pragma unroll
        for (int j = 0; j < 8; ++j){
          unsigned short b = f2bf(v[8+j]); v[8+j] -= bf2f(b); q1[j] = (short)b;
        }
        *(short8v*)&Alds[a_row*ASTR + l*32 + a_kh]     = q0;
        *(short8v*)&Alds[a_row*ASTR + l*32 + a_kh + 8] = q1;
      }
    }
  };

  f32x4 acc[RB][4];
  #pragma unroll
  for (int i = 0; i < RB; ++i)
    #pragma unroll
    for (int j = 0; j < 4; ++j)
      acc[i][j] = (f32x4){0.f, 0.f, 0.f, 0.f};

  loadreg(0);
  for (int kt = 0; kt < ntiles; ++kt){
    __syncthreads();                 // prior compute done reading LDS
    storelds();                      // convert/store current tile
    if (kt + 1 < ntiles) loadreg(kt + 1);   // prefetch next (hides under MFMA)
    __syncthreads();
    #pragma unroll
    for (int lA = 0; lA < LIMBS; ++lA){
      short8v af[RB];
      #pragma unroll
      for (int rb = 0; rb < RB; ++rb)
        af[rb] = *(const short8v*)&Alds[(wr + rb*16 + frow)*ASTR + lA*32 + fk];
      #pragma unroll
      for (int lB = 0; lB < LIMBS - lA; ++lB){
        const unsigned short* bbase =
            BL + ((long long)(lB*ntiles + kt)*ncp)*32;
        short8v bfr[4];
        #pragma unroll
        for (int cb = 0; cb < 4; ++cb){
          int col = col0 + wc + cb*16 + frow;
          bfr[cb] = *(const short8v*)&bbase[(long long)col*32 + fk];
        }
        #pragma unroll
        for (int rb = 0; rb < RB; ++rb)
          #pragma unroll
          for (int cb = 0; cb < 4; ++cb)
            acc[rb][cb] = __builtin_amdgcn_mfma_f32_16x16x32_bf16(
                af[rb], bfr[cb], acc[rb][cb], 0, 0, 0);
      }
    }
  }

  // ---- epilogue ----
  const int lr4 = (lane >> 4) * 4;
  #pragma unroll
  for (int rb = 0; rb < RB; ++rb){
    #pragma unroll
    for (int cb = 0; cb < 4; ++cb){
      const int col = col0 + wc + cb*16 + frow;
      if (col < Nn){
        float bv = 0.f;
        if (bias1) bv = (col < bsplit) ? bias1[col] : bias2[col - bsplit];
        #pragma unroll
        for (int ri = 0; ri < 4; ++ri){
          const size_t row = (size_t)(bm0 + wr + rb*16 + lr4 + ri);
          float vv = acc[rb][cb][ri];
          if (mode == 1){
            C[row*ldc + col] += vv;
          } else if (mode == 2){
            float a2 = vv + C[row*ldc + col] + bv;
            C[row*ldc + col] = (a2 > 0.f) ? a2 : expm1f(a2);
          } else {
            if (bias1) vv += bv;
            if (act == 1) vv = (vv > 0.f) ? vv : expm1f(vv);
            C[row*ldc + col] = vv;
            if (Cb) Cb[row*(size_t)ldcb + col] = f2bf(vv);
          }
        }
      }
    }
  }
}

// ---------------------------------------------------------------------------
// f32 register-tiled GEMM — only for the tiny final head projections.
// ---------------------------------------------------------------------------
template<int BM, int BN, int BK, int TM, int TN>
__global__ __launch_bounds__(256)
void gemm_tile_kernel(const float* __restrict__ A1, int lda1, int K1,
                      const float* __restrict__ W, const float* __restrict__ bias,
                      float* __restrict__ C, int ldc, int Nn, int act,
                      const float* __restrict__ addx, int addx_ld, int addx_off)
{
  constexpr int LDA = BM + 4;
  constexpr int LDB = BN + 4;
  constexpr int APASS = (BM*BK)/1024;
  constexpr int BPASS = (BN*BK)/1024;
  constexpr int AROWS = 256/(BK/4);
  constexpr int BROWS = 256/(BN/4);
  __shared__ float As[BK*LDA];
  __shared__ float Bs[BK*LDB];
  const int K = K1;
  const int t = threadIdx.x;
  const int bm0 = blockIdx.x * BM;
  const int bn0 = blockIdx.y * BN;
  const int tx = t % 16;
  const int ty = t / 16;
  const int a_r = t / (BK/4);
  const int a_k = 4 * (t % (BK/4));
  const int b_c = t % (BN/4);
  const int b_k = t / (BN/4);

  float ar[APASS][4], br[BPASS][4];
  auto load_tile = [&](int k0){
    #pragma unroll
    for (int p = 0; p < APASS; ++p){
      size_t rr = (size_t)(bm0 + a_r + p*AROWS);
      #pragma unroll
      for (int j = 0; j < 4; ++j){
        int ka = k0 + a_k + j;
        ar[p][j] = (ka < K) ? A1[rr*lda1 + ka] : 0.f;
      }
    }
    #pragma unroll
    for (int p = 0; p < BPASS; ++p){
      int kb = k0 + b_k + p*BROWS;
      #pragma unroll
      for (int j = 0; j < 4; ++j){
        int col = bn0 + 4*b_c + j;
        br[p][j] = (kb < K && col < Nn) ? W[(size_t)kb*Nn + col] : 0.f;
      }
    }
  };
  auto store_tile = [&](){
    #pragma unroll
    for (int p = 0; p < APASS; ++p)
      #pragma unroll
      for (int j = 0; j < 4; ++j)
        As[(a_k + j)*LDA + a_r + p*AROWS] = ar[p][j];
    #pragma unroll
    for (int p = 0; p < BPASS; ++p)
      *(float4*)&Bs[(b_k + p*BROWS)*LDB + 4*b_c] =
          make_float4(br[p][0], br[p][1], br[p][2], br[p][3]);
  };

  float acc[TM][TN];
  #pragma unroll
  for (int i = 0; i < TM; ++i)
    #pragma unroll
    for (int j = 0; j < TN; ++j) acc[i][j] = 0.f;

  auto compute_tile = [&](){
    #pragma unroll
    for (int kk = 0; kk < BK; ++kk){
      float a[TM], b[TN];
      #pragma unroll
      for (int iq = 0; iq < TM/4; ++iq){
        float4 v = *(const float4*)&As[kk*LDA + iq*(BM/2) + 4*ty];
        a[iq*4+0] = v.x; a[iq*4+1] = v.y; a[iq*4+2] = v.z; a[iq*4+3] = v.w;
      }
      #pragma unroll
      for (int jq = 0; jq < TN/4; ++jq){
        float4 v = *(const float4*)&Bs[kk*LDB + jq*(BN/2) + 4*tx];
        b[jq*4+0] = v.x; b[jq*4+1] = v.y; b[jq*4+2] = v.z; b[jq*4+3] = v.w;
      }
      #pragma unroll
      for (int i = 0; i < TM; ++i)
        #pragma unroll
        for (int j = 0; j < TN; ++j)
          acc[i][j] += a[i]*b[j];
    }
  };

  const int ntiles = (K + BK - 1)/BK;
  load_tile(0); store_tile(); __syncthreads();
  for (int tt = 1; tt < ntiles; ++tt){
    load_tile(tt*BK);
    compute_tile();
    __syncthreads();
    store_tile();
    __syncthreads();
  }
  compute_tile();

  #pragma unroll
  for (int i = 0; i < TM; ++i){
    size_t row = (size_t)(bm0 + (i/4)*(BM/2) + 4*ty + (i%4));
    #pragma unroll
    for (int j = 0; j < TN; ++j){
      int col = bn0 + (j/4)*(BN/2) + 4*tx + (j%4);
      if (col < Nn){
        float v = acc[i][j];
        if (bias) v += bias[col];
        if (act == 1) v = (v > 0.f) ? v : expm1f(v);
        if (addx) v += addx[row*addx_ld + addx_off + col];
        C[row*ldc + col] = v;
      }
    }
  }
}

// ---------------------------------------------------------------------------
// kNN + aggregation, 4-wave split-scan (unchanged from round 10).
// ---------------------------------------------------------------------------
__global__ __launch_bounds__(256)
void knn_agg_kernel(const float* __restrict__ proj, float* __restrict__ agg)
{
  __shared__ float4 ssv[GS];
  __shared__ float  sn2[GS];
  __shared__ float  cd[4][64][KNN];
  __shared__ int    ci[4][64][KNN];
  __shared__ float  wl[64][KNN];

  const int g   = blockIdx.x >> 4;
  const int seg = blockIdx.x & 15;
  const int t = threadIdx.x;
  const int wave = t >> 6;
  const int lane = t & 63;

  const float* pg = proj + (size_t)g*GS*PRJW;
  for (int i = t; i < GS; i += 256){
    float4 v = *(const float4*)(pg + (size_t)i*PRJW + PROP);
    ssv[i] = v;
    sn2[i] = v.x*v.x + v.y*v.y + v.z*v.z + v.w*v.w;
  }
  __syncthreads();

  const int i = seg*64 + lane;
  float4 sv = ssv[i];
  float myn2 = sn2[i];
  float si0 = sv.x, si1 = sv.y, si2 = sv.z, si3 = sv.w;

  float bd[KNN]; int bi[KNN];
  #pragma unroll
  for (int k = 0; k < KNN; ++k){ bd[k] = 1e30f; bi[k] = 0; }

  const int jbeg = wave * 256;
  for (int j0 = jbeg; j0 < jbeg + 256; j0 += 8){
    float dv[8];
    #pragma unroll
    for (int u = 0; u < 8; ++u){
      float4 sj = ssv[j0+u];
      float dot = si0*sj.x + si1*sj.y + si2*sj.z + si3*sj.w;
      dv[u] = myn2 + sn2[j0+u] - 2.f*dot;
    }
    float mn = fminf(fminf(fminf(dv[0],dv[1]), fminf(dv[2],dv[3])),
                     fminf(fminf(dv[4],dv[5]), fminf(dv[6],dv[7])));
    if (mn < bd[KNN-1]){
      #pragma unroll
      for (int u = 0; u < 8; ++u){
        float d2 = dv[u];
        if (d2 < bd[KNN-1]){
          int j = j0 + u;
          #pragma unroll
          for (int q = KNN-1; q >= 1; --q){
            bool cq = d2 < bd[q];
            bool cp = d2 < bd[q-1];
            float nv = cp ? bd[q-1] : d2;
            int   ni = cp ? bi[q-1] : j;
            if (cq){ bd[q] = nv; bi[q] = ni; }
          }
          if (d2 < bd[0]){ bd[0] = d2; bi[0] = j; }
        }
      }
    }
  }
  #pragma unroll
  for (int k = 0; k < KNN; ++k){ cd[wave][lane][k] = bd[k]; ci[wave][lane][k] = bi[k]; }
  __syncthreads();

  if (wave == 0){
    #pragma unroll
    for (int c = 1; c < 4; ++c){
      #pragma unroll
      for (int k = 0; k < KNN; ++k){
        float d2 = cd[c][lane][k];
        if (d2 < bd[KNN-1]){
          int j = ci[c][lane][k];
          #pragma unroll
          for (int q = KNN-1; q >= 1; --q){
            bool cq = d2 < bd[q];
            bool cp = d2 < bd[q-1];
            float nv = cp ? bd[q-1] : d2;
            int   ni = cp ? bi[q-1] : j;
            if (cq){ bd[q] = nv; bi[q] = ni; }
          }
          if (d2 < bd[0]){ bd[0] = d2; bi[0] = j; }
        }
      }
    }
    #pragma unroll
    for (int k = 0; k < KNN; ++k){ cd[0][lane][k] = bd[k]; ci[0][lane][k] = bi[k]; }
  }
  __syncthreads();

  {
    const int r = t & 63;
    float4 si_ = ssv[seg*64 + r];
    #pragma unroll
    for (int kx = (t >> 6); kx < KNN; kx += 4){
      int j = ci[0][r][kx];
      float4 sj = ssv[j];
      float d0 = si_.x - sj.x, d1 = si_.y - sj.y;
      float d2_ = si_.z - sj.z, d3 = si_.w - sj.w;
      float dd = d0*d0 + d1*d1 + d2_*d2_ + d3*d3;
      wl[r][kx] = expf(-10.f*dd);
    }
  }
  __syncthreads();

  {
    const int r = t & 63;
    const int q = t >> 6;
    float msum[8], mmax[8];
    #pragma unroll
    for (int u = 0; u < 8; ++u){ msum[u] = 0.f; mmax[u] = -1e30f; }
    #pragma unroll
    for (int k = 0; k < KNN; ++k){
      int j = ci[0][r][k];
      float wk = wl[r][k];
      const float* hr = pg + (size_t)j*PRJW + q*8;
      float4 h0 = *(const float4*)(hr);
      float4 h1 = *(const float4*)(hr + 4);
      float v0 = h0.x*wk, v1 = h0.y*wk, v2 = h0.z*wk, v3 = h0.w*wk;
      float v4 = h1.x*wk, v5 = h1.y*wk, v6 = h1.z*wk, v7 = h1.w*wk;
      msum[0]+=v0; mmax[0]=fmaxf(mmax[0],v0);
      msum[1]+=v1; mmax[1]=fmaxf(mmax[1],v1);
      msum[2]+=v2; mmax[2]=fmaxf(mmax[2],v2);
      msum[3]+=v3; mmax[3]=fmaxf(mmax[3],v3);
      msum[4]+=v4; mmax[4]=fmaxf(mmax[4],v4);
      msum[5]+=v5; mmax[5]=fmaxf(mmax[5],v5);
      msum[6]+=v6; mmax[6]=fmaxf(mmax[6],v6);
      msum[7]+=v7; mmax[7]=fmaxf(mmax[7],v7);
    }
    float* arow = agg + ((size_t)g*GS + seg*64 + r)*AGGW;
    #pragma unroll
    for (int u = 0; u < 8; ++u){
      arow[q*8 + u]        = msum[u]*(1.f/KNN);
      arow[PROP + q*8 + u] = mmax[u];
    }
  }
}

// ---------------------------------------------------------------------------
extern "C" void kernel_launch(void* const* d_in, const int* in_sizes, int n_in,
                              void* d_out, int out_size, void* d_ws, size_t ws_size,
                              hipStream_t stream)
{
  const float* x     = (const float*)d_in[0];
  const float* n0W1  = (const float*)d_in[2];
  const float* n0b1  = (const float*)d_in[3];
  const float* n0W23 = (const float*)d_in[4];
  const float* n0b23 = (const float*)d_in[5];
  const float* n0W4  = (const float*)d_in[6];
  const float* n0b4  = (const float*)d_in[7];
  const float* cWh   = (const float*)d_in[8];
  const float* cbh   = (const float*)d_in[9];
  const float* cWs   = (const float*)d_in[10];
  const float* cbs   = (const float*)d_in[11];
  const float* cWo   = (const float*)d_in[12];
  const float* cbo   = (const float*)d_in[13];
  const float* HW1   = (const float*)d_in[14];
  const float* Hb1   = (const float*)d_in[15];
  const float* HW23  = (const float*)d_in[16];
  const float* Hb23  = (const float*)d_in[17];
  const float* Wid   = (const float*)d_in[18];
  const float* bid   = (const float*)d_in[19];
  const float* Wreg  = (const float*)d_in[20];
  const float* breg  = (const float*)d_in[21];
  const float* Wch   = (const float*)d_in[22];
  const float* bch   = (const float*)d_in[23];
  float* out = (float*)d_out;
  (void)in_sizes; (void)n_in; (void)out_size;

  // ---- workspace layout (base ~186 MB; optional E buffer if ws allows) ----
  char* wsp = (char*)d_ws;
  unsigned short* featb = (unsigned short*)(wsp);        // N x 680 bf16
  float* P     = (float*)(wsp + 89128960);               // N x 128
  float* Q     = (float*)(wsp + 122683392);              // N x 128
  float* projb = (float*)(wsp + 156237824);              // N x 36
  float* aggb  = (float*)(wsp + 165675008);              // N x 64
  unsigned short* pool = (unsigned short*)(wsp + 182452224);
  float* hacc  = P;
  float* t1    = (float*)wsp;                            // head-phase scratch

  // ---- weight descriptors ----
  WDescs DS{};
  long long woff = 0; int nd = 0;
  auto addm = [&](const float* s1, const float* s2, int ld1, int ld2,
                  int nc1, int K, int Nn, int limbs, int nalign)->long long {
    int ntiles = (K + 31) >> 5;
    int ncp = (Nn + nalign - 1) & ~(nalign - 1);
    long long o = woff;
    DS.d[nd].s1 = s1; DS.d[nd].s2 = s2; DS.d[nd].ld1 = ld1; DS.d[nd].ld2 = ld2;
    DS.d[nd].nc1 = nc1; DS.d[nd].K = K; DS.d[nd].Nn = Nn; DS.d[nd].limbs = limbs;
    DS.d[nd].ncp = ncp; DS.d[nd].dstoff = o; nd++;
    woff += (long long)limbs * ntiles * ncp * 32;
    return o;
  };
  long long o_e1 = addm(n0W1, nullptr, WIDTH, 0, WIDTH, IN_DIM, WIDTH, 3, 128);
  long long o_e2 = addm(n0W23, nullptr, WIDTH, 0, WIDTH, WIDTH, WIDTH, 3, 128);
  long long o_e3 = addm(n0W23 + WIDTH*WIDTH, nullptr, WIDTH, 0, WIDTH, WIDTH, WIDTH, 3, 128);
  long long o_e4 = addm(n0W4, nullptr, EMB, 0, EMB, WIDTH, EMB, 3, 128);
  long long o_pj[10], o_wo[10];
  for (int p = 0; p < 10; ++p){
    o_pj[p] = addm(cWh + (size_t)p*EMB*PROP, cWs + (size_t)p*EMB*SPACE,
                   PROP, SPACE, PROP, EMB, PRJW, 3, 64);       // ncp = 64
    o_wo[p] = addm(cWo + (size_t)p*CATW*EMB, nullptr, EMB, 0, EMB, CATW, EMB, 3, 128);
  }
  long long o_L1s0  = addm(HW1, nullptr, WIDTH, 0, WIDTH, FEAT, WIDTH, 1, 128);
  long long o_L1s12 = addm(HW1 + (size_t)1*FEAT*WIDTH, HW1 + (size_t)2*FEAT*WIDTH,
                           WIDTH, WIDTH, WIDTH, FEAT, 2*WIDTH, 1, 128);
  long long o_hh[6];
  for (int q = 0; q < 6; ++q)
    o_hh[q] = addm(HW23 + (size_t)q*WIDTH*WIDTH, nullptr, WIDTH, 0, WIDTH, WIDTH, WIDTH, 1, 128);

  // optional embedding buffer E (computed once) if workspace allows
  long long E_off = ((182452224LL + woff*2) + 255) & ~255LL;
  bool haveE = (E_off + (long long)N_TOT*EMB*4 <= (long long)ws_size);
  float* E = (float*)(wsp + E_off);

  hipLaunchKernelGGL(conv_weights_kernel, dim3(176, NMAT), dim3(256), 0, stream, DS, pool);

  auto gemmM = [&](int limbs, int abf, int nt, const void* A1, int lda1, int K1,
                   const float* A2, int lda2, int K2,
                   long long boff, int ncp,
                   const float* b1, const float* b2, int bsplit,
                   float* C, int ldc, int Nn, int mode, int act,
                   unsigned short* Cb, int ldcb){
    dim3 grid(N_TOT/128, ncp/nt);
    if (limbs == 3 && nt == 64)
      hipLaunchKernelGGL((mfma_gemm<3,0,64>), grid, dim3(256), 0, stream,
          A1, lda1, K1, A2, lda2, K2, pool + boff, ncp, b1, b2, bsplit,
          C, ldc, Nn, mode, act, Cb, ldcb);
    else if (limbs == 3)
      hipLaunchKernelGGL((mfma_gemm<3,0,128>), grid, dim3(256), 0, stream,
          A1, lda1, K1, A2, lda2, K2, pool + boff, ncp, b1, b2, bsplit,
          C, ldc, Nn, mode, act, Cb, ldcb);
    else if (abf)
      hipLaunchKernelGGL((mfma_gemm<1,1,128>), grid, dim3(256), 0, stream,
          A1, lda1, K1, A2, lda2, K2, pool + boff, ncp, b1, b2, bsplit,
          C, ldc, Nn, mode, act, Cb, ldcb);
    else
      hipLaunchKernelGGL((mfma_gemm<1,0,128>), grid, dim3(256), 0, stream,
          A1, lda1, K1, A2, lda2, K2, pool + boff, ncp, b1, b2, bsplit,
          C, ldc, Nn, mode, act, Cb, ldcb);
  };
  auto gemmS = [&](const float* A1, int lda1, int K1,
                   const float* W, const float* b,
                   float* C, int ldc, int Nn, int act,
                   const float* addx, int addx_ld, int addx_off){
    dim3 grid(N_TOT/64, (Nn+63)/64);
    hipLaunchKernelGGL((gemm_tile_kernel<64,64,32,4,4>), grid, dim3(256), 0, stream,
        A1, lda1, K1, W, b, C, ldc, Nn, act, addx, addx_ld, addx_off);
  };
  const int BIG = 1 << 30;

  auto run_embedding = [&](float* dst){
    gemmM(3,0,128, x, IN_DIM, IN_DIM, nullptr,0,0, o_e1, 128, n0b1, nullptr, BIG,
          Q, EMB, WIDTH, 0, 1, nullptr, 0);
    gemmM(3,0,128, Q, EMB, WIDTH, nullptr,0,0, o_e2, 128, n0b23, nullptr, BIG,
          P, EMB, WIDTH, 0, 1, nullptr, 0);
    gemmM(3,0,128, P, EMB, WIDTH, nullptr,0,0, o_e3, 128, n0b23 + WIDTH, nullptr, BIG,
          Q, EMB, WIDTH, 0, 1, nullptr, 0);
    gemmM(3,0,128, Q, EMB, WIDTH, nullptr,0,0, o_e4, 128, n0b4, nullptr, BIG,
          dst, EMB, EMB, 0, 0, nullptr, 0);
  };

  if (haveE) run_embedding(E);     // embedding computed ONCE

  for (int s = 0; s < 2; ++s){
    hipLaunchKernelGGL(xconv_kernel, dim3((N_TOT*IN_DIM + 255)/256), dim3(256),
                       0, stream, x, featb);
    if (!haveE) run_embedding(P);

    float* cur = haveE ? E : P;
    float* b0  = haveE ? P : Q;
    float* b1  = haveE ? Q : P;

    for (int cv = 0; cv < NCONV; ++cv){
      int pidx = s*NCONV + cv;
      float* nxt = (cv & 1) ? b1 : b0;
      // h|s projections -> projb (ncp=64, NT=64 tile)
      gemmM(3,0,64, cur, EMB, EMB, nullptr,0,0, o_pj[pidx], 64,
            cbh + pidx*PROP, cbs + pidx*SPACE, PROP,
            projb, PRJW, PRJW, 0, 0, nullptr, 0);
      // kNN + aggregate -> aggb
      hipLaunchKernelGGL(knn_agg_kernel, dim3(NG*16), dim3(256), 0, stream,
                         projb, aggb);
      // o_cv = [cur | agg] @ Wo + bo -> nxt (f32) AND featb slot (bf16)
      gemmM(3,0,128, cur, EMB, EMB, aggb, AGGW, AGGW, o_wo[pidx], 128,
            cbo + pidx*EMB, nullptr, BIG, nxt, EMB, EMB, 0, 0,
            featb + IN_DIM + cv*EMB, FLDB);
      cur = nxt;
    }

    // ---- head layer-1: ONE K=674 GEMM from featb (bf16 A), bias+ELU fused ----
    if (s == 0){
      gemmM(1,1,128, featb, FLDB, FEAT, nullptr,0,0, o_L1s0, 128,
            Hb1, nullptr, BIG, hacc, WIDTH, WIDTH, 0, 1, nullptr, 0);
    } else {
      gemmM(1,1,128, featb, FLDB, FEAT, nullptr,0,0, o_L1s12, 256,
            Hb1 + WIDTH, Hb1 + 2*WIDTH, WIDTH,
            hacc, 2*WIDTH, 2*WIDTH, 0, 1, nullptr, 0);
    }

    // ---- head finish (t1 overlays featb region; rebuilt next stack) ----
    auto finish_head = [&](int hidx, float* ha, int lda_ha,
                           float* dst, int dst_ld, int out_dim,
                           const float* Wl, const float* bl,
                           const float* addx, int addx_ld, int addx_off){
      gemmM(1,0,128, ha, lda_ha, WIDTH, nullptr,0,0, o_hh[hidx*2+0], 128,
            Hb23 + (hidx*2+0)*WIDTH, nullptr, BIG,
            t1, WIDTH, WIDTH, 0, 1, nullptr, 0);
      gemmM(1,0,128, t1, WIDTH, WIDTH, nullptr,0,0, o_hh[hidx*2+1], 128,
            Hb23 + (hidx*2+1)*WIDTH, nullptr, BIG,
            ha, lda_ha, WIDTH, 0, 1, nullptr, 0);
      gemmS(ha, lda_ha, WIDTH, Wl, bl, dst, dst_ld, out_dim, 0,
            addx, addx_ld, addx_off);
    };

    if (s == 0){
      finish_head(0, hacc, WIDTH, out, 8, 8, Wid, bid, nullptr, 0, 0);
    } else {
      finish_head(1, hacc, 2*WIDTH, out + (size_t)N_TOT*8, 4, 4,
                  Wreg, breg, x, IN_DIM, 1);
      finish_head(2, hacc + WIDTH, 2*WIDTH, out + (size_t)N_TOT*12, 1, 1,
                  Wch, bch, nullptr, 0, 0);
    }
  }
}

// Round 12
// 1886.516 us; speedup vs baseline: 11.3863x; 1.2482x over previous
//
#include <hip/hip_runtime.h>
#include <hip/hip_bf16.h>
#include <cstdint>

#define N_TOT 65536
#define NG 64
#define GS 1024
#define IN_DIM 34
#define WIDTH 126
#define EMB 128
#define PROP 32
#define SPACE 4
#define KNN 8
#define NCONV 5
#define FEAT (IN_DIM + NCONV*EMB)   /* 674 */
#define FLDB 680                    /* featb bf16 leading dim */
#define CATW (EMB + 2*PROP)         /* 192 */
#define AGGW (2*PROP)               /* 64 */
#define PRJW 36                     /* h(32) | s(4) */

typedef unsigned short ushort;
typedef __attribute__((ext_vector_type(8))) short short8v;
typedef __attribute__((ext_vector_type(4))) float f32x4;

__device__ __forceinline__ ushort f2bf(float f){
  unsigned int u = __float_as_uint(f);
  unsigned int r = (u + 0x7FFFu + ((u >> 16) & 1u)) >> 16;
  return (ushort)r;
}
__device__ __forceinline__ float bf2f(ushort b){
  return __uint_as_float(((unsigned int)b) << 16);
}

// ---------------------------------------------------------------------------
// Weight pre-conversion -> bf16 limb pool [limb][ktile][col(<ncp)][k32].
// ---------------------------------------------------------------------------
struct WDesc {
  const float* s1; const float* s2;
  int ld1, ld2, nc1, K, Nn, limbs, ncp;
  long long dstoff;
};
#define NMAT 32
struct WDescs { WDesc d[NMAT]; };

__global__ __launch_bounds__(256)
void conv_weights_kernel(WDescs DS, ushort* __restrict__ pool)
{
  int m = blockIdx.y;
  WDesc d = DS.d[m];
  if (d.K == 0) return;
  int ntiles = (d.K + 31) >> 5;
  int ncp = d.ncp;
  int nchunk = ncp >> 5;
  int kt = blockIdx.x / nchunk;
  int cc = blockIdx.x % nchunk;
  if (kt >= ntiles) return;
  int t = threadIdx.x;
  int kk = t & 31;
  int k = kt*32 + kk;
  for (int c = (t >> 5); c < 32; c += 8){
    int col = cc*32 + c;
    float v = 0.f;
    if (k < d.K && col < d.Nn)
      v = (col < d.nc1) ? d.s1[(size_t)k*d.ld1 + col]
                        : d.s2[(size_t)k*d.ld2 + (col - d.nc1)];
    for (int l = 0; l < d.limbs; ++l){
      ushort b = f2bf(v); v -= bf2f(b);
      pool[d.dstoff + ((long long)(l*ntiles + kt)*ncp + col)*32 + kk] = b;
    }
  }
}

// ---------------------------------------------------------------------------
// x (f32 N x 34) -> featb bf16 cols 0..33
// ---------------------------------------------------------------------------
__global__ __launch_bounds__(256)
void xconv_kernel(const float* __restrict__ x, ushort* __restrict__ featb)
{
  int idx = blockIdx.x*256 + threadIdx.x;
  if (idx < N_TOT*IN_DIM){
    int r = idx / IN_DIM, c = idx - r*IN_DIM;
    featb[(size_t)r*FLDB + c] = f2bf(x[idx]);
  }
}

// ---------------------------------------------------------------------------
// MFMA bf16 GEMM, LIMBS-limb f32 emulation, BM=64 rows/block, reg-prefetch.
// ABF=1: A already bf16 (LIMBS=1). NT = 128 (waves 2x2, 32r x 64c each) or
// 64 (waves 2x2, 32r x 32c). C = act(A@W + bias[split]); optional bf16 copy.
// ---------------------------------------------------------------------------
template<int LIMBS, int ABF, int NT>
__global__ __launch_bounds__(256)
void mfma_gemm(const void* __restrict__ A1v, int lda1, int K1,
               const float* __restrict__ A2, int lda2, int K2,
               const ushort* __restrict__ BL, int ncp,
               const float* __restrict__ bias1, const float* __restrict__ bias2,
               int bsplit,
               float* __restrict__ C, int ldc, int Nn, int act,
               ushort* __restrict__ Cb, int ldcb)
{
  constexpr int ASTR = LIMBS*32 + 8;
  constexpr int CB = (NT == 128) ? 4 : 2;
  __shared__ __align__(16) ushort Alds[64*ASTR];
  const float* A1 = (const float*)A1v;
  const ushort* Ab = (const ushort*)A1v;

  const int K = K1 + K2;
  const int ntiles = (K + 31) >> 5;
  const int t = threadIdx.x;
  const int bm0 = blockIdx.x * 64;
  const int col0 = blockIdx.y * NT;
  const int lane = t & 63;
  const int wid  = t >> 6;
  const int wr = (wid >> 1) * 32;
  const int wc = (wid & 1) * (NT/2);
  const int frow = lane & 15;
  const int fk   = (lane >> 4) * 8;
  const int a_row = t >> 2;            // 0..63
  const int a_kh  = (t & 3) * 8;       // 0,8,16,24
  const size_t rr = (size_t)(bm0 + a_row);

  float v[8];
  short8v pb0;

  auto loadreg = [&](int kt){
    const int k0 = kt * 32;
    if (ABF){
      if (k0 + a_kh + 7 < K){
        pb0 = *(const short8v*)&Ab[rr*lda1 + k0 + a_kh];
      } else {
        #pragma unroll
        for (int j = 0; j < 8; ++j){
          int ka = k0 + a_kh + j;
          pb0[j] = (ka < K) ? (short)Ab[rr*lda1 + ka] : (short)0;
        }
      }
    } else {
      #pragma unroll
      for (int j = 0; j < 8; ++j){
        int ka = k0 + a_kh + j;
        float xv = 0.f;
        if (ka < K)
          xv = (ka < K1) ? A1[rr*lda1 + ka] : A2[rr*lda2 + (ka - K1)];
        v[j] = xv;
      }
    }
  };
  auto storelds = [&](){
    if (ABF){
      *(short8v*)&Alds[a_row*ASTR + a_kh] = pb0;
    } else {
      #pragma unroll
      for (int l = 0; l < LIMBS; ++l){
        short8v q0;
        #pragma unroll
        for (int j = 0; j < 8; ++j){
          ushort b = f2bf(v[j]); v[j] -= bf2f(b); q0[j] = (short)b;
        }
        *(short8v*)&Alds[a_row*ASTR + l*32 + a_kh] = q0;
      }
    }
  };

  f32x4 acc[2][CB];
  #pragma unroll
  for (int i = 0; i < 2; ++i)
    #pragma unroll
    for (int j = 0; j < CB; ++j)
      acc[i][j] = (f32x4){0.f, 0.f, 0.f, 0.f};

  loadreg(0);
  for (int kt = 0; kt < ntiles; ++kt){
    __syncthreads();
    storelds();
    if (kt + 1 < ntiles) loadreg(kt + 1);
    __syncthreads();
    #pragma unroll
    for (int lA = 0; lA < LIMBS; ++lA){
      short8v af[2];
      #pragma unroll
      for (int rb = 0; rb < 2; ++rb)
        af[rb] = *(const short8v*)&Alds[(wr + rb*16 + frow)*ASTR + lA*32 + fk];
      #pragma unroll
      for (int lB = 0; lB < LIMBS - lA; ++lB){
        const ushort* bbase = BL + ((long long)(lB*ntiles + kt)*ncp)*32;
        short8v bfr[CB];
        #pragma unroll
        for (int cb = 0; cb < CB; ++cb){
          int col = col0 + wc + cb*16 + frow;
          bfr[cb] = *(const short8v*)&bbase[(long long)col*32 + fk];
        }
        #pragma unroll
        for (int rb = 0; rb < 2; ++rb)
          #pragma unroll
          for (int cb = 0; cb < CB; ++cb)
            acc[rb][cb] = __builtin_amdgcn_mfma_f32_16x16x32_bf16(
                af[rb], bfr[cb], acc[rb][cb], 0, 0, 0);
      }
    }
  }

  const int lr4 = (lane >> 4) * 4;
  #pragma unroll
  for (int rb = 0; rb < 2; ++rb){
    #pragma unroll
    for (int cb = 0; cb < CB; ++cb){
      const int col = col0 + wc + cb*16 + frow;
      if (col < Nn){
        float bv = 0.f;
        if (bias1) bv = (col < bsplit) ? bias1[col] : bias2[col - bsplit];
        #pragma unroll
        for (int ri = 0; ri < 4; ++ri){
          const size_t row = (size_t)(bm0 + wr + rb*16 + lr4 + ri);
          float vv = acc[rb][cb][ri];
          if (bias1) vv += bv;
          if (act == 1) vv = (vv > 0.f) ? vv : expm1f(vv);
          C[row*ldc + col] = vv;
          if (Cb) Cb[row*(size_t)ldcb + col] = f2bf(vv);
        }
      }
    }
  }
}

// ---------------------------------------------------------------------------
// FUSED: o = [cur|agg]@Wo + bo (K=192, 3-limb) -> nxt f32 + featb bf16, then
// proj = o @ Wpj + [bh|bs] (K=128, 3-limb, in-LDS A) -> projb.
// Bit-exact vs separate kernels: same limb chains, same MFMA order.
// ---------------------------------------------------------------------------
__global__ __launch_bounds__(256)
void fused_wo_proj(const float* __restrict__ cur,
                   const float* __restrict__ agg,
                   const ushort* __restrict__ BLwo,     // ncp 128, ntiles 6
                   const float* __restrict__ cbo_,
                   const ushort* __restrict__ BLpj,     // ncp 64, ntiles 4
                   const float* __restrict__ cbh_, const float* __restrict__ cbs_,
                   float* __restrict__ nxt,
                   ushort* __restrict__ fslot, int ldcb,
                   float* __restrict__ projb_)
{
  constexpr int ASTR = 104;                  // 3*32+8
  __shared__ __align__(16) ushort Alds[64*ASTR];     // 13.3 KB
  __shared__ __align__(16) ushort PL[64*4*104];      // 53.2 KB: [row][kt*104+l*32+kk]

  const int t = threadIdx.x;
  const int bm0 = blockIdx.x * 64;
  const int lane = t & 63;
  const int wid  = t >> 6;
  const int wr = (wid >> 1) * 32;
  const int wc = (wid & 1) * 64;
  const int frow = lane & 15;
  const int fk   = (lane >> 4) * 8;
  const int lr4  = (lane >> 4) * 4;
  const int a_row = t >> 2;
  const int a_kh  = (t & 3) * 8;
  const size_t rr = (size_t)(bm0 + a_row);

  float v[8];
  auto loadreg = [&](int kt){
    const int k0 = kt * 32;
    #pragma unroll
    for (int j = 0; j < 8; ++j){
      int ka = k0 + a_kh + j;
      v[j] = (ka < EMB) ? cur[rr*EMB + ka] : agg[rr*AGGW + (ka - EMB)];
    }
  };
  auto storelds = [&](){
    #pragma unroll
    for (int l = 0; l < 3; ++l){
      short8v q0;
      #pragma unroll
      for (int j = 0; j < 8; ++j){
        ushort b = f2bf(v[j]); v[j] -= bf2f(b); q0[j] = (short)b;
      }
      *(short8v*)&Alds[a_row*ASTR + l*32 + a_kh] = q0;
    }
  };

  f32x4 acc[2][4];
  #pragma unroll
  for (int i = 0; i < 2; ++i)
    #pragma unroll
    for (int j = 0; j < 4; ++j)
      acc[i][j] = (f32x4){0.f, 0.f, 0.f, 0.f};

  loadreg(0);
  for (int kt = 0; kt < 6; ++kt){
    __syncthreads();
    storelds();
    if (kt + 1 < 6) loadreg(kt + 1);
    __syncthreads();
    #pragma unroll
    for (int lA = 0; lA < 3; ++lA){
      short8v af[2];
      #pragma unroll
      for (int rb = 0; rb < 2; ++rb)
        af[rb] = *(const short8v*)&Alds[(wr + rb*16 + frow)*ASTR + lA*32 + fk];
      #pragma unroll
      for (int lB = 0; lB < 3 - lA; ++lB){
        const ushort* bbase = BLwo + ((long long)(lB*6 + kt)*128)*32;
        short8v bfr[4];
        #pragma unroll
        for (int cb = 0; cb < 4; ++cb){
          int col = wc + cb*16 + frow;
          bfr[cb] = *(const short8v*)&bbase[(long long)col*32 + fk];
        }
        #pragma unroll
        for (int rb = 0; rb < 2; ++rb)
          #pragma unroll
          for (int cb = 0; cb < 4; ++cb)
            acc[rb][cb] = __builtin_amdgcn_mfma_f32_16x16x32_bf16(
                af[rb], bfr[cb], acc[rb][cb], 0, 0, 0);
      }
    }
  }
  __syncthreads();   // Alds done; PL about to be written

  // epilogue-1: write nxt/featb, stage limbs of o into PL
  #pragma unroll
  for (int rb = 0; rb < 2; ++rb){
    #pragma unroll
    for (int cb = 0; cb < 4; ++cb){
      const int col = wc + cb*16 + frow;
      const float bv = cbo_[col];
      #pragma unroll
      for (int ri = 0; ri < 4; ++ri){
        const int lr = wr + rb*16 + lr4 + ri;
        const size_t row = (size_t)(bm0 + lr);
        float vv = acc[rb][cb][ri] + bv;
        nxt[row*EMB + col] = vv;
        fslot[row*(size_t)ldcb + col] = f2bf(vv);
        ushort l0 = f2bf(vv); float r0 = vv - bf2f(l0);
        ushort l1 = f2bf(r0); r0 -= bf2f(l1);
        ushort l2 = f2bf(r0);
        const int kt2 = col >> 5, kk = col & 31;
        PL[lr*416 + kt2*104 + kk]      = l0;
        PL[lr*416 + kt2*104 + 32 + kk] = l1;
        PL[lr*416 + kt2*104 + 64 + kk] = l2;
      }
    }
  }
  __syncthreads();

  // proj: wave wid handles rows r0..r0+15, cols 0..63 of pool2
  const int r0 = wid * 16;
  f32x4 p[4];
  #pragma unroll
  for (int j = 0; j < 4; ++j) p[j] = (f32x4){0.f, 0.f, 0.f, 0.f};
  for (int kt2 = 0; kt2 < 4; ++kt2){
    #pragma unroll
    for (int lA = 0; lA < 3; ++lA){
      short8v af = *(const short8v*)&PL[(r0 + frow)*416 + kt2*104 + lA*32 + fk];
      #pragma unroll
      for (int lB = 0; lB < 3 - lA; ++lB){
        const ushort* bb = BLpj + ((long long)(lB*4 + kt2)*64)*32;
        #pragma unroll
        for (int cb = 0; cb < 4; ++cb){
          short8v bf_ = *(const short8v*)&bb[(long long)(cb*16 + frow)*32 + fk];
          p[cb] = __builtin_amdgcn_mfma_f32_16x16x32_bf16(af, bf_, p[cb], 0, 0, 0);
        }
      }
    }
  }
  #pragma unroll
  for (int cb = 0; cb < 4; ++cb){
    const int col = cb*16 + frow;
    if (col < PRJW){
      const float bv = (col < PROP) ? cbh_[col] : cbs_[col - PROP];
      #pragma unroll
      for (int ri = 0; ri < 4; ++ri){
        const size_t row = (size_t)(bm0 + r0 + lr4 + ri);
        projb_[row*PRJW + col] = p[cb][ri] + bv;
      }
    }
  }
}

// ---------------------------------------------------------------------------
// f32 register-tiled GEMM — only for the tiny final head projections.
// ---------------------------------------------------------------------------
template<int BM, int BN, int BK, int TM, int TN>
__global__ __launch_bounds__(256)
void gemm_tile_kernel(const float* __restrict__ A1, int lda1, int K1,
                      const float* __restrict__ W, const float* __restrict__ bias,
                      float* __restrict__ C, int ldc, int Nn, int act,
                      const float* __restrict__ addx, int addx_ld, int addx_off)
{
  constexpr int LDA = BM + 4;
  constexpr int LDB = BN + 4;
  constexpr int APASS = (BM*BK)/1024;
  constexpr int BPASS = (BN*BK)/1024;
  constexpr int AROWS = 256/(BK/4);
  constexpr int BROWS = 256/(BN/4);
  __shared__ float As[BK*LDA];
  __shared__ float Bs[BK*LDB];
  const int K = K1;
  const int t = threadIdx.x;
  const int bm0 = blockIdx.x * BM;
  const int bn0 = blockIdx.y * BN;
  const int tx = t % 16;
  const int ty = t / 16;
  const int a_r = t / (BK/4);
  const int a_k = 4 * (t % (BK/4));
  const int b_c = t % (BN/4);
  const int b_k = t / (BN/4);

  float ar[APASS][4], br[BPASS][4];
  auto load_tile = [&](int k0){
    #pragma unroll
    for (int p = 0; p < APASS; ++p){
      size_t rr = (size_t)(bm0 + a_r + p*AROWS);
      #pragma unroll
      for (int j = 0; j < 4; ++j){
        int ka = k0 + a_k + j;
        ar[p][j] = (ka < K) ? A1[rr*lda1 + ka] : 0.f;
      }
    }
    #pragma unroll
    for (int p = 0; p < BPASS; ++p){
      int kb = k0 + b_k + p*BROWS;
      #pragma unroll
      for (int j = 0; j < 4; ++j){
        int col = bn0 + 4*b_c + j;
        br[p][j] = (kb < K && col < Nn) ? W[(size_t)kb*Nn + col] : 0.f;
      }
    }
  };
  auto store_tile = [&](){
    #pragma unroll
    for (int p = 0; p < APASS; ++p)
      #pragma unroll
      for (int j = 0; j < 4; ++j)
        As[(a_k + j)*LDA + a_r + p*AROWS] = ar[p][j];
    #pragma unroll
    for (int p = 0; p < BPASS; ++p)
      *(float4*)&Bs[(b_k + p*BROWS)*LDB + 4*b_c] =
          make_float4(br[p][0], br[p][1], br[p][2], br[p][3]);
  };

  float acc[TM][TN];
  #pragma unroll
  for (int i = 0; i < TM; ++i)
    #pragma unroll
    for (int j = 0; j < TN; ++j) acc[i][j] = 0.f;

  auto compute_tile = [&](){
    #pragma unroll
    for (int kk = 0; kk < BK; ++kk){
      float a[TM], b[TN];
      #pragma unroll
      for (int iq = 0; iq < TM/4; ++iq){
        float4 v = *(const float4*)&As[kk*LDA + iq*(BM/2) + 4*ty];
        a[iq*4+0] = v.x; a[iq*4+1] = v.y; a[iq*4+2] = v.z; a[iq*4+3] = v.w;
      }
      #pragma unroll
      for (int jq = 0; jq < TN/4; ++jq){
        float4 v = *(const float4*)&Bs[kk*LDB + jq*(BN/2) + 4*tx];
        b[jq*4+0] = v.x; b[jq*4+1] = v.y; b[jq*4+2] = v.z; b[jq*4+3] = v.w;
      }
      #pragma unroll
      for (int i = 0; i < TM; ++i)
        #pragma unroll
        for (int j = 0; j < TN; ++j)
          acc[i][j] += a[i]*b[j];
    }
  };

  const int ntiles = (K + BK - 1)/BK;
  load_tile(0); store_tile(); __syncthreads();
  for (int tt = 1; tt < ntiles; ++tt){
    load_tile(tt*BK);
    compute_tile();
    __syncthreads();
    store_tile();
    __syncthreads();
  }
  compute_tile();

  #pragma unroll
  for (int i = 0; i < TM; ++i){
    size_t row = (size_t)(bm0 + (i/4)*(BM/2) + 4*ty + (i%4));
    #pragma unroll
    for (int j = 0; j < TN; ++j){
      int col = bn0 + (j/4)*(BN/2) + 4*tx + (j%4);
      if (col < Nn){
        float v = acc[i][j];
        if (bias) v += bias[col];
        if (act == 1) v = (v > 0.f) ? v : expm1f(v);
        if (addx) v += addx[row*addx_ld + addx_off + col];
        C[row*ldc + col] = v;
      }
    }
  }
}

// ---------------------------------------------------------------------------
// kNN + aggregation, 4-wave split-scan. XCD-co-located: g = bid & 63 so all
// 16 segs of a graph share one XCD's L2 (dispatch slot mod 8 == g mod 8).
// ---------------------------------------------------------------------------
__global__ __launch_bounds__(256)
void knn_agg_kernel(const float* __restrict__ proj, float* __restrict__ agg)
{
  __shared__ float4 ssv[GS];
  __shared__ float  sn2[GS];
  __shared__ float  cd[4][64][KNN];
  __shared__ int    ci[4][64][KNN];
  __shared__ float  wl[64][KNN];

  const int g   = blockIdx.x & 63;
  const int seg = blockIdx.x >> 6;
  const int t = threadIdx.x;
  const int wave = t >> 6;
  const int lane = t & 63;

  const float* pg = proj + (size_t)g*GS*PRJW;
  for (int i = t; i < GS; i += 256){
    float4 v = *(const float4*)(pg + (size_t)i*PRJW + PROP);
    ssv[i] = v;
    sn2[i] = v.x*v.x + v.y*v.y + v.z*v.z + v.w*v.w;
  }
  __syncthreads();

  const int i = seg*64 + lane;
  float4 sv = ssv[i];
  float myn2 = sn2[i];
  float si0 = sv.x, si1 = sv.y, si2 = sv.z, si3 = sv.w;

  float bd[KNN]; int bi[KNN];
  #pragma unroll
  for (int k = 0; k < KNN; ++k){ bd[k] = 1e30f; bi[k] = 0; }

  const int jbeg = wave * 256;
  for (int j0 = jbeg; j0 < jbeg + 256; j0 += 8){
    float dv[8];
    #pragma unroll
    for (int u = 0; u < 8; ++u){
      float4 sj = ssv[j0+u];
      float dot = si0*sj.x + si1*sj.y + si2*sj.z + si3*sj.w;
      dv[u] = myn2 + sn2[j0+u] - 2.f*dot;
    }
    float mn = fminf(fminf(fminf(dv[0],dv[1]), fminf(dv[2],dv[3])),
                     fminf(fminf(dv[4],dv[5]), fminf(dv[6],dv[7])));
    if (mn < bd[KNN-1]){
      #pragma unroll
      for (int u = 0; u < 8; ++u){
        float d2 = dv[u];
        if (d2 < bd[KNN-1]){
          int j = j0 + u;
          #pragma unroll
          for (int q = KNN-1; q >= 1; --q){
            bool cq = d2 < bd[q];
            bool cp = d2 < bd[q-1];
            float nv = cp ? bd[q-1] : d2;
            int   ni = cp ? bi[q-1] : j;
            if (cq){ bd[q] = nv; bi[q] = ni; }
          }
          if (d2 < bd[0]){ bd[0] = d2; bi[0] = j; }
        }
      }
    }
  }
  #pragma unroll
  for (int k = 0; k < KNN; ++k){ cd[wave][lane][k] = bd[k]; ci[wave][lane][k] = bi[k]; }
  __syncthreads();

  if (wave == 0){
    #pragma unroll
    for (int c = 1; c < 4; ++c){
      #pragma unroll
      for (int k = 0; k < KNN; ++k){
        float d2 = cd[c][lane][k];
        if (d2 < bd[KNN-1]){
          int j = ci[c][lane][k];
          #pragma unroll
          for (int q = KNN-1; q >= 1; --q){
            bool cq = d2 < bd[q];
            bool cp = d2 < bd[q-1];
            float nv = cp ? bd[q-1] : d2;
            int   ni = cp ? bi[q-1] : j;
            if (cq){ bd[q] = nv; bi[q] = ni; }
          }
          if (d2 < bd[0]){ bd[0] = d2; bi[0] = j; }
        }
      }
    }
    #pragma unroll
    for (int k = 0; k < KNN; ++k){ cd[0][lane][k] = bd[k]; ci[0][lane][k] = bi[k]; }
  }
  __syncthreads();

  {
    const int r = t & 63;
    float4 si_ = ssv[seg*64 + r];
    #pragma unroll
    for (int kx = (t >> 6); kx < KNN; kx += 4){
      int j = ci[0][r][kx];
      float4 sj = ssv[j];
      float d0 = si_.x - sj.x, d1 = si_.y - sj.y;
      float d2_ = si_.z - sj.z, d3 = si_.w - sj.w;
      float dd = d0*d0 + d1*d1 + d2_*d2_ + d3*d3;
      wl[r][kx] = expf(-10.f*dd);
    }
  }
  __syncthreads();

  {
    const int r = t & 63;
    const int q = t >> 6;
    float msum[8], mmax[8];
    #pragma unroll
    for (int u = 0; u < 8; ++u){ msum[u] = 0.f; mmax[u] = -1e30f; }
    #pragma unroll
    for (int k = 0; k < KNN; ++k){
      int j = ci[0][r][k];
      float wk = wl[r][k];
      const float* hr = pg + (size_t)j*PRJW + q*8;
      float4 h0 = *(const float4*)(hr);
      float4 h1 = *(const float4*)(hr + 4);
      float v0 = h0.x*wk, v1 = h0.y*wk, v2 = h0.z*wk, v3 = h0.w*wk;
      float v4 = h1.x*wk, v5 = h1.y*wk, v6 = h1.z*wk, v7 = h1.w*wk;
      msum[0]+=v0; mmax[0]=fmaxf(mmax[0],v0);
      msum[1]+=v1; mmax[1]=fmaxf(mmax[1],v1);
      msum[2]+=v2; mmax[2]=fmaxf(mmax[2],v2);
      msum[3]+=v3; mmax[3]=fmaxf(mmax[3],v3);
      msum[4]+=v4; mmax[4]=fmaxf(mmax[4],v4);
      msum[5]+=v5; mmax[5]=fmaxf(mmax[5],v5);
      msum[6]+=v6; mmax[6]=fmaxf(mmax[6],v6);
      msum[7]+=v7; mmax[7]=fmaxf(mmax[7],v7);
    }
    float* arow = agg + ((size_t)g*GS + seg*64 + r)*AGGW;
    #pragma unroll
    for (int u = 0; u < 8; ++u){
      arow[q*8 + u]        = msum[u]*(1.f/KNN);
      arow[PROP + q*8 + u] = mmax[u];
    }
  }
}

// ---------------------------------------------------------------------------
extern "C" void kernel_launch(void* const* d_in, const int* in_sizes, int n_in,
                              void* d_out, int out_size, void* d_ws, size_t ws_size,
                              hipStream_t stream)
{
  const float* x     = (const float*)d_in[0];
  const float* n0W1  = (const float*)d_in[2];
  const float* n0b1  = (const float*)d_in[3];
  const float* n0W23 = (const float*)d_in[4];
  const float* n0b23 = (const float*)d_in[5];
  const float* n0W4  = (const float*)d_in[6];
  const float* n0b4  = (const float*)d_in[7];
  const float* cWh   = (const float*)d_in[8];
  const float* cbh   = (const float*)d_in[9];
  const float* cWs   = (const float*)d_in[10];
  const float* cbs   = (const float*)d_in[11];
  const float* cWo   = (const float*)d_in[12];
  const float* cbo   = (const float*)d_in[13];
  const float* HW1   = (const float*)d_in[14];
  const float* Hb1   = (const float*)d_in[15];
  const float* HW23  = (const float*)d_in[16];
  const float* Hb23  = (const float*)d_in[17];
  const float* Wid   = (const float*)d_in[18];
  const float* bid   = (const float*)d_in[19];
  const float* Wreg  = (const float*)d_in[20];
  const float* breg  = (const float*)d_in[21];
  const float* Wch   = (const float*)d_in[22];
  const float* bch   = (const float*)d_in[23];
  float* out = (float*)d_out;
  (void)in_sizes; (void)n_in; (void)out_size;

  char* wsp = (char*)d_ws;
  ushort* featb = (ushort*)(wsp);                        // N x 680 bf16
  float* P     = (float*)(wsp + 89128960);               // N x 128
  float* Q     = (float*)(wsp + 122683392);              // N x 128
  float* projb = (float*)(wsp + 156237824);              // N x 36
  float* aggb  = (float*)(wsp + 165675008);              // N x 64
  ushort* pool = (ushort*)(wsp + 182452224);
  float* hacc  = P;
  float* t1    = (float*)wsp;

  WDescs DS{};
  long long woff = 0; int nd = 0;
  auto addm = [&](const float* s1, const float* s2, int ld1, int ld2,
                  int nc1, int K, int Nn, int limbs, int nalign)->long long {
    int ntiles = (K + 31) >> 5;
    int ncp = (Nn + nalign - 1) & ~(nalign - 1);
    long long o = woff;
    DS.d[nd].s1 = s1; DS.d[nd].s2 = s2; DS.d[nd].ld1 = ld1; DS.d[nd].ld2 = ld2;
    DS.d[nd].nc1 = nc1; DS.d[nd].K = K; DS.d[nd].Nn = Nn; DS.d[nd].limbs = limbs;
    DS.d[nd].ncp = ncp; DS.d[nd].dstoff = o; nd++;
    woff += (long long)limbs * ntiles * ncp * 32;
    return o;
  };
  long long o_e1 = addm(n0W1, nullptr, WIDTH, 0, WIDTH, IN_DIM, WIDTH, 3, 128);
  long long o_e2 = addm(n0W23, nullptr, WIDTH, 0, WIDTH, WIDTH, WIDTH, 3, 128);
  long long o_e3 = addm(n0W23 + WIDTH*WIDTH, nullptr, WIDTH, 0, WIDTH, WIDTH, WIDTH, 3, 128);
  long long o_e4 = addm(n0W4, nullptr, EMB, 0, EMB, WIDTH, EMB, 3, 128);
  long long o_pj[10], o_wo[10];
  for (int p = 0; p < 10; ++p){
    o_pj[p] = addm(cWh + (size_t)p*EMB*PROP, cWs + (size_t)p*EMB*SPACE,
                   PROP, SPACE, PROP, EMB, PRJW, 3, 64);
    o_wo[p] = addm(cWo + (size_t)p*CATW*EMB, nullptr, EMB, 0, EMB, CATW, EMB, 3, 128);
  }
  long long o_L1s0  = addm(HW1, nullptr, WIDTH, 0, WIDTH, FEAT, WIDTH, 1, 128);
  long long o_L1s12 = addm(HW1 + (size_t)1*FEAT*WIDTH, HW1 + (size_t)2*FEAT*WIDTH,
                           WIDTH, WIDTH, WIDTH, FEAT, 2*WIDTH, 1, 128);
  long long o_hh[6];
  for (int q = 0; q < 6; ++q)
    o_hh[q] = addm(HW23 + (size_t)q*WIDTH*WIDTH, nullptr, WIDTH, 0, WIDTH, WIDTH, WIDTH, 1, 128);

  long long E_off = ((182452224LL + woff*2) + 255) & ~255LL;
  bool haveE = (E_off + (long long)N_TOT*EMB*4 <= (long long)ws_size);
  float* E = (float*)(wsp + E_off);

  hipLaunchKernelGGL(conv_weights_kernel, dim3(176, NMAT), dim3(256), 0, stream, DS, pool);

  auto gemmM = [&](int limbs, int abf, int nt, const void* A1, int lda1, int K1,
                   const float* A2, int lda2, int K2,
                   long long boff, int ncp,
                   const float* b1, const float* b2, int bsplit,
                   float* C, int ldc, int Nn, int act,
                   ushort* Cb, int ldcb){
    dim3 grid(N_TOT/64, ncp/nt);
    if (limbs == 3 && nt == 64)
      hipLaunchKernelGGL((mfma_gemm<3,0,64>), grid, dim3(256), 0, stream,
          A1, lda1, K1, A2, lda2, K2, pool + boff, ncp, b1, b2, bsplit,
          C, ldc, Nn, act, Cb, ldcb);
    else if (limbs == 3)
      hipLaunchKernelGGL((mfma_gemm<3,0,128>), grid, dim3(256), 0, stream,
          A1, lda1, K1, A2, lda2, K2, pool + boff, ncp, b1, b2, bsplit,
          C, ldc, Nn, act, Cb, ldcb);
    else if (abf)
      hipLaunchKernelGGL((mfma_gemm<1,1,128>), grid, dim3(256), 0, stream,
          A1, lda1, K1, A2, lda2, K2, pool + boff, ncp, b1, b2, bsplit,
          C, ldc, Nn, act, Cb, ldcb);
    else
      hipLaunchKernelGGL((mfma_gemm<1,0,128>), grid, dim3(256), 0, stream,
          A1, lda1, K1, A2, lda2, K2, pool + boff, ncp, b1, b2, bsplit,
          C, ldc, Nn, act, Cb, ldcb);
  };
  auto gemmS = [&](const float* A1, int lda1, int K1,
                   const float* W, const float* b,
                   float* C, int ldc, int Nn, int act,
                   const float* addx, int addx_ld, int addx_off){
    dim3 grid(N_TOT/64, (Nn+63)/64);
    hipLaunchKernelGGL((gemm_tile_kernel<64,64,32,4,4>), grid, dim3(256), 0, stream,
        A1, lda1, K1, W, b, C, ldc, Nn, act, addx, addx_ld, addx_off);
  };
  const int BIG = 1 << 30;

  auto run_embedding = [&](float* dst){
    gemmM(3,0,128, x, IN_DIM, IN_DIM, nullptr,0,0, o_e1, 128, n0b1, nullptr, BIG,
          Q, EMB, WIDTH, 1, nullptr, 0);
    gemmM(3,0,128, Q, EMB, WIDTH, nullptr,0,0, o_e2, 128, n0b23, nullptr, BIG,
          P, EMB, WIDTH, 1, nullptr, 0);
    gemmM(3,0,128, P, EMB, WIDTH, nullptr,0,0, o_e3, 128, n0b23 + WIDTH, nullptr, BIG,
          Q, EMB, WIDTH, 1, nullptr, 0);
    gemmM(3,0,128, Q, EMB, WIDTH, nullptr,0,0, o_e4, 128, n0b4, nullptr, BIG,
          dst, EMB, EMB, 0, nullptr, 0);
  };

  if (haveE) run_embedding(E);

  for (int s = 0; s < 2; ++s){
    hipLaunchKernelGGL(xconv_kernel, dim3((N_TOT*IN_DIM + 255)/256), dim3(256),
                       0, stream, x, featb);
    if (!haveE) run_embedding(P);

    float* cur = haveE ? E : P;
    float* b0  = haveE ? P : Q;
    float* b1  = haveE ? Q : P;

    // standalone h|s projection of the stack's first conv input
    gemmM(3,0,64, cur, EMB, EMB, nullptr,0,0, o_pj[s*NCONV], 64,
          cbh + (s*NCONV)*PROP, cbs + (s*NCONV)*SPACE, PROP,
          projb, PRJW, PRJW, 0, nullptr, 0);

    for (int cv = 0; cv < NCONV; ++cv){
      int pidx = s*NCONV + cv;
      float* nxt = (cv & 1) ? b1 : b0;
      // kNN + aggregate on this conv's projections
      hipLaunchKernelGGL(knn_agg_kernel, dim3(NG*16), dim3(256), 0, stream,
                         projb, aggb);
      if (cv < NCONV-1){
        // fused: o_cv (wo) -> nxt + featb, then next conv's h|s proj -> projb
        int pnx = pidx + 1;
        hipLaunchKernelGGL(fused_wo_proj, dim3(N_TOT/64), dim3(256), 0, stream,
            cur, aggb, pool + o_wo[pidx], cbo + pidx*EMB,
            pool + o_pj[pnx], cbh + pnx*PROP, cbs + pnx*SPACE,
            nxt, featb + IN_DIM + cv*EMB, FLDB, projb);
      } else {
        // last conv: wo only
        gemmM(3,0,128, cur, EMB, EMB, aggb, AGGW, AGGW, o_wo[pidx], 128,
              cbo + pidx*EMB, nullptr, BIG, nxt, EMB, EMB, 0,
              featb + IN_DIM + cv*EMB, FLDB);
      }
      cur = nxt;
    }

    // head layer-1: one K=674 GEMM from featb (bf16 A), bias+ELU fused
    if (s == 0){
      gemmM(1,1,128, featb, FLDB, FEAT, nullptr,0,0, o_L1s0, 128,
            Hb1, nullptr, BIG, hacc, WIDTH, WIDTH, 1, nullptr, 0);
    } else {
      gemmM(1,1,128, featb, FLDB, FEAT, nullptr,0,0, o_L1s12, 256,
            Hb1 + WIDTH, Hb1 + 2*WIDTH, WIDTH,
            hacc, 2*WIDTH, 2*WIDTH, 1, nullptr, 0);
    }

    auto finish_head = [&](int hidx, float* ha, int lda_ha,
                           float* dst, int dst_ld, int out_dim,
                           const float* Wl, const float* bl,
                           const float* addx, int addx_ld, int addx_off){
      gemmM(1,0,128, ha, lda_ha, WIDTH, nullptr,0,0, o_hh[hidx*2+0], 128,
            Hb23 + (hidx*2+0)*WIDTH, nullptr, BIG,
            t1, WIDTH, WIDTH, 1, nullptr, 0);
      gemmM(1,0,128, t1, WIDTH, WIDTH, nullptr,0,0, o_hh[hidx*2+1], 128,
            Hb23 + (hidx*2+1)*WIDTH, nullptr, BIG,
            ha, lda_ha, WIDTH, 1, nullptr, 0);
      gemmS(ha, lda_ha, WIDTH, Wl, bl, dst, dst_ld, out_dim, 0,
            addx, addx_ld, addx_off);
    };

    if (s == 0){
      finish_head(0, hacc, WIDTH, out, 8, 8, Wid, bid, nullptr, 0, 0);
    } else {
      finish_head(1, hacc, 2*WIDTH, out + (size_t)N_TOT*8, 4, 4,
                  Wreg, breg, x, IN_DIM, 1);
      finish_head(2, hacc + WIDTH, 2*WIDTH, out + (size_t)N_TOT*12, 1, 1,
                  Wch, bch, nullptr, 0, 0);
    }
  }
}

// Round 15
// 1885.456 us; speedup vs baseline: 11.3927x; 1.0006x over previous
//
#include <hip/hip_runtime.h>
#include <hip/hip_bf16.h>
#include <cstdint>

#define N_TOT 65536
#define NG 64
#define GS 1024
#define IN_DIM 34
#define WIDTH 126
#define EMB 128
#define PROP 32
#define SPACE 4
#define KNN 8
#define NCONV 5
#define FEAT (IN_DIM + NCONV*EMB)   /* 674 */
#define FLDB 680                    /* featb bf16 leading dim */
#define CATW (EMB + 2*PROP)         /* 192 */
#define AGGW (2*PROP)               /* 64 */
#define PRJW 36                     /* h(32) | s(4) */

typedef unsigned short ushort;
typedef __attribute__((ext_vector_type(8))) short short8v;
typedef __attribute__((ext_vector_type(4))) float f32x4;

__device__ __forceinline__ ushort f2bf(float f){
  unsigned int u = __float_as_uint(f);
  unsigned int r = (u + 0x7FFFu + ((u >> 16) & 1u)) >> 16;
  return (ushort)r;
}
__device__ __forceinline__ float bf2f(ushort b){
  return __uint_as_float(((unsigned int)b) << 16);
}

// ---------------------------------------------------------------------------
// Weight pre-conversion -> bf16 limb pool [limb][ktile][col(<ncp)][k32].
// ---------------------------------------------------------------------------
struct WDesc {
  const float* s1; const float* s2;
  int ld1, ld2, nc1, K, Nn, limbs, ncp;
  long long dstoff;
};
#define NMAT 32
struct WDescs { WDesc d[NMAT]; };

__global__ __launch_bounds__(256)
void conv_weights_kernel(WDescs DS, ushort* __restrict__ pool)
{
  int m = blockIdx.y;
  WDesc d = DS.d[m];
  if (d.K == 0) return;
  int ntiles = (d.K + 31) >> 5;
  int ncp = d.ncp;
  int nchunk = ncp >> 5;
  int kt = blockIdx.x / nchunk;
  int cc = blockIdx.x % nchunk;
  if (kt >= ntiles) return;
  int t = threadIdx.x;
  int kk = t & 31;
  int k = kt*32 + kk;
  for (int c = (t >> 5); c < 32; c += 8){
    int col = cc*32 + c;
    float v = 0.f;
    if (k < d.K && col < d.Nn)
      v = (col < d.nc1) ? d.s1[(size_t)k*d.ld1 + col]
                        : d.s2[(size_t)k*d.ld2 + (col - d.nc1)];
    for (int l = 0; l < d.limbs; ++l){
      ushort b = f2bf(v); v -= bf2f(b);
      pool[d.dstoff + ((long long)(l*ntiles + kt)*ncp + col)*32 + kk] = b;
    }
  }
}

// ---------------------------------------------------------------------------
// x (f32 N x 34) -> featb bf16 cols 0..33
// ---------------------------------------------------------------------------
__global__ __launch_bounds__(256)
void xconv_kernel(const float* __restrict__ x, ushort* __restrict__ featb)
{
  int idx = blockIdx.x*256 + threadIdx.x;
  if (idx < N_TOT*IN_DIM){
    int r = idx / IN_DIM, c = idx - r*IN_DIM;
    featb[(size_t)r*FLDB + c] = f2bf(x[idx]);
  }
}

// ---------------------------------------------------------------------------
// MFMA bf16 GEMM, LIMBS-limb f32 emulation, BM=64 rows/block, reg-prefetch.
// ABF=1: A already bf16 (LIMBS=1). NT = 128 (waves 2x2, 32r x 64c each) or
// 64 (waves 2x2, 32r x 32c). C = act(A@W + bias[split]); optional bf16 copy.
// ---------------------------------------------------------------------------
template<int LIMBS, int ABF, int NT>
__global__ __launch_bounds__(256)
void mfma_gemm(const void* __restrict__ A1v, int lda1, int K1,
               const float* __restrict__ A2, int lda2, int K2,
               const ushort* __restrict__ BL, int ncp,
               const float* __restrict__ bias1, const float* __restrict__ bias2,
               int bsplit,
               float* __restrict__ C, int ldc, int Nn, int act,
               ushort* __restrict__ Cb, int ldcb)
{
  constexpr int ASTR = LIMBS*32 + 8;
  constexpr int CB = (NT == 128) ? 4 : 2;
  __shared__ __align__(16) ushort Alds[64*ASTR];
  const float* A1 = (const float*)A1v;
  const ushort* Ab = (const ushort*)A1v;

  const int K = K1 + K2;
  const int ntiles = (K + 31) >> 5;
  const int t = threadIdx.x;
  const int bm0 = blockIdx.x * 64;
  const int col0 = blockIdx.y * NT;
  const int lane = t & 63;
  const int wid  = t >> 6;
  const int wr = (wid >> 1) * 32;
  const int wc = (wid & 1) * (NT/2);
  const int frow = lane & 15;
  const int fk   = (lane >> 4) * 8;
  const int a_row = t >> 2;
  const int a_kh  = (t & 3) * 8;
  const size_t rr = (size_t)(bm0 + a_row);

  float v[8];
  short8v pb0;

  auto loadreg = [&](int kt){
    const int k0 = kt * 32;
    if (ABF){
      if (k0 + a_kh + 7 < K){
        pb0 = *(const short8v*)&Ab[rr*lda1 + k0 + a_kh];
      } else {
        #pragma unroll
        for (int j = 0; j < 8; ++j){
          int ka = k0 + a_kh + j;
          pb0[j] = (ka < K) ? (short)Ab[rr*lda1 + ka] : (short)0;
        }
      }
    } else {
      #pragma unroll
      for (int j = 0; j < 8; ++j){
        int ka = k0 + a_kh + j;
        float xv = 0.f;
        if (ka < K)
          xv = (ka < K1) ? A1[rr*lda1 + ka] : A2[rr*lda2 + (ka - K1)];
        v[j] = xv;
      }
    }
  };
  auto storelds = [&](){
    if (ABF){
      *(short8v*)&Alds[a_row*ASTR + a_kh] = pb0;
    } else {
      #pragma unroll
      for (int l = 0; l < LIMBS; ++l){
        short8v q0;
        #pragma unroll
        for (int j = 0; j < 8; ++j){
          ushort b = f2bf(v[j]); v[j] -= bf2f(b); q0[j] = (short)b;
        }
        *(short8v*)&Alds[a_row*ASTR + l*32 + a_kh] = q0;
      }
    }
  };

  f32x4 acc[2][CB];
  #pragma unroll
  for (int i = 0; i < 2; ++i)
    #pragma unroll
    for (int j = 0; j < CB; ++j)
      acc[i][j] = (f32x4){0.f, 0.f, 0.f, 0.f};

  loadreg(0);
  for (int kt = 0; kt < ntiles; ++kt){
    __syncthreads();
    storelds();
    if (kt + 1 < ntiles) loadreg(kt + 1);
    __syncthreads();
    #pragma unroll
    for (int lA = 0; lA < LIMBS; ++lA){
      short8v af[2];
      #pragma unroll
      for (int rb = 0; rb < 2; ++rb)
        af[rb] = *(const short8v*)&Alds[(wr + rb*16 + frow)*ASTR + lA*32 + fk];
      #pragma unroll
      for (int lB = 0; lB < LIMBS - lA; ++lB){
        const ushort* bbase = BL + ((long long)(lB*ntiles + kt)*ncp)*32;
        short8v bfr[CB];
        #pragma unroll
        for (int cb = 0; cb < CB; ++cb){
          int col = col0 + wc + cb*16 + frow;
          bfr[cb] = *(const short8v*)&bbase[(long long)col*32 + fk];
        }
        #pragma unroll
        for (int rb = 0; rb < 2; ++rb)
          #pragma unroll
          for (int cb = 0; cb < CB; ++cb)
            acc[rb][cb] = __builtin_amdgcn_mfma_f32_16x16x32_bf16(
                af[rb], bfr[cb], acc[rb][cb], 0, 0, 0);
      }
    }
  }

  const int lr4 = (lane >> 4) * 4;
  #pragma unroll
  for (int rb = 0; rb < 2; ++rb){
    #pragma unroll
    for (int cb = 0; cb < CB; ++cb){
      const int col = col0 + wc + cb*16 + frow;
      if (col < Nn){
        float bv = 0.f;
        if (bias1) bv = (col < bsplit) ? bias1[col] : bias2[col - bsplit];
        #pragma unroll
        for (int ri = 0; ri < 4; ++ri){
          const size_t row = (size_t)(bm0 + wr + rb*16 + lr4 + ri);
          float vv = acc[rb][cb][ri];
          if (bias1) vv += bv;
          if (act == 1) vv = (vv > 0.f) ? vv : expm1f(vv);
          C[row*ldc + col] = vv;
          if (Cb) Cb[row*(size_t)ldcb + col] = f2bf(vv);
        }
      }
    }
  }
}

// ---------------------------------------------------------------------------
// FUSED: o = [cur|agg]@Wo + bo (K=192, 3-limb) -> nxt f32 + featb bf16, then
// proj = o @ Wpj + [bh|bs] (K=128, 3-limb, in-LDS A) -> projb.
// Bit-exact vs separate kernels: same limb chains, same MFMA order.
// ---------------------------------------------------------------------------
__global__ __launch_bounds__(256)
void fused_wo_proj(const float* __restrict__ cur,
                   const float* __restrict__ agg,
                   const ushort* __restrict__ BLwo,     // ncp 128, ntiles 6
                   const float* __restrict__ cbo_,
                   const ushort* __restrict__ BLpj,     // ncp 64, ntiles 4
                   const float* __restrict__ cbh_, const float* __restrict__ cbs_,
                   float* __restrict__ nxt,
                   ushort* __restrict__ fslot, int ldcb,
                   float* __restrict__ projb_)
{
  constexpr int ASTR = 104;                  // 3*32+8
  __shared__ __align__(16) ushort Alds[64*ASTR];     // 13.3 KB
  __shared__ __align__(16) ushort PL[64*4*104];      // 53.2 KB

  const int t = threadIdx.x;
  const int bm0 = blockIdx.x * 64;
  const int lane = t & 63;
  const int wid  = t >> 6;
  const int wr = (wid >> 1) * 32;
  const int wc = (wid & 1) * 64;
  const int frow = lane & 15;
  const int fk   = (lane >> 4) * 8;
  const int lr4  = (lane >> 4) * 4;
  const int a_row = t >> 2;
  const int a_kh  = (t & 3) * 8;
  const size_t rr = (size_t)(bm0 + a_row);

  float v[8];
  auto loadreg = [&](int kt){
    const int k0 = kt * 32;
    #pragma unroll
    for (int j = 0; j < 8; ++j){
      int ka = k0 + a_kh + j;
      v[j] = (ka < EMB) ? cur[rr*EMB + ka] : agg[rr*AGGW + (ka - EMB)];
    }
  };
  auto storelds = [&](){
    #pragma unroll
    for (int l = 0; l < 3; ++l){
      short8v q0;
      #pragma unroll
      for (int j = 0; j < 8; ++j){
        ushort b = f2bf(v[j]); v[j] -= bf2f(b); q0[j] = (short)b;
      }
      *(short8v*)&Alds[a_row*ASTR + l*32 + a_kh] = q0;
    }
  };

  f32x4 acc[2][4];
  #pragma unroll
  for (int i = 0; i < 2; ++i)
    #pragma unroll
    for (int j = 0; j < 4; ++j)
      acc[i][j] = (f32x4){0.f, 0.f, 0.f, 0.f};

  loadreg(0);
  for (int kt = 0; kt < 6; ++kt){
    __syncthreads();
    storelds();
    if (kt + 1 < 6) loadreg(kt + 1);
    __syncthreads();
    #pragma unroll
    for (int lA = 0; lA < 3; ++lA){
      short8v af[2];
      #pragma unroll
      for (int rb = 0; rb < 2; ++rb)
        af[rb] = *(const short8v*)&Alds[(wr + rb*16 + frow)*ASTR + lA*32 + fk];
      #pragma unroll
      for (int lB = 0; lB < 3 - lA; ++lB){
        const ushort* bbase = BLwo + ((long long)(lB*6 + kt)*128)*32;
        short8v bfr[4];
        #pragma unroll
        for (int cb = 0; cb < 4; ++cb){
          int col = wc + cb*16 + frow;
          bfr[cb] = *(const short8v*)&bbase[(long long)col*32 + fk];
        }
        #pragma unroll
        for (int rb = 0; rb < 2; ++rb)
          #pragma unroll
          for (int cb = 0; cb < 4; ++cb)
            acc[rb][cb] = __builtin_amdgcn_mfma_f32_16x16x32_bf16(
                af[rb], bfr[cb], acc[rb][cb], 0, 0, 0);
      }
    }
  }
  __syncthreads();   // Alds done; PL about to be written

  // epilogue-1: write nxt/featb, stage limbs of o into PL
  #pragma unroll
  for (int rb = 0; rb < 2; ++rb){
    #pragma unroll
    for (int cb = 0; cb < 4; ++cb){
      const int col = wc + cb*16 + frow;
      const float bv = cbo_[col];
      #pragma unroll
      for (int ri = 0; ri < 4; ++ri){
        const int lr = wr + rb*16 + lr4 + ri;
        const size_t row = (size_t)(bm0 + lr);
        float vv = acc[rb][cb][ri] + bv;
        nxt[row*EMB + col] = vv;
        fslot[row*(size_t)ldcb + col] = f2bf(vv);
        ushort l0 = f2bf(vv); float r0 = vv - bf2f(l0);
        ushort l1 = f2bf(r0); r0 -= bf2f(l1);
        ushort l2 = f2bf(r0);
        const int kt2 = col >> 5, kk = col & 31;
        PL[lr*416 + kt2*104 + kk]      = l0;
        PL[lr*416 + kt2*104 + 32 + kk] = l1;
        PL[lr*416 + kt2*104 + 64 + kk] = l2;
      }
    }
  }
  __syncthreads();

  // proj: wave wid handles rows r0..r0+15, cols 0..63
  const int r0 = wid * 16;
  f32x4 p[4];
  #pragma unroll
  for (int j = 0; j < 4; ++j) p[j] = (f32x4){0.f, 0.f, 0.f, 0.f};
  for (int kt2 = 0; kt2 < 4; ++kt2){
    #pragma unroll
    for (int lA = 0; lA < 3; ++lA){
      short8v af = *(const short8v*)&PL[(r0 + frow)*416 + kt2*104 + lA*32 + fk];
      #pragma unroll
      for (int lB = 0; lB < 3 - lA; ++lB){
        const ushort* bb = BLpj + ((long long)(lB*4 + kt2)*64)*32;
        #pragma unroll
        for (int cb = 0; cb < 4; ++cb){
          short8v bf_ = *(const short8v*)&bb[(long long)(cb*16 + frow)*32 + fk];
          p[cb] = __builtin_amdgcn_mfma_f32_16x16x32_bf16(af, bf_, p[cb], 0, 0, 0);
        }
      }
    }
  }
  #pragma unroll
  for (int cb = 0; cb < 4; ++cb){
    const int col = cb*16 + frow;
    if (col < PRJW){
      const float bv = (col < PROP) ? cbh_[col] : cbs_[col - PROP];
      #pragma unroll
      for (int ri = 0; ri < 4; ++ri){
        const size_t row = (size_t)(bm0 + r0 + lr4 + ri);
        projb_[row*PRJW + col] = p[cb][ri] + bv;
      }
    }
  }
}

// ---------------------------------------------------------------------------
// f32 register-tiled GEMM — only for the tiny final head projections.
// ---------------------------------------------------------------------------
template<int BM, int BN, int BK, int TM, int TN>
__global__ __launch_bounds__(256)
void gemm_tile_kernel(const float* __restrict__ A1, int lda1, int K1,
                      const float* __restrict__ W, const float* __restrict__ bias,
                      float* __restrict__ C, int ldc, int Nn, int act,
                      const float* __restrict__ addx, int addx_ld, int addx_off)
{
  constexpr int LDA = BM + 4;
  constexpr int LDB = BN + 4;
  constexpr int APASS = (BM*BK)/1024;
  constexpr int BPASS = (BN*BK)/1024;
  constexpr int AROWS = 256/(BK/4);
  constexpr int BROWS = 256/(BN/4);
  __shared__ float As[BK*LDA];
  __shared__ float Bs[BK*LDB];
  const int K = K1;
  const int t = threadIdx.x;
  const int bm0 = blockIdx.x * BM;
  const int bn0 = blockIdx.y * BN;
  const int tx = t % 16;
  const int ty = t / 16;
  const int a_r = t / (BK/4);
  const int a_k = 4 * (t % (BK/4));
  const int b_c = t % (BN/4);
  const int b_k = t / (BN/4);

  float ar[APASS][4], br[BPASS][4];
  auto load_tile = [&](int k0){
    #pragma unroll
    for (int p = 0; p < APASS; ++p){
      size_t rr = (size_t)(bm0 + a_r + p*AROWS);
      #pragma unroll
      for (int j = 0; j < 4; ++j){
        int ka = k0 + a_k + j;
        ar[p][j] = (ka < K) ? A1[rr*lda1 + ka] : 0.f;
      }
    }
    #pragma unroll
    for (int p = 0; p < BPASS; ++p){
      int kb = k0 + b_k + p*BROWS;
      #pragma unroll
      for (int j = 0; j < 4; ++j){
        int col = bn0 + 4*b_c + j;
        br[p][j] = (kb < K && col < Nn) ? W[(size_t)kb*Nn + col] : 0.f;
      }
    }
  };
  auto store_tile = [&](){
    #pragma unroll
    for (int p = 0; p < APASS; ++p)
      #pragma unroll
      for (int j = 0; j < 4; ++j)
        As[(a_k + j)*LDA + a_r + p*AROWS] = ar[p][j];
    #pragma unroll
    for (int p = 0; p < BPASS; ++p)
      *(float4*)&Bs[(b_k + p*BROWS)*LDB + 4*b_c] =
          make_float4(br[p][0], br[p][1], br[p][2], br[p][3]);
  };

  float acc[TM][TN];
  #pragma unroll
  for (int i = 0; i < TM; ++i)
    #pragma unroll
    for (int j = 0; j < TN; ++j) acc[i][j] = 0.f;

  auto compute_tile = [&](){
    #pragma unroll
    for (int kk = 0; kk < BK; ++kk){
      float a[TM], b[TN];
      #pragma unroll
      for (int iq = 0; iq < TM/4; ++iq){
        float4 v = *(const float4*)&As[kk*LDA + iq*(BM/2) + 4*ty];
        a[iq*4+0] = v.x; a[iq*4+1] = v.y; a[iq*4+2] = v.z; a[iq*4+3] = v.w;
      }
      #pragma unroll
      for (int jq = 0; jq < TN/4; ++jq){
        float4 v = *(const float4*)&Bs[kk*LDB + jq*(BN/2) + 4*tx];
        b[jq*4+0] = v.x; b[jq*4+1] = v.y; b[jq*4+2] = v.z; b[jq*4+3] = v.w;
      }
      #pragma unroll
      for (int i = 0; i < TM; ++i)
        #pragma unroll
        for (int j = 0; j < TN; ++j)
          acc[i][j] += a[i]*b[j];
    }
  };

  const int ntiles = (K + BK - 1)/BK;
  load_tile(0); store_tile(); __syncthreads();
  for (int tt = 1; tt < ntiles; ++tt){
    load_tile(tt*BK);
    compute_tile();
    __syncthreads();
    store_tile();
    __syncthreads();
  }
  compute_tile();

  #pragma unroll
  for (int i = 0; i < TM; ++i){
    size_t row = (size_t)(bm0 + (i/4)*(BM/2) + 4*ty + (i%4));
    #pragma unroll
    for (int j = 0; j < TN; ++j){
      int col = bn0 + (j/4)*(BN/2) + 4*tx + (j%4);
      if (col < Nn){
        float v = acc[i][j];
        if (bias) v += bias[col];
        if (act == 1) v = (v > 0.f) ? v : expm1f(v);
        if (addx) v += addx[row*addx_ld + addx_off + col];
        C[row*ldc + col] = v;
      }
    }
  }
}

// ---------------------------------------------------------------------------
// kNN + aggregation, 4-wave split-scan. XCD-co-located: g = bid & 63 so all
// 16 segs of a graph share one XCD's L2. EXACT round-12 source (proven bits:
// absmax 0.05474854 stable across rounds 9-12).
// ---------------------------------------------------------------------------
__global__ __launch_bounds__(256)
void knn_agg_kernel(const float* __restrict__ proj, float* __restrict__ agg)
{
  __shared__ float4 ssv[GS];
  __shared__ float  sn2[GS];
  __shared__ float  cd[4][64][KNN];
  __shared__ int    ci[4][64][KNN];
  __shared__ float  wl[64][KNN];

  const int g   = blockIdx.x & 63;
  const int seg = blockIdx.x >> 6;
  const int t = threadIdx.x;
  const int wave = t >> 6;
  const int lane = t & 63;

  const float* pg = proj + (size_t)g*GS*PRJW;
  for (int i = t; i < GS; i += 256){
    float4 v = *(const float4*)(pg + (size_t)i*PRJW + PROP);
    ssv[i] = v;
    sn2[i] = v.x*v.x + v.y*v.y + v.z*v.z + v.w*v.w;
  }
  __syncthreads();

  const int i = seg*64 + lane;
  float4 sv = ssv[i];
  float myn2 = sn2[i];
  float si0 = sv.x, si1 = sv.y, si2 = sv.z, si3 = sv.w;

  float bd[KNN]; int bi[KNN];
  #pragma unroll
  for (int k = 0; k < KNN; ++k){ bd[k] = 1e30f; bi[k] = 0; }

  const int jbeg = wave * 256;
  for (int j0 = jbeg; j0 < jbeg + 256; j0 += 8){
    float dv[8];
    #pragma unroll
    for (int u = 0; u < 8; ++u){
      float4 sj = ssv[j0+u];
      float dot = si0*sj.x + si1*sj.y + si2*sj.z + si3*sj.w;
      dv[u] = myn2 + sn2[j0+u] - 2.f*dot;
    }
    float mn = fminf(fminf(fminf(dv[0],dv[1]), fminf(dv[2],dv[3])),
                     fminf(fminf(dv[4],dv[5]), fminf(dv[6],dv[7])));
    if (mn < bd[KNN-1]){
      #pragma unroll
      for (int u = 0; u < 8; ++u){
        float d2 = dv[u];
        if (d2 < bd[KNN-1]){
          int j = j0 + u;
          #pragma unroll
          for (int q = KNN-1; q >= 1; --q){
            bool cq = d2 < bd[q];
            bool cp = d2 < bd[q-1];
            float nv = cp ? bd[q-1] : d2;
            int   ni = cp ? bi[q-1] : j;
            if (cq){ bd[q] = nv; bi[q] = ni; }
          }
          if (d2 < bd[0]){ bd[0] = d2; bi[0] = j; }
        }
      }
    }
  }
  #pragma unroll
  for (int k = 0; k < KNN; ++k){ cd[wave][lane][k] = bd[k]; ci[wave][lane][k] = bi[k]; }
  __syncthreads();

  if (wave == 0){
    #pragma unroll
    for (int c = 1; c < 4; ++c){
      #pragma unroll
      for (int k = 0; k < KNN; ++k){
        float d2 = cd[c][lane][k];
        if (d2 < bd[KNN-1]){
          int j = ci[c][lane][k];
          #pragma unroll
          for (int q = KNN-1; q >= 1; --q){
            bool cq = d2 < bd[q];
            bool cp = d2 < bd[q-1];
            float nv = cp ? bd[q-1] : d2;
            int   ni = cp ? bi[q-1] : j;
            if (cq){ bd[q] = nv; bi[q] = ni; }
          }
          if (d2 < bd[0]){ bd[0] = d2; bi[0] = j; }
        }
      }
    }
    #pragma unroll
    for (int k = 0; k < KNN; ++k){ cd[0][lane][k] = bd[k]; ci[0][lane][k] = bi[k]; }
  }
  __syncthreads();

  {
    const int r = t & 63;
    float4 si_ = ssv[seg*64 + r];
    #pragma unroll
    for (int kx = (t >> 6); kx < KNN; kx += 4){
      int j = ci[0][r][kx];
      float4 sj = ssv[j];
      float d0 = si_.x - sj.x, d1 = si_.y - sj.y;
      float d2_ = si_.z - sj.z, d3 = si_.w - sj.w;
      float dd = d0*d0 + d1*d1 + d2_*d2_ + d3*d3;
      wl[r][kx] = expf(-10.f*dd);
    }
  }
  __syncthreads();

  {
    const int r = t & 63;
    const int q = t >> 6;
    float msum[8], mmax[8];
    #pragma unroll
    for (int u = 0; u < 8; ++u){ msum[u] = 0.f; mmax[u] = -1e30f; }
    #pragma unroll
    for (int k = 0; k < KNN; ++k){
      int j = ci[0][r][k];
      float wk = wl[r][k];
      const float* hr = pg + (size_t)j*PRJW + q*8;
      float4 h0 = *(const float4*)(hr);
      float4 h1 = *(const float4*)(hr + 4);
      float v0 = h0.x*wk, v1 = h0.y*wk, v2 = h0.z*wk, v3 = h0.w*wk;
      float v4 = h1.x*wk, v5 = h1.y*wk, v6 = h1.z*wk, v7 = h1.w*wk;
      msum[0]+=v0; mmax[0]=fmaxf(mmax[0],v0);
      msum[1]+=v1; mmax[1]=fmaxf(mmax[1],v1);
      msum[2]+=v2; mmax[2]=fmaxf(mmax[2],v2);
      msum[3]+=v3; mmax[3]=fmaxf(mmax[3],v3);
      msum[4]+=v4; mmax[4]=fmaxf(mmax[4],v4);
      msum[5]+=v5; mmax[5]=fmaxf(mmax[5],v5);
      msum[6]+=v6; mmax[6]=fmaxf(mmax[6],v6);
      msum[7]+=v7; mmax[7]=fmaxf(mmax[7],v7);
    }
    float* arow = agg + ((size_t)g*GS + seg*64 + r)*AGGW;
    #pragma unroll
    for (int u = 0; u < 8; ++u){
      arow[q*8 + u]        = msum[u]*(1.f/KNN);
      arow[PROP + q*8 + u] = mmax[u];
    }
  }
}

// ---------------------------------------------------------------------------
extern "C" void kernel_launch(void* const* d_in, const int* in_sizes, int n_in,
                              void* d_out, int out_size, void* d_ws, size_t ws_size,
                              hipStream_t stream)
{
  const float* x     = (const float*)d_in[0];
  const float* n0W1  = (const float*)d_in[2];
  const float* n0b1  = (const float*)d_in[3];
  const float* n0W23 = (const float*)d_in[4];
  const float* n0b23 = (const float*)d_in[5];
  const float* n0W4  = (const float*)d_in[6];
  const float* n0b4  = (const float*)d_in[7];
  const float* cWh   = (const float*)d_in[8];
  const float* cbh   = (const float*)d_in[9];
  const float* cWs   = (const float*)d_in[10];
  const float* cbs   = (const float*)d_in[11];
  const float* cWo   = (const float*)d_in[12];
  const float* cbo   = (const float*)d_in[13];
  const float* HW1   = (const float*)d_in[14];
  const float* Hb1   = (const float*)d_in[15];
  const float* HW23  = (const float*)d_in[16];
  const float* Hb23  = (const float*)d_in[17];
  const float* Wid   = (const float*)d_in[18];
  const float* bid   = (const float*)d_in[19];
  const float* Wreg  = (const float*)d_in[20];
  const float* breg  = (const float*)d_in[21];
  const float* Wch   = (const float*)d_in[22];
  const float* bch   = (const float*)d_in[23];
  float* out = (float*)d_out;
  (void)in_sizes; (void)n_in; (void)out_size;

  char* wsp = (char*)d_ws;
  ushort* featb = (ushort*)(wsp);                        // N x 680 bf16
  float* P     = (float*)(wsp + 89128960);               // N x 128
  float* Q     = (float*)(wsp + 122683392);              // N x 128
  float* projb = (float*)(wsp + 156237824);              // N x 36
  float* aggb  = (float*)(wsp + 165675008);              // N x 64
  ushort* pool = (ushort*)(wsp + 182452224);
  float* hacc  = P;
  float* t1    = (float*)wsp;

  WDescs DS{};
  long long woff = 0; int nd = 0;
  auto addm = [&](const float* s1, const float* s2, int ld1, int ld2,
                  int nc1, int K, int Nn, int limbs, int nalign)->long long {
    int ntiles = (K + 31) >> 5;
    int ncp = (Nn + nalign - 1) & ~(nalign - 1);
    long long o = woff;
    DS.d[nd].s1 = s1; DS.d[nd].s2 = s2; DS.d[nd].ld1 = ld1; DS.d[nd].ld2 = ld2;
    DS.d[nd].nc1 = nc1; DS.d[nd].K = K; DS.d[nd].Nn = Nn; DS.d[nd].limbs = limbs;
    DS.d[nd].ncp = ncp; DS.d[nd].dstoff = o; nd++;
    woff += (long long)limbs * ntiles * ncp * 32;
    return o;
  };
  long long o_e1 = addm(n0W1, nullptr, WIDTH, 0, WIDTH, IN_DIM, WIDTH, 3, 128);
  long long o_e2 = addm(n0W23, nullptr, WIDTH, 0, WIDTH, WIDTH, WIDTH, 3, 128);
  long long o_e3 = addm(n0W23 + WIDTH*WIDTH, nullptr, WIDTH, 0, WIDTH, WIDTH, WIDTH, 3, 128);
  long long o_e4 = addm(n0W4, nullptr, EMB, 0, EMB, WIDTH, EMB, 3, 128);
  long long o_pj[10], o_wo[10];
  for (int p = 0; p < 10; ++p){
    o_pj[p] = addm(cWh + (size_t)p*EMB*PROP, cWs + (size_t)p*EMB*SPACE,
                   PROP, SPACE, PROP, EMB, PRJW, 3, 64);
    o_wo[p] = addm(cWo + (size_t)p*CATW*EMB, nullptr, EMB, 0, EMB, CATW, EMB, 3, 128);
  }
  long long o_L1s0  = addm(HW1, nullptr, WIDTH, 0, WIDTH, FEAT, WIDTH, 1, 128);
  long long o_L1s12 = addm(HW1 + (size_t)1*FEAT*WIDTH, HW1 + (size_t)2*FEAT*WIDTH,
                           WIDTH, WIDTH, WIDTH, FEAT, 2*WIDTH, 1, 128);
  long long o_hh[6];
  for (int q = 0; q < 6; ++q)
    o_hh[q] = addm(HW23 + (size_t)q*WIDTH*WIDTH, nullptr, WIDTH, 0, WIDTH, WIDTH, WIDTH, 1, 128);

  long long E_off = ((182452224LL + woff*2) + 255) & ~255LL;
  bool haveE = (E_off + (long long)N_TOT*EMB*4 <= (long long)ws_size);
  float* E = (float*)(wsp + E_off);

  hipLaunchKernelGGL(conv_weights_kernel, dim3(176, NMAT), dim3(256), 0, stream, DS, pool);

  auto gemmM = [&](int limbs, int abf, int nt, const void* A1, int lda1, int K1,
                   const float* A2, int lda2, int K2,
                   long long boff, int ncp,
                   const float* b1, const float* b2, int bsplit,
                   float* C, int ldc, int Nn, int act,
                   ushort* Cb, int ldcb){
    dim3 grid(N_TOT/64, ncp/nt);
    if (limbs == 3 && nt == 64)
      hipLaunchKernelGGL((mfma_gemm<3,0,64>), grid, dim3(256), 0, stream,
          A1, lda1, K1, A2, lda2, K2, pool + boff, ncp, b1, b2, bsplit,
          C, ldc, Nn, act, Cb, ldcb);
    else if (limbs == 3)
      hipLaunchKernelGGL((mfma_gemm<3,0,128>), grid, dim3(256), 0, stream,
          A1, lda1, K1, A2, lda2, K2, pool + boff, ncp, b1, b2, bsplit,
          C, ldc, Nn, act, Cb, ldcb);
    else if (abf)
      hipLaunchKernelGGL((mfma_gemm<1,1,128>), grid, dim3(256), 0, stream,
          A1, lda1, K1, A2, lda2, K2, pool + boff, ncp, b1, b2, bsplit,
          C, ldc, Nn, act, Cb, ldcb);
    else
      hipLaunchKernelGGL((mfma_gemm<1,0,128>), grid, dim3(256), 0, stream,
          A1, lda1, K1, A2, lda2, K2, pool + boff, ncp, b1, b2, bsplit,
          C, ldc, Nn, act, Cb, ldcb);
  };
  auto gemmS = [&](const float* A1, int lda1, int K1,
                   const float* W, const float* b,
                   float* C, int ldc, int Nn, int act,
                   const float* addx, int addx_ld, int addx_off){
    dim3 grid(N_TOT/64, (Nn+63)/64);
    hipLaunchKernelGGL((gemm_tile_kernel<64,64,32,4,4>), grid, dim3(256), 0, stream,
        A1, lda1, K1, W, b, C, ldc, Nn, act, addx, addx_ld, addx_off);
  };
  const int BIG = 1 << 30;

  auto run_embedding = [&](float* dst){
    gemmM(3,0,128, x, IN_DIM, IN_DIM, nullptr,0,0, o_e1, 128, n0b1, nullptr, BIG,
          Q, EMB, WIDTH, 1, nullptr, 0);
    gemmM(3,0,128, Q, EMB, WIDTH, nullptr,0,0, o_e2, 128, n0b23, nullptr, BIG,
          P, EMB, WIDTH, 1, nullptr, 0);
    gemmM(3,0,128, P, EMB, WIDTH, nullptr,0,0, o_e3, 128, n0b23 + WIDTH, nullptr, BIG,
          Q, EMB, WIDTH, 1, nullptr, 0);
    gemmM(3,0,128, Q, EMB, WIDTH, nullptr,0,0, o_e4, 128, n0b4, nullptr, BIG,
          dst, EMB, EMB, 0, nullptr, 0);
  };

  if (haveE) run_embedding(E);

  for (int s = 0; s < 2; ++s){
    hipLaunchKernelGGL(xconv_kernel, dim3((N_TOT*IN_DIM + 255)/256), dim3(256),
                       0, stream, x, featb);
    if (!haveE) run_embedding(P);

    float* cur = haveE ? E : P;
    float* b0  = haveE ? P : Q;
    float* b1  = haveE ? Q : P;

    gemmM(3,0,64, cur, EMB, EMB, nullptr,0,0, o_pj[s*NCONV], 64,
          cbh + (s*NCONV)*PROP, cbs + (s*NCONV)*SPACE, PROP,
          projb, PRJW, PRJW, 0, nullptr, 0);

    for (int cv = 0; cv < NCONV; ++cv){
      int pidx = s*NCONV + cv;
      float* nxt = (cv & 1) ? b1 : b0;
      hipLaunchKernelGGL(knn_agg_kernel, dim3(NG*16), dim3(256), 0, stream,
                         projb, aggb);
      if (cv < NCONV-1){
        int pnx = pidx + 1;
        hipLaunchKernelGGL(fused_wo_proj, dim3(N_TOT/64), dim3(256), 0, stream,
            cur, aggb, pool + o_wo[pidx], cbo + pidx*EMB,
            pool + o_pj[pnx], cbh + pnx*PROP, cbs + pnx*SPACE,
            nxt, featb + IN_DIM + cv*EMB, FLDB, projb);
      } else {
        gemmM(3,0,128, cur, EMB, EMB, aggb, AGGW, AGGW, o_wo[pidx], 128,
              cbo + pidx*EMB, nullptr, BIG, nxt, EMB, EMB, 0,
              featb + IN_DIM + cv*EMB, FLDB);
      }
      cur = nxt;
    }

    if (s == 0){
      gemmM(1,1,128, featb, FLDB, FEAT, nullptr,0,0, o_L1s0, 128,
            Hb1, nullptr, BIG, hacc, WIDTH, WIDTH, 1, nullptr, 0);
    } else {
      gemmM(1,1,128, featb, FLDB, FEAT, nullptr,0,0, o_L1s12, 256,
            Hb1 + WIDTH, Hb1 + 2*WIDTH, WIDTH,
            hacc, 2*WIDTH, 2*WIDTH, 1, nullptr, 0);
    }

    auto finish_head = [&](int hidx, float* ha, int lda_ha,
                           float* dst, int dst_ld, int out_dim,
                           const float* Wl, const float* bl,
                           const float* addx, int addx_ld, int addx_off){
      gemmM(1,0,128, ha, lda_ha, WIDTH, nullptr,0,0, o_hh[hidx*2+0], 128,
            Hb23 + (hidx*2+0)*WIDTH, nullptr, BIG,
            t1, WIDTH, WIDTH, 1, nullptr, 0);
      gemmM(1,0,128, t1, WIDTH, WIDTH, nullptr,0,0, o_hh[hidx*2+1], 128,
            Hb23 + (hidx*2+1)*WIDTH, nullptr, BIG,
            ha, lda_ha, WIDTH, 1, nullptr, 0);
      gemmS(ha, lda_ha, WIDTH, Wl, bl, dst, dst_ld, out_dim, 0,
            addx, addx_ld, addx_off);
    };

    if (s == 0){
      finish_head(0, hacc, WIDTH, out, 8, 8, Wid, bid, nullptr, 0, 0);
    } else {
      finish_head(1, hacc, 2*WIDTH, out + (size_t)N_TOT*8, 4, 4,
                  Wreg, breg, x, IN_DIM, 1);
      finish_head(2, hacc + WIDTH, 2*WIDTH, out + (size_t)N_TOT*12, 1, 1,
                  Wch, bch, nullptr, 0, 0);
    }
  }
}